// Round 1
// baseline (1970.204 us; speedup 1.0000x reference)
//
#include <hip/hip_runtime.h>
#include <math.h>

#define C_DIM 192
#define N_ST 16
#define K_DIR 4
#define D_RK 12
#define B_SZ 2
#define H_SZ 64
#define W_SZ 64
#define L_SZ 4096
#define DPROJ 44  // D_RK + 2*N_ST

__device__ __forceinline__ float sigmoidf_(float x) { return 1.f / (1.f + __expf(-x)); }

// scan-order index t -> memory index l in xc's (B,L,C) layout, per direction k
__device__ __forceinline__ int scan_map(int k, int t) {
    int te = (k & 1) ? (L_SZ - 1 - t) : t;
    return (k >= 2) ? (((te & 63) << 6) | (te >> 6)) : te;  // transpose HxW (64x64)
}

// C = A(MxK) * B(KxN), row-major. Tiles 64x64, K-step 16, thread 4x4.
__global__ __launch_bounds__(256) void gemm_f32(const float* __restrict__ A,
        const float* __restrict__ Bw, float* __restrict__ Cc, int M, int N, int Kd)
{
    __shared__ float As[16][64];
    __shared__ float Bs[16][64];
    const int tx = threadIdx.x & 15, ty = threadIdx.x >> 4;
    const int row0 = blockIdx.x * 64, col0 = blockIdx.y * 64;
    float acc[4][4] = {{0.f}};
    for (int kk = 0; kk < Kd; kk += 16) {
        for (int i = threadIdx.x; i < 1024; i += 256) {
            int m = i >> 4, kq = i & 15;
            As[kq][m] = A[(size_t)(row0 + m) * Kd + kk + kq];
        }
        for (int i = threadIdx.x; i < 1024; i += 256) {
            int kq = i >> 6, nn = i & 63;
            Bs[kq][nn] = Bw[(size_t)(kk + kq) * N + col0 + nn];
        }
        __syncthreads();
        #pragma unroll
        for (int kq = 0; kq < 16; ++kq) {
            float av[4], bv[4];
            #pragma unroll
            for (int i = 0; i < 4; ++i) av[i] = As[kq][ty * 4 + i];
            #pragma unroll
            for (int j = 0; j < 4; ++j) bv[j] = Bs[kq][tx * 4 + j];
            #pragma unroll
            for (int i = 0; i < 4; ++i)
                #pragma unroll
                for (int j = 0; j < 4; ++j)
                    acc[i][j] = fmaf(av[i], bv[j], acc[i][j]);
        }
        __syncthreads();
    }
    #pragma unroll
    for (int i = 0; i < 4; ++i)
        #pragma unroll
        for (int j = 0; j < 4; ++j)
            Cc[(size_t)(row0 + ty * 4 + i) * N + col0 + tx * 4 + j] = acc[i][j];
}

// depthwise 3x3 SAME conv on x_ssm (first 192 cols of xz) + bias + SiLU -> xc (B,L,C)
__global__ __launch_bounds__(192) void conv_silu(const float* __restrict__ xz,
        const float* __restrict__ cw, const float* __restrict__ cb, float* __restrict__ xc)
{
    const int c = threadIdx.x;
    const int l = blockIdx.x;
    const int b = blockIdx.y;
    const int h = l >> 6, w = l & 63;
    float wg[9];
    #pragma unroll
    for (int i = 0; i < 9; ++i) wg[i] = cw[c * 9 + i];
    float acc = cb[c];
    #pragma unroll
    for (int dh = -1; dh <= 1; ++dh) {
        int hh = h + dh;
        if (hh < 0 || hh >= H_SZ) continue;
        #pragma unroll
        for (int dw = -1; dw <= 1; ++dw) {
            int ww = w + dw;
            if (ww < 0 || ww >= W_SZ) continue;
            acc += xz[((size_t)(b * L_SZ) + hh * W_SZ + ww) * (2 * C_DIM) + c]
                   * wg[(dh + 1) * 3 + (dw + 1)];
        }
    }
    float v = acc * sigmoidf_(acc);
    xc[((size_t)(b * L_SZ) + l) * C_DIM + c] = v;
}

// per (k,b,l-tile of 64): proj = xs @ x_proj_w (44 out), then
// delta = softplus(dpart @ dt_w + 2*dt_b) (dt_b added twice in reference!)
__global__ __launch_bounds__(256) void proj_kernel(const float* __restrict__ xc,
        const float* __restrict__ xpw, const float* __restrict__ dtw,
        const float* __restrict__ dtb,
        float* __restrict__ delta, float* __restrict__ Bm, float* __restrict__ Cm)
{
    __shared__ float ls[64][C_DIM];  // 48 KB
    __shared__ float pj[64][DPROJ];  // 11 KB
    const int l0 = blockIdx.x * 64;
    const int b = blockIdx.y;
    const int k = blockIdx.z;
    const int kb = k * B_SZ + b;
    for (int i = threadIdx.x; i < 64 * C_DIM; i += 256) {
        int ll = i / C_DIM, c = i % C_DIM;
        ls[ll][c] = xc[((size_t)b * L_SZ + scan_map(k, l0 + ll)) * C_DIM + c];
    }
    __syncthreads();
    for (int o = threadIdx.x; o < 64 * DPROJ; o += 256) {
        int ll = o / DPROJ, d = o % DPROJ;
        float s = 0.f;
        const float* wp = xpw + (size_t)k * C_DIM * DPROJ + d;
        #pragma unroll 8
        for (int c = 0; c < C_DIM; ++c) s = fmaf(ls[ll][c], wp[c * DPROJ], s);
        pj[ll][d] = s;
    }
    __syncthreads();
    for (int o = threadIdx.x; o < 64 * C_DIM; o += 256) {
        int ll = o / C_DIM, c = o % C_DIM;
        float s = 2.f * dtb[k * C_DIM + c];
        const float* wp = dtw + (size_t)k * D_RK * C_DIM + c;
        #pragma unroll
        for (int r = 0; r < D_RK; ++r) s = fmaf(pj[ll][r], wp[r * C_DIM], s);
        float sp = (s > 20.f) ? s : log1pf(__expf(s));
        delta[((size_t)kb * L_SZ + l0 + ll) * C_DIM + c] = sp;
    }
    for (int o = threadIdx.x; o < 64 * N_ST; o += 256) {
        int ll = o / N_ST, n = o % N_ST;
        Bm[((size_t)kb * L_SZ + l0 + ll) * N_ST + n] = pj[ll][D_RK + n];
        Cm[((size_t)kb * L_SZ + l0 + ll) * N_ST + n] = pj[ll][D_RK + N_ST + n];
    }
}

// sequential selective scan. wave = 4 channels x 16 states; lane=(ci,n).
// ys (K,B,L,C) gets y + Ds*u.
__global__ __launch_bounds__(256) void scan_kernel(const float* __restrict__ delta,
        const float* __restrict__ Bm, const float* __restrict__ Cm,
        const float* __restrict__ xc, const float* __restrict__ A_logs,
        const float* __restrict__ Ds, float* __restrict__ ys)
{
    const int kb = blockIdx.y;
    const int k = kb / B_SZ, b = kb % B_SZ;
    const int wave = threadIdx.x >> 6;
    const int lane = threadIdx.x & 63;
    const int ci = lane >> 4;
    const int n = lane & 15;
    const int c = blockIdx.x * 16 + wave * 4 + ci;
    const float A_neg = -__expf(A_logs[((size_t)k * C_DIM + c) * N_ST + n]);
    const float Dv = Ds[k * C_DIM + c];
    const float* dp = delta + (size_t)kb * L_SZ * C_DIM + c;
    const float* Bp = Bm + (size_t)kb * L_SZ * N_ST + n;
    const float* Cp = Cm + (size_t)kb * L_SZ * N_ST + n;
    const float* xcb = xc + (size_t)b * L_SZ * C_DIM + c;
    float* yp = ys + (size_t)kb * L_SZ * C_DIM + c;
    const bool rev = (k & 1), tr = (k >= 2);
    float h = 0.f;
    #pragma unroll 4
    for (int t = 0; t < L_SZ; ++t) {
        int te = rev ? (L_SZ - 1 - t) : t;
        int lm = tr ? (((te & 63) << 6) | (te >> 6)) : te;
        float dlt = dp[(size_t)t * C_DIM];
        float u = xcb[(size_t)lm * C_DIM];
        float Bv = Bp[(size_t)t * N_ST];
        float Cv = Cp[(size_t)t * N_ST];
        float a = __expf(dlt * A_neg);
        h = fmaf(a, h, dlt * u * Bv);
        float p = h * Cv;
        p += __shfl_xor(p, 1);
        p += __shfl_xor(p, 2);
        p += __shfl_xor(p, 4);
        p += __shfl_xor(p, 8);
        if (n == 0) yp[(size_t)t * C_DIM] = p + Dv * u;
    }
}

// y(b,l,c) = sum over 4 directions with inverse index maps
__global__ __launch_bounds__(256) void combine_kernel(const float* __restrict__ ys,
                                                      float* __restrict__ yc)
{
    int idx = blockIdx.x * 256 + threadIdx.x;  // (b*L + l)*C + c
    int c = idx % C_DIM;
    int bl = idx / C_DIM;
    int l = bl % L_SZ;
    int b = bl / L_SZ;
    int l2 = ((l & 63) << 6) | (l >> 6);
    size_t s0 = ((size_t)(0 * B_SZ + b) * L_SZ + l) * C_DIM + c;
    size_t s1 = ((size_t)(1 * B_SZ + b) * L_SZ + (L_SZ - 1 - l)) * C_DIM + c;
    size_t s2 = ((size_t)(2 * B_SZ + b) * L_SZ + l2) * C_DIM + c;
    size_t s3 = ((size_t)(3 * B_SZ + b) * L_SZ + (L_SZ - 1 - l2)) * C_DIM + c;
    yc[idx] = ys[s0] + ys[s1] + ys[s2] + ys[s3];
}

// LayerNorm over C, then * silu(z). wave per row.
__global__ __launch_bounds__(256) void ln_silu_kernel(const float* __restrict__ yc,
        const float* __restrict__ xz, const float* __restrict__ g,
        const float* __restrict__ bb, float* __restrict__ outp)
{
    const int row = blockIdx.x * 4 + (threadIdx.x >> 6);
    const int lane = threadIdx.x & 63;
    float v[3];
    float s = 0.f, s2 = 0.f;
    #pragma unroll
    for (int j = 0; j < 3; ++j) {
        v[j] = yc[(size_t)row * C_DIM + lane + 64 * j];
        s += v[j];
        s2 += v[j] * v[j];
    }
    #pragma unroll
    for (int off = 1; off < 64; off <<= 1) {
        s += __shfl_xor(s, off);
        s2 += __shfl_xor(s2, off);
    }
    float mu = s / C_DIM;
    float var = s2 / C_DIM - mu * mu;
    float rstd = rsqrtf(var + 1e-5f);
    #pragma unroll
    for (int j = 0; j < 3; ++j) {
        int c = lane + 64 * j;
        float zv = xz[(size_t)row * (2 * C_DIM) + C_DIM + c];
        float t = (v[j] - mu) * rstd * g[c] + bb[c];
        outp[(size_t)row * C_DIM + c] = t * (zv * sigmoidf_(zv));
    }
}

extern "C" void kernel_launch(void* const* d_in, const int* in_sizes, int n_in,
                              void* d_out, int out_size, void* d_ws, size_t ws_size,
                              hipStream_t stream)
{
    const float* x         = (const float*)d_in[0];
    const float* in_proj_w = (const float*)d_in[1];
    const float* conv_w    = (const float*)d_in[2];
    const float* conv_b    = (const float*)d_in[3];
    const float* x_proj_w  = (const float*)d_in[4];
    const float* dt_w      = (const float*)d_in[5];
    const float* dt_b      = (const float*)d_in[6];
    const float* A_logs    = (const float*)d_in[7];
    const float* Ds        = (const float*)d_in[8];
    const float* ln_g      = (const float*)d_in[9];
    const float* ln_b      = (const float*)d_in[10];
    const float* out_w     = (const float*)d_in[11];
    float* out = (float*)d_out;
    float* ws = (float*)d_ws;

    const size_t M = (size_t)B_SZ * L_SZ;  // 8192
    float* xz    = ws;                              // M*384
    float* xc    = xz + M * 384;                    // M*192
    float* delta = xc + M * C_DIM;                  // K*M*192
    float* Bm    = delta + (size_t)K_DIR * M * C_DIM;
    float* Cm    = Bm + (size_t)K_DIR * M * N_ST;
    float* ys    = Cm + (size_t)K_DIR * M * N_ST;   // K*M*192
    float* yc    = delta;                           // reuse after scan
    float* tbuf  = delta + M * C_DIM;               // reuse after scan

    gemm_f32<<<dim3(M / 64, 384 / 64), 256, 0, stream>>>(x, in_proj_w, xz, (int)M, 2 * C_DIM, C_DIM);
    conv_silu<<<dim3(L_SZ, B_SZ), 192, 0, stream>>>(xz, conv_w, conv_b, xc);
    proj_kernel<<<dim3(L_SZ / 64, B_SZ, K_DIR), 256, 0, stream>>>(xc, x_proj_w, dt_w, dt_b, delta, Bm, Cm);
    scan_kernel<<<dim3(C_DIM / 16, K_DIR * B_SZ), 256, 0, stream>>>(delta, Bm, Cm, xc, A_logs, Ds, ys);
    combine_kernel<<<dim3((B_SZ * L_SZ * C_DIM) / 256), 256, 0, stream>>>(ys, yc);
    ln_silu_kernel<<<dim3(M / 4), 256, 0, stream>>>(yc, xz, ln_g, ln_b, tbuf);
    gemm_f32<<<dim3(M / 64, C_DIM / 64), 256, 0, stream>>>(tbuf, out_w, out, (int)M, C_DIM, C_DIM);
}

// Round 2
// 318.852 us; speedup vs baseline: 6.1791x; 6.1791x over previous
//
#include <hip/hip_runtime.h>
#include <math.h>

#define C_DIM 192
#define N_ST 16
#define K_DIR 4
#define D_RK 12
#define B_SZ 2
#define H_SZ 64
#define W_SZ 64
#define L_SZ 4096
#define DPROJ 44   // D_RK + 2*N_ST
#define NCHUNK 64
#define TCHUNK 64  // L_SZ / NCHUNK

__device__ __forceinline__ float sigmoidf_(float x) { return 1.f / (1.f + __expf(-x)); }

// scan-order index t -> memory index l in xc's (B,L,C) layout, per direction k
__device__ __forceinline__ int scan_map(int k, int t) {
    int te = (k & 1) ? (L_SZ - 1 - t) : t;
    return (k >= 2) ? (((te & 63) << 6) | (te >> 6)) : te;  // transpose HxW (64x64)
}

// C = A(MxK) * B(KxN), row-major. Tiles 64x64, K-step 16, thread 4x4.
__global__ __launch_bounds__(256) void gemm_f32(const float* __restrict__ A,
        const float* __restrict__ Bw, float* __restrict__ Cc, int M, int N, int Kd)
{
    __shared__ float As[16][64];
    __shared__ float Bs[16][64];
    const int tx = threadIdx.x & 15, ty = threadIdx.x >> 4;
    const int row0 = blockIdx.x * 64, col0 = blockIdx.y * 64;
    float acc[4][4] = {{0.f}};
    for (int kk = 0; kk < Kd; kk += 16) {
        for (int i = threadIdx.x; i < 1024; i += 256) {
            int m = i >> 4, kq = i & 15;
            As[kq][m] = A[(size_t)(row0 + m) * Kd + kk + kq];
        }
        for (int i = threadIdx.x; i < 1024; i += 256) {
            int kq = i >> 6, nn = i & 63;
            Bs[kq][nn] = Bw[(size_t)(kk + kq) * N + col0 + nn];
        }
        __syncthreads();
        #pragma unroll
        for (int kq = 0; kq < 16; ++kq) {
            float av[4], bv[4];
            #pragma unroll
            for (int i = 0; i < 4; ++i) av[i] = As[kq][ty * 4 + i];
            #pragma unroll
            for (int j = 0; j < 4; ++j) bv[j] = Bs[kq][tx * 4 + j];
            #pragma unroll
            for (int i = 0; i < 4; ++i)
                #pragma unroll
                for (int j = 0; j < 4; ++j)
                    acc[i][j] = fmaf(av[i], bv[j], acc[i][j]);
        }
        __syncthreads();
    }
    #pragma unroll
    for (int i = 0; i < 4; ++i)
        #pragma unroll
        for (int j = 0; j < 4; ++j)
            Cc[(size_t)(row0 + ty * 4 + i) * N + col0 + tx * 4 + j] = acc[i][j];
}

// depthwise 3x3 SAME conv on x_ssm (first 192 cols of xz) + bias + SiLU -> xc (B,L,C)
__global__ __launch_bounds__(192) void conv_silu(const float* __restrict__ xz,
        const float* __restrict__ cw, const float* __restrict__ cb, float* __restrict__ xc)
{
    const int c = threadIdx.x;
    const int l = blockIdx.x;
    const int b = blockIdx.y;
    const int h = l >> 6, w = l & 63;
    float wg[9];
    #pragma unroll
    for (int i = 0; i < 9; ++i) wg[i] = cw[c * 9 + i];
    float acc = cb[c];
    #pragma unroll
    for (int dh = -1; dh <= 1; ++dh) {
        int hh = h + dh;
        if (hh < 0 || hh >= H_SZ) continue;
        #pragma unroll
        for (int dw = -1; dw <= 1; ++dw) {
            int ww = w + dw;
            if (ww < 0 || ww >= W_SZ) continue;
            acc += xz[((size_t)(b * L_SZ) + hh * W_SZ + ww) * (2 * C_DIM) + c]
                   * wg[(dh + 1) * 3 + (dw + 1)];
        }
    }
    float v = acc * sigmoidf_(acc);
    xc[((size_t)(b * L_SZ) + l) * C_DIM + c] = v;
}

// per (k,b,l-tile of 64): proj = xs @ x_proj_w (44 out), then
// delta = softplus(dpart @ dt_w + 2*dt_b) (dt_b added twice in reference!)
__global__ __launch_bounds__(256) void proj_kernel(const float* __restrict__ xc,
        const float* __restrict__ xpw, const float* __restrict__ dtw,
        const float* __restrict__ dtb,
        float* __restrict__ delta, float* __restrict__ Bm, float* __restrict__ Cm)
{
    __shared__ float ls[64][C_DIM];  // 48 KB
    __shared__ float pj[64][DPROJ];  // 11 KB
    const int l0 = blockIdx.x * 64;
    const int b = blockIdx.y;
    const int k = blockIdx.z;
    const int kb = k * B_SZ + b;
    for (int i = threadIdx.x; i < 64 * C_DIM; i += 256) {
        int ll = i / C_DIM, c = i % C_DIM;
        ls[ll][c] = xc[((size_t)b * L_SZ + scan_map(k, l0 + ll)) * C_DIM + c];
    }
    __syncthreads();
    for (int o = threadIdx.x; o < 64 * DPROJ; o += 256) {
        int ll = o / DPROJ, d = o % DPROJ;
        float s = 0.f;
        const float* wp = xpw + (size_t)k * C_DIM * DPROJ + d;
        #pragma unroll 8
        for (int c = 0; c < C_DIM; ++c) s = fmaf(ls[ll][c], wp[c * DPROJ], s);
        pj[ll][d] = s;
    }
    __syncthreads();
    for (int o = threadIdx.x; o < 64 * C_DIM; o += 256) {
        int ll = o / C_DIM, c = o % C_DIM;
        float s = 2.f * dtb[k * C_DIM + c];
        const float* wp = dtw + (size_t)k * D_RK * C_DIM + c;
        #pragma unroll
        for (int r = 0; r < D_RK; ++r) s = fmaf(pj[ll][r], wp[r * C_DIM], s);
        float sp = (s > 20.f) ? s : log1pf(__expf(s));
        delta[((size_t)kb * L_SZ + l0 + ll) * C_DIM + c] = sp;
    }
    for (int o = threadIdx.x; o < 64 * N_ST; o += 256) {
        int ll = o / N_ST, n = o % N_ST;
        Bm[((size_t)kb * L_SZ + l0 + ll) * N_ST + n] = pj[ll][D_RK + n];
        Cm[((size_t)kb * L_SZ + l0 + ll) * N_ST + n] = pj[ll][D_RK + N_ST + n];
    }
}

// ---- chunked parallel scan ----
// S1: per (kb, c, n, chunk): chunk summary (Aprod, Bsum) of h' = a*h + b over TCHUNK steps.
__global__ __launch_bounds__(256) void scan_part1(const float* __restrict__ delta,
        const float* __restrict__ Bm, const float* __restrict__ xc,
        const float* __restrict__ A_logs,
        float* __restrict__ Aprod, float* __restrict__ Bsum)
{
    const int kb = blockIdx.y;
    const int k = kb >> 1, b = kb & 1;
    const int chunk = blockIdx.z;
    const int wave = threadIdx.x >> 6;
    const int lane = threadIdx.x & 63;
    const int ci = lane >> 4;
    const int n = lane & 15;
    const int c = blockIdx.x * 16 + wave * 4 + ci;
    const float A_neg = -__expf(A_logs[((size_t)k * C_DIM + c) * N_ST + n]);
    const float* dp = delta + ((size_t)kb * L_SZ + chunk * TCHUNK) * C_DIM + c;
    const float* Bp = Bm + ((size_t)kb * L_SZ + chunk * TCHUNK) * N_ST + n;
    const float* xcb = xc + (size_t)b * L_SZ * C_DIM + c;
    float Ap = 1.f, h = 0.f;
    #pragma unroll 4
    for (int i = 0; i < TCHUNK; ++i) {
        int t = chunk * TCHUNK + i;
        float dlt = dp[(size_t)i * C_DIM];
        float u = xcb[(size_t)scan_map(k, t) * C_DIM];
        float Bv = Bp[(size_t)i * N_ST];
        float a = __expf(dlt * A_neg);
        h = fmaf(a, h, dlt * u * Bv);
        Ap *= a;
    }
    size_t o = ((size_t)(chunk * K_DIR * B_SZ + kb) * C_DIM + c) * N_ST + n;
    Aprod[o] = Ap;
    Bsum[o] = h;
}

// S2: sequential compose over chunks -> exclusive prefix = h_init per chunk.
__global__ __launch_bounds__(256) void scan_part2(const float* __restrict__ Aprod,
        const float* __restrict__ Bsum, float* __restrict__ hinit)
{
    const int kb = blockIdx.y;
    const int wave = threadIdx.x >> 6;
    const int lane = threadIdx.x & 63;
    const int ci = lane >> 4;
    const int n = lane & 15;
    const int c = blockIdx.x * 16 + wave * 4 + ci;
    float h = 0.f;
    #pragma unroll 8
    for (int ch = 0; ch < NCHUNK; ++ch) {
        size_t o = ((size_t)(ch * K_DIR * B_SZ + kb) * C_DIM + c) * N_ST + n;
        hinit[o] = h;
        h = fmaf(Aprod[o], h, Bsum[o]);
    }
}

// S3: re-run each chunk from h_init; y = sum_n h*C (+ Ds*u) -> ys (K,B,L,C)
__global__ __launch_bounds__(256) void scan_part3(const float* __restrict__ delta,
        const float* __restrict__ Bm, const float* __restrict__ Cm,
        const float* __restrict__ xc, const float* __restrict__ A_logs,
        const float* __restrict__ Ds, const float* __restrict__ hinit,
        float* __restrict__ ys)
{
    const int kb = blockIdx.y;
    const int k = kb >> 1, b = kb & 1;
    const int chunk = blockIdx.z;
    const int wave = threadIdx.x >> 6;
    const int lane = threadIdx.x & 63;
    const int ci = lane >> 4;
    const int n = lane & 15;
    const int c = blockIdx.x * 16 + wave * 4 + ci;
    const float A_neg = -__expf(A_logs[((size_t)k * C_DIM + c) * N_ST + n]);
    const float Dv = Ds[k * C_DIM + c];
    const float* dp = delta + ((size_t)kb * L_SZ + chunk * TCHUNK) * C_DIM + c;
    const float* Bp = Bm + ((size_t)kb * L_SZ + chunk * TCHUNK) * N_ST + n;
    const float* Cp = Cm + ((size_t)kb * L_SZ + chunk * TCHUNK) * N_ST + n;
    const float* xcb = xc + (size_t)b * L_SZ * C_DIM + c;
    float* yp = ys + ((size_t)kb * L_SZ + chunk * TCHUNK) * C_DIM + c;
    float h = hinit[((size_t)(chunk * K_DIR * B_SZ + kb) * C_DIM + c) * N_ST + n];
    #pragma unroll 4
    for (int i = 0; i < TCHUNK; ++i) {
        int t = chunk * TCHUNK + i;
        float dlt = dp[(size_t)i * C_DIM];
        float u = xcb[(size_t)scan_map(k, t) * C_DIM];
        float Bv = Bp[(size_t)i * N_ST];
        float Cv = Cp[(size_t)i * N_ST];
        float a = __expf(dlt * A_neg);
        h = fmaf(a, h, dlt * u * Bv);
        float p = h * Cv;
        p += __shfl_xor(p, 1);
        p += __shfl_xor(p, 2);
        p += __shfl_xor(p, 4);
        p += __shfl_xor(p, 8);
        if (n == 0) yp[(size_t)i * C_DIM] = p + Dv * u;
    }
}

// y(b,l,c) = sum over 4 directions with inverse index maps
__global__ __launch_bounds__(256) void combine_kernel(const float* __restrict__ ys,
                                                      float* __restrict__ yc)
{
    int idx = blockIdx.x * 256 + threadIdx.x;  // (b*L + l)*C + c
    int c = idx % C_DIM;
    int bl = idx / C_DIM;
    int l = bl % L_SZ;
    int b = bl / L_SZ;
    int l2 = ((l & 63) << 6) | (l >> 6);
    size_t s0 = ((size_t)(0 * B_SZ + b) * L_SZ + l) * C_DIM + c;
    size_t s1 = ((size_t)(1 * B_SZ + b) * L_SZ + (L_SZ - 1 - l)) * C_DIM + c;
    size_t s2 = ((size_t)(2 * B_SZ + b) * L_SZ + l2) * C_DIM + c;
    size_t s3 = ((size_t)(3 * B_SZ + b) * L_SZ + (L_SZ - 1 - l2)) * C_DIM + c;
    yc[idx] = ys[s0] + ys[s1] + ys[s2] + ys[s3];
}

// LayerNorm over C, then * silu(z). wave per row.
__global__ __launch_bounds__(256) void ln_silu_kernel(const float* __restrict__ yc,
        const float* __restrict__ xz, const float* __restrict__ g,
        const float* __restrict__ bb, float* __restrict__ outp)
{
    const int row = blockIdx.x * 4 + (threadIdx.x >> 6);
    const int lane = threadIdx.x & 63;
    float v[3];
    float s = 0.f, s2 = 0.f;
    #pragma unroll
    for (int j = 0; j < 3; ++j) {
        v[j] = yc[(size_t)row * C_DIM + lane + 64 * j];
        s += v[j];
        s2 += v[j] * v[j];
    }
    #pragma unroll
    for (int off = 1; off < 64; off <<= 1) {
        s += __shfl_xor(s, off);
        s2 += __shfl_xor(s2, off);
    }
    float mu = s / C_DIM;
    float var = s2 / C_DIM - mu * mu;
    float rstd = rsqrtf(var + 1e-5f);
    #pragma unroll
    for (int j = 0; j < 3; ++j) {
        int c = lane + 64 * j;
        float zv = xz[(size_t)row * (2 * C_DIM) + C_DIM + c];
        float t = (v[j] - mu) * rstd * g[c] + bb[c];
        outp[(size_t)row * C_DIM + c] = t * (zv * sigmoidf_(zv));
    }
}

extern "C" void kernel_launch(void* const* d_in, const int* in_sizes, int n_in,
                              void* d_out, int out_size, void* d_ws, size_t ws_size,
                              hipStream_t stream)
{
    const float* x         = (const float*)d_in[0];
    const float* in_proj_w = (const float*)d_in[1];
    const float* conv_w    = (const float*)d_in[2];
    const float* conv_b    = (const float*)d_in[3];
    const float* x_proj_w  = (const float*)d_in[4];
    const float* dt_w      = (const float*)d_in[5];
    const float* dt_b      = (const float*)d_in[6];
    const float* A_logs    = (const float*)d_in[7];
    const float* Ds        = (const float*)d_in[8];
    const float* ln_g      = (const float*)d_in[9];
    const float* ln_b      = (const float*)d_in[10];
    const float* out_w     = (const float*)d_in[11];
    float* out = (float*)d_out;
    float* ws = (float*)d_ws;

    const size_t M = (size_t)B_SZ * L_SZ;  // 8192
    const size_t SUMSZ = (size_t)NCHUNK * K_DIR * B_SZ * C_DIM * N_ST;  // 1.57M

    float* xz    = ws;                              // M*384
    float* xc    = xz + M * 384;                    // M*192
    float* delta = xc + M * C_DIM;                  // K*M*192
    float* Bm    = delta + (size_t)K_DIR * M * C_DIM;
    float* Cm    = Bm + (size_t)K_DIR * M * N_ST;
    float* ys    = Cm + (size_t)K_DIR * M * N_ST;   // K*M*192
    // Aprod/Bsum overlay ys (dead before scan_part3 writes ys)
    float* Aprod = ys;
    float* Bsum  = ys + SUMSZ;
    float* hinit = ys + (size_t)K_DIR * M * C_DIM;  // +6.3MB past ys
    float* yc    = delta;                           // reuse after scan
    float* tbuf  = delta + M * C_DIM;               // reuse after scan

    gemm_f32<<<dim3(M / 64, 384 / 64), 256, 0, stream>>>(x, in_proj_w, xz, (int)M, 2 * C_DIM, C_DIM);
    conv_silu<<<dim3(L_SZ, B_SZ), 192, 0, stream>>>(xz, conv_w, conv_b, xc);
    proj_kernel<<<dim3(L_SZ / 64, B_SZ, K_DIR), 256, 0, stream>>>(xc, x_proj_w, dt_w, dt_b, delta, Bm, Cm);
    scan_part1<<<dim3(C_DIM / 16, K_DIR * B_SZ, NCHUNK), 256, 0, stream>>>(delta, Bm, xc, A_logs, Aprod, Bsum);
    scan_part2<<<dim3(C_DIM / 16, K_DIR * B_SZ), 256, 0, stream>>>(Aprod, Bsum, hinit);
    scan_part3<<<dim3(C_DIM / 16, K_DIR * B_SZ, NCHUNK), 256, 0, stream>>>(delta, Bm, Cm, xc, A_logs, Ds, hinit, ys);
    combine_kernel<<<dim3((B_SZ * L_SZ * C_DIM) / 256), 256, 0, stream>>>(ys, yc);
    ln_silu_kernel<<<dim3(M / 4), 256, 0, stream>>>(yc, xz, ln_g, ln_b, tbuf);
    gemm_f32<<<dim3(M / 64, C_DIM / 64), 256, 0, stream>>>(tbuf, out_w, out, (int)M, C_DIM, C_DIM);
}

// Round 3
// 297.306 us; speedup vs baseline: 6.6269x; 1.0725x over previous
//
#include <hip/hip_runtime.h>
#include <math.h>

#define C_DIM 192
#define N_ST 16
#define K_DIR 4
#define D_RK 12
#define B_SZ 2
#define H_SZ 64
#define W_SZ 64
#define L_SZ 4096
#define DPROJ 44   // D_RK + 2*N_ST
#define NCHUNK 64
#define TCHUNK 64  // L_SZ / NCHUNK

__device__ __forceinline__ float sigmoidf_(float x) { return 1.f / (1.f + __expf(-x)); }

// scan-order index t -> memory index l in xc's (B,L,C) layout, per direction k
__device__ __forceinline__ int scan_map(int k, int t) {
    int te = (k & 1) ? (L_SZ - 1 - t) : t;
    return (k >= 2) ? (((te & 63) << 6) | (te >> 6)) : te;  // transpose HxW (64x64)
}

// C = A(MxK) * B(KxN), row-major. Tiles 64x64, K-step 16, thread 4x4.
__global__ __launch_bounds__(256) void gemm_f32(const float* __restrict__ A,
        const float* __restrict__ Bw, float* __restrict__ Cc, int M, int N, int Kd)
{
    __shared__ float As[16][64];
    __shared__ float Bs[16][64];
    const int tx = threadIdx.x & 15, ty = threadIdx.x >> 4;
    const int row0 = blockIdx.x * 64, col0 = blockIdx.y * 64;
    float acc[4][4] = {{0.f}};
    for (int kk = 0; kk < Kd; kk += 16) {
        for (int i = threadIdx.x; i < 1024; i += 256) {
            int m = i >> 4, kq = i & 15;
            As[kq][m] = A[(size_t)(row0 + m) * Kd + kk + kq];
        }
        for (int i = threadIdx.x; i < 1024; i += 256) {
            int kq = i >> 6, nn = i & 63;
            Bs[kq][nn] = Bw[(size_t)(kk + kq) * N + col0 + nn];
        }
        __syncthreads();
        #pragma unroll
        for (int kq = 0; kq < 16; ++kq) {
            float av[4], bv[4];
            #pragma unroll
            for (int i = 0; i < 4; ++i) av[i] = As[kq][ty * 4 + i];
            #pragma unroll
            for (int j = 0; j < 4; ++j) bv[j] = Bs[kq][tx * 4 + j];
            #pragma unroll
            for (int i = 0; i < 4; ++i)
                #pragma unroll
                for (int j = 0; j < 4; ++j)
                    acc[i][j] = fmaf(av[i], bv[j], acc[i][j]);
        }
        __syncthreads();
    }
    #pragma unroll
    for (int i = 0; i < 4; ++i)
        #pragma unroll
        for (int j = 0; j < 4; ++j)
            Cc[(size_t)(row0 + ty * 4 + i) * N + col0 + tx * 4 + j] = acc[i][j];
}

// depthwise 3x3 SAME conv on x_ssm (first 192 cols of xz) + bias + SiLU -> xc (B,L,C)
__global__ __launch_bounds__(192) void conv_silu(const float* __restrict__ xz,
        const float* __restrict__ cw, const float* __restrict__ cb, float* __restrict__ xc)
{
    const int c = threadIdx.x;
    const int l = blockIdx.x;
    const int b = blockIdx.y;
    const int h = l >> 6, w = l & 63;
    float wg[9];
    #pragma unroll
    for (int i = 0; i < 9; ++i) wg[i] = cw[c * 9 + i];
    float acc = cb[c];
    #pragma unroll
    for (int dh = -1; dh <= 1; ++dh) {
        int hh = h + dh;
        if (hh < 0 || hh >= H_SZ) continue;
        #pragma unroll
        for (int dw = -1; dw <= 1; ++dw) {
            int ww = w + dw;
            if (ww < 0 || ww >= W_SZ) continue;
            acc += xz[((size_t)(b * L_SZ) + hh * W_SZ + ww) * (2 * C_DIM) + c]
                   * wg[(dh + 1) * 3 + (dw + 1)];
        }
    }
    float v = acc * sigmoidf_(acc);
    xc[((size_t)(b * L_SZ) + l) * C_DIM + c] = v;
}

// per (k,b,l-tile of 64): proj = xs @ x_proj_w (44 out), then
// delta = softplus(dpart @ dt_w + 2*dt_b) (dt_b added twice in reference!)
__global__ __launch_bounds__(256) void proj_kernel(const float* __restrict__ xc,
        const float* __restrict__ xpw, const float* __restrict__ dtw,
        const float* __restrict__ dtb,
        float* __restrict__ delta, float* __restrict__ Bm, float* __restrict__ Cm)
{
    __shared__ float ls[64][C_DIM];  // 48 KB
    __shared__ float pj[64][DPROJ];  // 11 KB
    const int l0 = blockIdx.x * 64;
    const int b = blockIdx.y;
    const int k = blockIdx.z;
    const int kb = k * B_SZ + b;
    for (int i = threadIdx.x; i < 64 * C_DIM; i += 256) {
        int ll = i / C_DIM, c = i % C_DIM;
        ls[ll][c] = xc[((size_t)b * L_SZ + scan_map(k, l0 + ll)) * C_DIM + c];
    }
    __syncthreads();
    for (int o = threadIdx.x; o < 64 * DPROJ; o += 256) {
        int ll = o / DPROJ, d = o % DPROJ;
        float s = 0.f;
        const float* wp = xpw + (size_t)k * C_DIM * DPROJ + d;
        #pragma unroll 8
        for (int c = 0; c < C_DIM; ++c) s = fmaf(ls[ll][c], wp[c * DPROJ], s);
        pj[ll][d] = s;
    }
    __syncthreads();
    for (int o = threadIdx.x; o < 64 * C_DIM; o += 256) {
        int ll = o / C_DIM, c = o % C_DIM;
        float s = 2.f * dtb[k * C_DIM + c];
        const float* wp = dtw + (size_t)k * D_RK * C_DIM + c;
        #pragma unroll
        for (int r = 0; r < D_RK; ++r) s = fmaf(pj[ll][r], wp[r * C_DIM], s);
        float sp = (s > 20.f) ? s : log1pf(__expf(s));
        delta[((size_t)kb * L_SZ + l0 + ll) * C_DIM + c] = sp;
    }
    for (int o = threadIdx.x; o < 64 * N_ST; o += 256) {
        int ll = o / N_ST, n = o % N_ST;
        Bm[((size_t)kb * L_SZ + l0 + ll) * N_ST + n] = pj[ll][D_RK + n];
        Cm[((size_t)kb * L_SZ + l0 + ll) * N_ST + n] = pj[ll][D_RK + N_ST + n];
    }
}

// ---- chunked parallel scan, LDS-staged ----
// Block: (c-block of 16, kb, chunk). Stage delta/u/B(/C) tiles to LDS coalesced,
// run recurrence out of LDS. lane = (ci, n): c = c0 + wave*4 + ci, state n.

// S1: chunk summary (Aprod, Bsum)
__global__ __launch_bounds__(256) void scan_part1(const float* __restrict__ delta,
        const float* __restrict__ Bm, const float* __restrict__ xc,
        const float* __restrict__ A_logs,
        float* __restrict__ Aprod, float* __restrict__ Bsum)
{
    __shared__ float d_s[TCHUNK][16];
    __shared__ float u_s[TCHUNK][16];
    __shared__ float B_s[TCHUNK][16];
    const int c0 = blockIdx.x * 16;
    const int kb = blockIdx.y;
    const int k = kb >> 1, b = kb & 1;
    const int ch = blockIdx.z;

    // stage: delta/u rows (64B per row), B contiguous 4KB
    {
        const int tr = threadIdx.x >> 2;      // row 0..63
        const int tq = threadIdx.x & 3;       // float4 within row
        int t = ch * TCHUNK + tr;
        *(float4*)&d_s[tr][tq * 4] =
            *(const float4*)&delta[((size_t)kb * L_SZ + t) * C_DIM + c0 + tq * 4];
        *(float4*)&u_s[tr][tq * 4] =
            *(const float4*)&xc[((size_t)b * L_SZ + scan_map(k, t)) * C_DIM + c0 + tq * 4];
        ((float4*)&B_s[0][0])[threadIdx.x] =
            ((const float4*)(Bm + ((size_t)kb * L_SZ + ch * TCHUNK) * N_ST))[threadIdx.x];
    }
    __syncthreads();

    const int wave = threadIdx.x >> 6;
    const int lane = threadIdx.x & 63;
    const int ci = lane >> 4;
    const int n = lane & 15;
    const int cl = wave * 4 + ci;   // 0..15 within block
    const float A_neg = -__expf(A_logs[((size_t)k * C_DIM + c0 + cl) * N_ST + n]);
    float Ap = 1.f, h = 0.f;
    #pragma unroll 8
    for (int i = 0; i < TCHUNK; ++i) {
        float dlt = d_s[i][cl];
        float u = u_s[i][cl];
        float Bv = B_s[i][n];
        float a = __expf(dlt * A_neg);
        h = fmaf(a, h, dlt * u * Bv);
        Ap *= a;
    }
    size_t o = ((size_t)(ch * K_DIR * B_SZ + kb) * C_DIM + c0 + cl) * N_ST + n;
    Aprod[o] = Ap;
    Bsum[o] = h;
}

// S2: sequential compose over chunks -> exclusive prefix = h_init per chunk.
__global__ __launch_bounds__(256) void scan_part2(const float* __restrict__ Aprod,
        const float* __restrict__ Bsum, float* __restrict__ hinit)
{
    const int kb = blockIdx.y;
    const int wave = threadIdx.x >> 6;
    const int lane = threadIdx.x & 63;
    const int ci = lane >> 4;
    const int n = lane & 15;
    const int c = blockIdx.x * 16 + wave * 4 + ci;
    float h = 0.f;
    #pragma unroll 8
    for (int ch = 0; ch < NCHUNK; ++ch) {
        size_t o = ((size_t)(ch * K_DIR * B_SZ + kb) * C_DIM + c) * N_ST + n;
        hinit[o] = h;
        h = fmaf(Aprod[o], h, Bsum[o]);
    }
}

// S3: re-run each chunk from h_init; y = sum_n h*C (+ Ds*u) -> ys (K,B,L,C)
__global__ __launch_bounds__(256) void scan_part3(const float* __restrict__ delta,
        const float* __restrict__ Bm, const float* __restrict__ Cm,
        const float* __restrict__ xc, const float* __restrict__ A_logs,
        const float* __restrict__ Ds, const float* __restrict__ hinit,
        float* __restrict__ ys)
{
    __shared__ float d_s[TCHUNK][16];
    __shared__ float u_s[TCHUNK][16];
    __shared__ float B_s[TCHUNK][16];
    __shared__ float C_s[TCHUNK][16];
    const int c0 = blockIdx.x * 16;
    const int kb = blockIdx.y;
    const int k = kb >> 1, b = kb & 1;
    const int ch = blockIdx.z;

    {
        const int tr = threadIdx.x >> 2;
        const int tq = threadIdx.x & 3;
        int t = ch * TCHUNK + tr;
        *(float4*)&d_s[tr][tq * 4] =
            *(const float4*)&delta[((size_t)kb * L_SZ + t) * C_DIM + c0 + tq * 4];
        *(float4*)&u_s[tr][tq * 4] =
            *(const float4*)&xc[((size_t)b * L_SZ + scan_map(k, t)) * C_DIM + c0 + tq * 4];
        ((float4*)&B_s[0][0])[threadIdx.x] =
            ((const float4*)(Bm + ((size_t)kb * L_SZ + ch * TCHUNK) * N_ST))[threadIdx.x];
        ((float4*)&C_s[0][0])[threadIdx.x] =
            ((const float4*)(Cm + ((size_t)kb * L_SZ + ch * TCHUNK) * N_ST))[threadIdx.x];
    }
    __syncthreads();

    const int wave = threadIdx.x >> 6;
    const int lane = threadIdx.x & 63;
    const int ci = lane >> 4;
    const int n = lane & 15;
    const int cl = wave * 4 + ci;
    const int c = c0 + cl;
    const float A_neg = -__expf(A_logs[((size_t)k * C_DIM + c) * N_ST + n]);
    const float Dv = Ds[k * C_DIM + c];
    float* yp = ys + ((size_t)kb * L_SZ + ch * TCHUNK) * C_DIM + c;
    float h = hinit[((size_t)(ch * K_DIR * B_SZ + kb) * C_DIM + c) * N_ST + n];
    #pragma unroll 4
    for (int i = 0; i < TCHUNK; ++i) {
        float dlt = d_s[i][cl];
        float u = u_s[i][cl];
        float Bv = B_s[i][n];
        float a = __expf(dlt * A_neg);
        h = fmaf(a, h, dlt * u * Bv);
        float p = h * C_s[i][n];
        p += __shfl_xor(p, 1);
        p += __shfl_xor(p, 2);
        p += __shfl_xor(p, 4);
        p += __shfl_xor(p, 8);
        if (n == 0) yp[(size_t)i * C_DIM] = p + Dv * u;
    }
}

// fused: gather 4 directions + LayerNorm over C + * silu(z). wave per row.
__global__ __launch_bounds__(256) void ln_silu_fused(const float* __restrict__ ys,
        const float* __restrict__ xz, const float* __restrict__ g,
        const float* __restrict__ bb, float* __restrict__ outp)
{
    const int row = blockIdx.x * 4 + (threadIdx.x >> 6);  // b*L + l
    const int lane = threadIdx.x & 63;
    const int b = row >> 12, l = row & (L_SZ - 1);
    const int l2 = ((l & 63) << 6) | (l >> 6);
    const float* r0 = ys + ((size_t)(0 * B_SZ + b) * L_SZ + l) * C_DIM;
    const float* r1 = ys + ((size_t)(1 * B_SZ + b) * L_SZ + (L_SZ - 1 - l)) * C_DIM;
    const float* r2 = ys + ((size_t)(2 * B_SZ + b) * L_SZ + l2) * C_DIM;
    const float* r3 = ys + ((size_t)(3 * B_SZ + b) * L_SZ + (L_SZ - 1 - l2)) * C_DIM;
    float v[3];
    float s = 0.f, s2 = 0.f;
    #pragma unroll
    for (int j = 0; j < 3; ++j) {
        int cc = lane + 64 * j;
        v[j] = r0[cc] + r1[cc] + r2[cc] + r3[cc];
        s += v[j];
        s2 += v[j] * v[j];
    }
    #pragma unroll
    for (int off = 1; off < 64; off <<= 1) {
        s += __shfl_xor(s, off);
        s2 += __shfl_xor(s2, off);
    }
    float mu = s / C_DIM;
    float var = s2 / C_DIM - mu * mu;
    float rstd = rsqrtf(var + 1e-5f);
    #pragma unroll
    for (int j = 0; j < 3; ++j) {
        int cc = lane + 64 * j;
        float zv = xz[(size_t)row * (2 * C_DIM) + C_DIM + cc];
        float t = (v[j] - mu) * rstd * g[cc] + bb[cc];
        outp[(size_t)row * C_DIM + cc] = t * (zv * sigmoidf_(zv));
    }
}

extern "C" void kernel_launch(void* const* d_in, const int* in_sizes, int n_in,
                              void* d_out, int out_size, void* d_ws, size_t ws_size,
                              hipStream_t stream)
{
    const float* x         = (const float*)d_in[0];
    const float* in_proj_w = (const float*)d_in[1];
    const float* conv_w    = (const float*)d_in[2];
    const float* conv_b    = (const float*)d_in[3];
    const float* x_proj_w  = (const float*)d_in[4];
    const float* dt_w      = (const float*)d_in[5];
    const float* dt_b      = (const float*)d_in[6];
    const float* A_logs    = (const float*)d_in[7];
    const float* Ds        = (const float*)d_in[8];
    const float* ln_g      = (const float*)d_in[9];
    const float* ln_b      = (const float*)d_in[10];
    const float* out_w     = (const float*)d_in[11];
    float* out = (float*)d_out;
    float* ws = (float*)d_ws;

    const size_t M = (size_t)B_SZ * L_SZ;  // 8192
    const size_t SUMSZ = (size_t)NCHUNK * K_DIR * B_SZ * C_DIM * N_ST;  // 1.57M

    float* xz    = ws;                              // M*384
    float* xc    = xz + M * 384;                    // M*192
    float* delta = xc + M * C_DIM;                  // K*M*192
    float* Bm    = delta + (size_t)K_DIR * M * C_DIM;
    float* Cm    = Bm + (size_t)K_DIR * M * N_ST;
    float* ys    = Cm + (size_t)K_DIR * M * N_ST;   // K*M*192
    // Aprod/Bsum overlay ys (dead before scan_part3 writes ys)
    float* Aprod = ys;
    float* Bsum  = ys + SUMSZ;
    float* hinit = ys + (size_t)K_DIR * M * C_DIM;  // +6.3MB past ys
    float* tbuf  = delta;                           // reuse after scan

    gemm_f32<<<dim3(M / 64, 384 / 64), 256, 0, stream>>>(x, in_proj_w, xz, (int)M, 2 * C_DIM, C_DIM);
    conv_silu<<<dim3(L_SZ, B_SZ), 192, 0, stream>>>(xz, conv_w, conv_b, xc);
    proj_kernel<<<dim3(L_SZ / 64, B_SZ, K_DIR), 256, 0, stream>>>(xc, x_proj_w, dt_w, dt_b, delta, Bm, Cm);
    scan_part1<<<dim3(C_DIM / 16, K_DIR * B_SZ, NCHUNK), 256, 0, stream>>>(delta, Bm, xc, A_logs, Aprod, Bsum);
    scan_part2<<<dim3(C_DIM / 16, K_DIR * B_SZ), 256, 0, stream>>>(Aprod, Bsum, hinit);
    scan_part3<<<dim3(C_DIM / 16, K_DIR * B_SZ, NCHUNK), 256, 0, stream>>>(delta, Bm, Cm, xc, A_logs, Ds, hinit, ys);
    ln_silu_fused<<<dim3(M / 4), 256, 0, stream>>>(ys, xz, ln_g, ln_b, tbuf);
    gemm_f32<<<dim3(M / 64, C_DIM / 64), 256, 0, stream>>>(tbuf, out_w, out, (int)M, C_DIM, C_DIM);
}

// Round 4
// 257.159 us; speedup vs baseline: 7.6614x; 1.1561x over previous
//
#include <hip/hip_runtime.h>
#include <math.h>

#define C_DIM 192
#define N_ST 16
#define K_DIR 4
#define D_RK 12
#define B_SZ 2
#define H_SZ 64
#define W_SZ 64
#define L_SZ 4096
#define DPROJ 44   // D_RK + 2*N_ST
#define NCHUNK 64
#define TCHUNK 64  // L_SZ / NCHUNK
#define TPAD 68    // TCHUNK + 4 (bank stagger)

__device__ __forceinline__ float sigmoidf_(float x) { return 1.f / (1.f + __expf(-x)); }

// DPP row_ror add: cross-lane sum within 16-lane rows on the VALU pipe (no LDS)
#define DPP_ADD(x, ctrl) ((x) + __builtin_bit_cast(float, \
    __builtin_amdgcn_update_dpp(0, __builtin_bit_cast(int, (x)), (ctrl), 0xf, 0xf, false)))

// scan-order index t -> memory index l in (B,L,C) layout, per direction k
__device__ __forceinline__ int scan_map(int k, int t) {
    int te = (k & 1) ? (L_SZ - 1 - t) : t;
    return (k >= 2) ? (((te & 63) << 6) | (te >> 6)) : te;  // transpose HxW (64x64)
}

// Aprod scratch lives in the dead x_ssm half of xz (cols 0..191 of each 384-row)
__device__ __forceinline__ size_t apr_idx(unsigned o) {
    unsigned r = o / 192u;
    unsigned m = o - r * 192u;
    return (size_t)r * 384u + m;
}

// C = A(MxK) * B(KxN), row-major. Tiles 64x64, K-step 16, thread 4x4.
__global__ __launch_bounds__(256) void gemm_f32(const float* __restrict__ A,
        const float* __restrict__ Bw, float* __restrict__ Cc, int M, int N, int Kd)
{
    __shared__ float As[16][64];
    __shared__ float Bs[16][64];
    const int tx = threadIdx.x & 15, ty = threadIdx.x >> 4;
    const int row0 = blockIdx.x * 64, col0 = blockIdx.y * 64;
    float acc[4][4] = {{0.f}};
    for (int kk = 0; kk < Kd; kk += 16) {
        for (int i = threadIdx.x; i < 1024; i += 256) {
            int m = i >> 4, kq = i & 15;
            As[kq][m] = A[(size_t)(row0 + m) * Kd + kk + kq];
        }
        for (int i = threadIdx.x; i < 1024; i += 256) {
            int kq = i >> 6, nn = i & 63;
            Bs[kq][nn] = Bw[(size_t)(kk + kq) * N + col0 + nn];
        }
        __syncthreads();
        #pragma unroll
        for (int kq = 0; kq < 16; ++kq) {
            float av[4], bv[4];
            #pragma unroll
            for (int i = 0; i < 4; ++i) av[i] = As[kq][ty * 4 + i];
            #pragma unroll
            for (int j = 0; j < 4; ++j) bv[j] = Bs[kq][tx * 4 + j];
            #pragma unroll
            for (int i = 0; i < 4; ++i)
                #pragma unroll
                for (int j = 0; j < 4; ++j)
                    acc[i][j] = fmaf(av[i], bv[j], acc[i][j]);
        }
        __syncthreads();
    }
    #pragma unroll
    for (int i = 0; i < 4; ++i)
        #pragma unroll
        for (int j = 0; j < 4; ++j)
            Cc[(size_t)(row0 + ty * 4 + i) * N + col0 + tx * 4 + j] = acc[i][j];
}

// depthwise 3x3 SAME conv + bias + SiLU -> xc (B,L,C). Sliding-window over w.
__global__ __launch_bounds__(192) void conv_silu(const float* __restrict__ xz,
        const float* __restrict__ cw, const float* __restrict__ cb, float* __restrict__ xc)
{
    const int c = threadIdx.x;
    const int h = blockIdx.x;
    const int w0 = blockIdx.y * 32;
    const int b = blockIdx.z;
    float wg[9];
    #pragma unroll
    for (int i = 0; i < 9; ++i) wg[i] = cw[c * 9 + i];
    const float* base = xz + ((size_t)b * L_SZ + (size_t)h * W_SZ) * (2 * C_DIM) + c;
    const bool hm = (h > 0), hp = (h < H_SZ - 1);
    const int RS = W_SZ * 2 * C_DIM;  // 24576
    float cL[3], cC[3], cR[3];
    #define LDCOL(w, dst) { \
        int off_ = (w) * (2 * C_DIM); \
        dst[0] = hm ? base[off_ - RS] : 0.f; \
        dst[1] = base[off_]; \
        dst[2] = hp ? base[off_ + RS] : 0.f; }
    if (w0 > 0) { LDCOL(w0 - 1, cL) } else { cL[0] = cL[1] = cL[2] = 0.f; }
    LDCOL(w0, cC)
    const float bias = cb[c];
    for (int w = w0; w < w0 + 32; ++w) {
        if (w < W_SZ - 1) { LDCOL(w + 1, cR) } else { cR[0] = cR[1] = cR[2] = 0.f; }
        float acc = bias;
        #pragma unroll
        for (int r = 0; r < 3; ++r)
            acc += cL[r] * wg[r * 3] + cC[r] * wg[r * 3 + 1] + cR[r] * wg[r * 3 + 2];
        float v = acc * sigmoidf_(acc);
        xc[((size_t)b * L_SZ + h * W_SZ + w) * C_DIM + c] = v;
        cL[0] = cC[0]; cL[1] = cC[1]; cL[2] = cC[2];
        cC[0] = cR[0]; cC[1] = cR[1]; cC[2] = cR[2];
    }
    #undef LDCOL
}

// per (k,b,l-tile of 64): proj = xs @ x_proj_w, delta = softplus(dpart@dt_w + 2*dt_b),
// du = delta * u  (so scan kernels never gather xc)
__global__ __launch_bounds__(256) void proj_kernel(const float* __restrict__ xc,
        const float* __restrict__ xpw, const float* __restrict__ dtw,
        const float* __restrict__ dtb,
        float* __restrict__ delta, float* __restrict__ du,
        float* __restrict__ Bm, float* __restrict__ Cm)
{
    __shared__ float ls[64][C_DIM];  // 48 KB
    __shared__ float pj[64][DPROJ];  // 11 KB
    const int l0 = blockIdx.x * 64;
    const int b = blockIdx.y;
    const int k = blockIdx.z;
    const int kb = k * B_SZ + b;
    for (int i = threadIdx.x; i < 64 * C_DIM; i += 256) {
        int ll = i / C_DIM, c = i % C_DIM;
        ls[ll][c] = xc[((size_t)b * L_SZ + scan_map(k, l0 + ll)) * C_DIM + c];
    }
    __syncthreads();
    for (int o = threadIdx.x; o < 64 * DPROJ; o += 256) {
        int ll = o / DPROJ, d = o % DPROJ;
        float s = 0.f;
        const float* wp = xpw + (size_t)k * C_DIM * DPROJ + d;
        #pragma unroll 8
        for (int c = 0; c < C_DIM; ++c) s = fmaf(ls[ll][c], wp[c * DPROJ], s);
        pj[ll][d] = s;
    }
    __syncthreads();
    for (int o = threadIdx.x; o < 64 * C_DIM; o += 256) {
        int ll = o / C_DIM, c = o % C_DIM;
        float s = 2.f * dtb[k * C_DIM + c];
        const float* wp = dtw + (size_t)k * D_RK * C_DIM + c;
        #pragma unroll
        for (int r = 0; r < D_RK; ++r) s = fmaf(pj[ll][r], wp[r * C_DIM], s);
        float sp = (s > 20.f) ? s : log1pf(__expf(s));
        size_t oi = ((size_t)kb * L_SZ + l0 + ll) * C_DIM + c;
        delta[oi] = sp;
        du[oi] = sp * ls[ll][c];
    }
    for (int o = threadIdx.x; o < 64 * N_ST; o += 256) {
        int ll = o / N_ST, n = o % N_ST;
        Bm[((size_t)kb * L_SZ + l0 + ll) * N_ST + n] = pj[ll][D_RK + n];
        Cm[((size_t)kb * L_SZ + l0 + ll) * N_ST + n] = pj[ll][D_RK + N_ST + n];
    }
}

// ---- staging helpers: transpose 64x16 global tile into [16][TPAD] LDS ----
#define STAGE_CTILE(dst, src_base) { \
    const int tr_ = threadIdx.x >> 2; \
    const int tq_ = threadIdx.x & 3; \
    const float4 v_ = *(const float4*)&(src_base)[(size_t)tr_ * C_DIM + tq_ * 4]; \
    dst[tq_ * 4 + 0][tr_] = v_.x; dst[tq_ * 4 + 1][tr_] = v_.y; \
    dst[tq_ * 4 + 2][tr_] = v_.z; dst[tq_ * 4 + 3][tr_] = v_.w; }

#define STAGE_NTILE(dst, src_base) { \
    const int t_ = threadIdx.x >> 2; \
    const int nb_ = (threadIdx.x & 3) * 4; \
    const float4 v_ = *(const float4*)&(src_base)[t_ * N_ST + nb_]; \
    dst[nb_ + 0][t_] = v_.x; dst[nb_ + 1][t_] = v_.y; \
    dst[nb_ + 2][t_] = v_.z; dst[nb_ + 3][t_] = v_.w; }

// S1: chunk summary. Aprod -> dead-xz scratch, Bsum -> hb.
__global__ __launch_bounds__(256) void scan_part1(const float* __restrict__ delta,
        const float* __restrict__ du, const float* __restrict__ Bm,
        const float* __restrict__ A_logs,
        float* __restrict__ Apr, float* __restrict__ hb)
{
    __shared__ float d_s[16][TPAD];
    __shared__ float q_s[16][TPAD];
    __shared__ float B_s[16][TPAD];
    const int c0 = blockIdx.x * 16;
    const int kb = blockIdx.y;
    const int k = kb >> 1;
    const int ch = blockIdx.z;
    const size_t tbase = ((size_t)kb * L_SZ + ch * TCHUNK) * C_DIM + c0;
    STAGE_CTILE(d_s, delta + tbase)
    STAGE_CTILE(q_s, du + tbase)
    STAGE_NTILE(B_s, Bm + ((size_t)kb * L_SZ + ch * TCHUNK) * N_ST)
    __syncthreads();

    const int wave = threadIdx.x >> 6;
    const int lane = threadIdx.x & 63;
    const int ci = lane >> 4;
    const int n = lane & 15;
    const int cl = wave * 4 + ci;
    const float A_neg = -__expf(A_logs[((size_t)k * C_DIM + c0 + cl) * N_ST + n]);
    float h = 0.f, dsum = 0.f;
    #pragma unroll 4
    for (int i4 = 0; i4 < TCHUNK; i4 += 4) {
        const float4 d4 = *(const float4*)&d_s[cl][i4];
        const float4 q4 = *(const float4*)&q_s[cl][i4];
        const float4 B4 = *(const float4*)&B_s[n][i4];
        #define S1STEP(dd, qq, BB) { \
            float a_ = __expf((dd) * A_neg); \
            h = fmaf(a_, h, (qq) * (BB)); \
            dsum += (dd); }
        S1STEP(d4.x, q4.x, B4.x) S1STEP(d4.y, q4.y, B4.y)
        S1STEP(d4.z, q4.z, B4.z) S1STEP(d4.w, q4.w, B4.w)
        #undef S1STEP
    }
    unsigned o = ((unsigned)(ch * K_DIR * B_SZ + kb) * C_DIM + c0 + cl) * N_ST + n;
    Apr[apr_idx(o)] = __expf(dsum * A_neg);
    hb[o] = h;
}

// S2: sequential compose over chunks; hb: reads Bsum, writes hinit (same buffer).
__global__ __launch_bounds__(256) void scan_part2(const float* __restrict__ Apr,
        float* hb)
{
    const int kb = blockIdx.y;
    const int wave = threadIdx.x >> 6;
    const int lane = threadIdx.x & 63;
    const int ci = lane >> 4;
    const int n = lane & 15;
    const int c = blockIdx.x * 16 + wave * 4 + ci;
    float h = 0.f;
    #pragma unroll 8
    for (int ch = 0; ch < NCHUNK; ++ch) {
        unsigned o = ((unsigned)(ch * K_DIR * B_SZ + kb) * C_DIM + c) * N_ST + n;
        float Ap = Apr[apr_idx(o)];
        float Bs = hb[o];
        hb[o] = h;                 // hinit (exclusive prefix)
        h = fmaf(Ap, h, Bs);
    }
}

// S3: re-run chunk from hinit; y = sum_n h*C -> overwrite du tile (ys).
__global__ __launch_bounds__(256) void scan_part3(const float* __restrict__ delta,
        float* duys, const float* __restrict__ Bm, const float* __restrict__ Cm,
        const float* __restrict__ A_logs, const float* __restrict__ hb)
{
    __shared__ float d_s[16][TPAD];
    __shared__ float q_s[16][TPAD];
    __shared__ float B_s[16][TPAD];
    __shared__ float C_s[16][TPAD];
    const int c0 = blockIdx.x * 16;
    const int kb = blockIdx.y;
    const int k = kb >> 1;
    const int ch = blockIdx.z;
    const size_t tbase = ((size_t)kb * L_SZ + ch * TCHUNK) * C_DIM + c0;
    STAGE_CTILE(d_s, delta + tbase)
    STAGE_CTILE(q_s, duys + tbase)   // read du tile (will be overwritten below)
    STAGE_NTILE(B_s, Bm + ((size_t)kb * L_SZ + ch * TCHUNK) * N_ST)
    STAGE_NTILE(C_s, Cm + ((size_t)kb * L_SZ + ch * TCHUNK) * N_ST)
    __syncthreads();

    const int wave = threadIdx.x >> 6;
    const int lane = threadIdx.x & 63;
    const int ci = lane >> 4;
    const int n = lane & 15;
    const int cl = wave * 4 + ci;
    const float A_neg = -__expf(A_logs[((size_t)k * C_DIM + c0 + cl) * N_ST + n]);
    float* yp = duys + tbase + cl;
    float h = hb[((unsigned)(ch * K_DIR * B_SZ + kb) * C_DIM + c0 + cl) * N_ST + n];
    #pragma unroll 4
    for (int i4 = 0; i4 < TCHUNK; i4 += 4) {
        const float4 d4 = *(const float4*)&d_s[cl][i4];
        const float4 q4 = *(const float4*)&q_s[cl][i4];
        const float4 B4 = *(const float4*)&B_s[n][i4];
        const float4 C4 = *(const float4*)&C_s[n][i4];
        #define S3STEP(dd, qq, BB, CC, ii) { \
            float a_ = __expf((dd) * A_neg); \
            h = fmaf(a_, h, (qq) * (BB)); \
            float p_ = h * (CC); \
            p_ = DPP_ADD(p_, 0x128); p_ = DPP_ADD(p_, 0x124); \
            p_ = DPP_ADD(p_, 0x122); p_ = DPP_ADD(p_, 0x121); \
            if (n == 0) yp[(size_t)(i4 + (ii)) * C_DIM] = p_; }
        S3STEP(d4.x, q4.x, B4.x, C4.x, 0) S3STEP(d4.y, q4.y, B4.y, C4.y, 1)
        S3STEP(d4.z, q4.z, B4.z, C4.z, 2) S3STEP(d4.w, q4.w, B4.w, C4.w, 3)
        #undef S3STEP
    }
}

// fused: gather 4 directions + (sum_k Ds)*xc + LayerNorm + *silu(z). wave per row.
__global__ __launch_bounds__(256) void ln_silu_fused(const float* __restrict__ ys,
        const float* __restrict__ xz, const float* __restrict__ xc,
        const float* __restrict__ Dsv, const float* __restrict__ g,
        const float* __restrict__ bb, float* __restrict__ outp)
{
    const int row = blockIdx.x * 4 + (threadIdx.x >> 6);  // b*L + l
    const int lane = threadIdx.x & 63;
    const int b = row >> 12, l = row & (L_SZ - 1);
    const int l2 = ((l & 63) << 6) | (l >> 6);
    const float* r0 = ys + ((size_t)(0 * B_SZ + b) * L_SZ + l) * C_DIM;
    const float* r1 = ys + ((size_t)(1 * B_SZ + b) * L_SZ + (L_SZ - 1 - l)) * C_DIM;
    const float* r2 = ys + ((size_t)(2 * B_SZ + b) * L_SZ + l2) * C_DIM;
    const float* r3 = ys + ((size_t)(3 * B_SZ + b) * L_SZ + (L_SZ - 1 - l2)) * C_DIM;
    float v[3];
    float s = 0.f, s2 = 0.f;
    #pragma unroll
    for (int j = 0; j < 3; ++j) {
        int cc = lane + 64 * j;
        float ds4 = Dsv[cc] + Dsv[C_DIM + cc] + Dsv[2 * C_DIM + cc] + Dsv[3 * C_DIM + cc];
        v[j] = r0[cc] + r1[cc] + r2[cc] + r3[cc]
             + ds4 * xc[(size_t)row * C_DIM + cc];
        s += v[j];
        s2 += v[j] * v[j];
    }
    #pragma unroll
    for (int off = 1; off < 64; off <<= 1) {
        s += __shfl_xor(s, off);
        s2 += __shfl_xor(s2, off);
    }
    float mu = s / C_DIM;
    float var = s2 / C_DIM - mu * mu;
    float rstd = rsqrtf(var + 1e-5f);
    #pragma unroll
    for (int j = 0; j < 3; ++j) {
        int cc = lane + 64 * j;
        float zv = xz[(size_t)row * (2 * C_DIM) + C_DIM + cc];
        float t = (v[j] - mu) * rstd * g[cc] + bb[cc];
        outp[(size_t)row * C_DIM + cc] = t * (zv * sigmoidf_(zv));
    }
}

extern "C" void kernel_launch(void* const* d_in, const int* in_sizes, int n_in,
                              void* d_out, int out_size, void* d_ws, size_t ws_size,
                              hipStream_t stream)
{
    const float* x         = (const float*)d_in[0];
    const float* in_proj_w = (const float*)d_in[1];
    const float* conv_w    = (const float*)d_in[2];
    const float* conv_b    = (const float*)d_in[3];
    const float* x_proj_w  = (const float*)d_in[4];
    const float* dt_w      = (const float*)d_in[5];
    const float* dt_b      = (const float*)d_in[6];
    const float* A_logs    = (const float*)d_in[7];
    const float* Ds        = (const float*)d_in[8];
    const float* ln_g      = (const float*)d_in[9];
    const float* ln_b      = (const float*)d_in[10];
    const float* out_w     = (const float*)d_in[11];
    float* out = (float*)d_out;
    float* ws = (float*)d_ws;

    const size_t M = (size_t)B_SZ * L_SZ;          // 8192
    const size_t KM = (size_t)K_DIR * M;           // 32768

    float* xz    = ws;                       // M*384  (first half dead after conv -> Aprod scratch)
    float* xc    = xz + M * 384;             // M*192
    float* delta = xc + M * C_DIM;           // KM*192
    float* duys  = delta + KM * C_DIM;       // KM*192 : du, then ys in-place
    float* Bm    = duys + KM * C_DIM;        // KM*16
    float* Cm    = Bm + KM * N_ST;           // KM*16
    float* hb    = Cm + KM * N_ST;           // NCHUNK*8*192*16 : Bsum then hinit
    float* tbuf  = delta;                    // reuse after scan

    gemm_f32<<<dim3(M / 64, 384 / 64), 256, 0, stream>>>(x, in_proj_w, xz, (int)M, 2 * C_DIM, C_DIM);
    conv_silu<<<dim3(H_SZ, 2, B_SZ), 192, 0, stream>>>(xz, conv_w, conv_b, xc);
    proj_kernel<<<dim3(L_SZ / 64, B_SZ, K_DIR), 256, 0, stream>>>(xc, x_proj_w, dt_w, dt_b, delta, duys, Bm, Cm);
    scan_part1<<<dim3(C_DIM / 16, K_DIR * B_SZ, NCHUNK), 256, 0, stream>>>(delta, duys, Bm, A_logs, xz, hb);
    scan_part2<<<dim3(C_DIM / 16, K_DIR * B_SZ), 256, 0, stream>>>(xz, hb);
    scan_part3<<<dim3(C_DIM / 16, K_DIR * B_SZ, NCHUNK), 256, 0, stream>>>(delta, duys, Bm, Cm, A_logs, hb);
    ln_silu_fused<<<dim3(M / 4), 256, 0, stream>>>(duys, xz, xc, Ds, ln_g, ln_b, tbuf);
    gemm_f32<<<dim3(M / 64, C_DIM / 64), 256, 0, stream>>>(tbuf, out_w, out, (int)M, C_DIM, C_DIM);
}

// Round 5
// 237.332 us; speedup vs baseline: 8.3015x; 1.0835x over previous
//
#include <hip/hip_runtime.h>
#include <math.h>

#define C_DIM 192
#define N_ST 16
#define K_DIR 4
#define D_RK 12
#define B_SZ 2
#define H_SZ 64
#define W_SZ 64
#define L_SZ 4096
#define DPROJ 44   // D_RK + 2*N_ST
#define NPADJ 48   // DPROJ padded
#define NCHUNK 64
#define TCHUNK 64  // L_SZ / NCHUNK
#define TPAD 68    // TCHUNK + 4 (bank stagger)

__device__ __forceinline__ float sigmoidf_(float x) { return 1.f / (1.f + __expf(-x)); }

// DPP row_ror add: cross-lane sum within 16-lane rows on the VALU pipe (no LDS)
#define DPP_ADD(x, ctrl) ((x) + __builtin_bit_cast(float, \
    __builtin_amdgcn_update_dpp(0, __builtin_bit_cast(int, (x)), (ctrl), 0xf, 0xf, false)))

// scan-order index t -> memory index l in (B,L,C) layout, per direction k
__device__ __forceinline__ int scan_map(int k, int t) {
    int te = (k & 1) ? (L_SZ - 1 - t) : t;
    return (k >= 2) ? (((te & 63) << 6) | (te >> 6)) : te;  // transpose HxW (64x64)
}

// Aprod scratch lives in the dead x_ssm half of xz (cols 0..191 of each 384-row)
__device__ __forceinline__ size_t apr_idx(unsigned o) {
    unsigned r = o / 192u;
    unsigned m = o - r * 192u;
    return (size_t)r * 384u + m;
}

// C = A(MxK) * B(KxN), row-major. Tiles 64x64, K-step 16, thread 4x4.
__global__ __launch_bounds__(256) void gemm_f32(const float* __restrict__ A,
        const float* __restrict__ Bw, float* __restrict__ Cc, int M, int N, int Kd)
{
    __shared__ float As[16][64];
    __shared__ float Bs[16][64];
    const int tx = threadIdx.x & 15, ty = threadIdx.x >> 4;
    const int row0 = blockIdx.x * 64, col0 = blockIdx.y * 64;
    float acc[4][4] = {{0.f}};
    for (int kk = 0; kk < Kd; kk += 16) {
        for (int i = threadIdx.x; i < 1024; i += 256) {
            int m = i >> 4, kq = i & 15;
            As[kq][m] = A[(size_t)(row0 + m) * Kd + kk + kq];
        }
        for (int i = threadIdx.x; i < 1024; i += 256) {
            int kq = i >> 6, nn = i & 63;
            Bs[kq][nn] = Bw[(size_t)(kk + kq) * N + col0 + nn];
        }
        __syncthreads();
        #pragma unroll
        for (int kq = 0; kq < 16; ++kq) {
            float av[4], bv[4];
            #pragma unroll
            for (int i = 0; i < 4; ++i) av[i] = As[kq][ty * 4 + i];
            #pragma unroll
            for (int j = 0; j < 4; ++j) bv[j] = Bs[kq][tx * 4 + j];
            #pragma unroll
            for (int i = 0; i < 4; ++i)
                #pragma unroll
                for (int j = 0; j < 4; ++j)
                    acc[i][j] = fmaf(av[i], bv[j], acc[i][j]);
        }
        __syncthreads();
    }
    #pragma unroll
    for (int i = 0; i < 4; ++i)
        #pragma unroll
        for (int j = 0; j < 4; ++j)
            Cc[(size_t)(row0 + ty * 4 + i) * N + col0 + tx * 4 + j] = acc[i][j];
}

// depthwise 3x3 SAME conv + bias + SiLU -> xc (B,L,C). Sliding-window over w.
__global__ __launch_bounds__(192) void conv_silu(const float* __restrict__ xz,
        const float* __restrict__ cw, const float* __restrict__ cb, float* __restrict__ xc)
{
    const int c = threadIdx.x;
    const int h = blockIdx.x;
    const int w0 = blockIdx.y * 32;
    const int b = blockIdx.z;
    float wg[9];
    #pragma unroll
    for (int i = 0; i < 9; ++i) wg[i] = cw[c * 9 + i];
    const float* base = xz + ((size_t)b * L_SZ + (size_t)h * W_SZ) * (2 * C_DIM) + c;
    const bool hm = (h > 0), hp = (h < H_SZ - 1);
    const int RS = W_SZ * 2 * C_DIM;  // 24576
    float cL[3], cC[3], cR[3];
    #define LDCOL(w, dst) { \
        int off_ = (w) * (2 * C_DIM); \
        dst[0] = hm ? base[off_ - RS] : 0.f; \
        dst[1] = base[off_]; \
        dst[2] = hp ? base[off_ + RS] : 0.f; }
    if (w0 > 0) { LDCOL(w0 - 1, cL) } else { cL[0] = cL[1] = cL[2] = 0.f; }
    LDCOL(w0, cC)
    const float bias = cb[c];
    for (int w = w0; w < w0 + 32; ++w) {
        if (w < W_SZ - 1) { LDCOL(w + 1, cR) } else { cR[0] = cR[1] = cR[2] = 0.f; }
        float acc = bias;
        #pragma unroll
        for (int r = 0; r < 3; ++r)
            acc += cL[r] * wg[r * 3] + cC[r] * wg[r * 3 + 1] + cR[r] * wg[r * 3 + 2];
        float v = acc * sigmoidf_(acc);
        xc[((size_t)b * L_SZ + h * W_SZ + w) * C_DIM + c] = v;
        cL[0] = cC[0]; cL[1] = cC[1]; cL[2] = cC[2];
        cC[0] = cR[0]; cC[1] = cR[1]; cC[2] = cR[2];
    }
    #undef LDCOL
}

// per (k,b,l-tile of 64): register-tiled LDS GEMM for proj (64x48 tile, K=192
// in chunks of 32), then delta = softplus(dpart@dt_w + 2*dt_b), du = delta*u.
// No in-loop VMEM: A-tile, W-tile, dt_w all staged in LDS.
__global__ __launch_bounds__(256) void proj_kernel(const float* __restrict__ xc,
        const float* __restrict__ xpw, const float* __restrict__ dtw,
        const float* __restrict__ dtb,
        float* __restrict__ delta, float* __restrict__ du,
        float* __restrict__ Bm, float* __restrict__ Cm)
{
    __shared__ float As[32][68];       // [k][row] transposed, padded
    __shared__ float Ws[32][NPADJ];    // [k][d], cols 44..47 zero
    __shared__ float pj[64][NPADJ];    // proj outputs
    __shared__ float Dw[D_RK * C_DIM]; // dt_w[k] flat (9 KB)
    const int l0 = blockIdx.x * 64;
    const int b = blockIdx.y;
    const int k = blockIdx.z;
    const int kb = k * B_SZ + b;
    const int ty = threadIdx.x >> 4;   // 0..15 -> rows ty*4..+3
    const int tx = threadIdx.x & 15;   // 0..15 -> cols tx*3..+2

    // stage dt_w (flat copy) + zero W pad cols
    for (int i = threadIdx.x; i < D_RK * C_DIM; i += 256)
        Dw[i] = dtw[(size_t)k * D_RK * C_DIM + i];
    if (threadIdx.x < 128)
        Ws[threadIdx.x >> 2][44 + (threadIdx.x & 3)] = 0.f;

    const int srow = threadIdx.x >> 2;        // 0..63
    const int skq  = (threadIdx.x & 3) * 8;   // 0,8,16,24
    const size_t xrow = ((size_t)b * L_SZ + scan_map(k, l0 + srow)) * C_DIM;
    const float* wbase = xpw + (size_t)k * C_DIM * DPROJ;

    float acc[4][3] = {{0.f}};
    for (int kk = 0; kk < C_DIM; kk += 32) {
        float4 a0 = *(const float4*)&xc[xrow + kk + skq];
        float4 a1 = *(const float4*)&xc[xrow + kk + skq + 4];
        As[skq + 0][srow] = a0.x; As[skq + 1][srow] = a0.y;
        As[skq + 2][srow] = a0.z; As[skq + 3][srow] = a0.w;
        As[skq + 4][srow] = a1.x; As[skq + 5][srow] = a1.y;
        As[skq + 6][srow] = a1.z; As[skq + 7][srow] = a1.w;
        for (int i = threadIdx.x; i < 32 * DPROJ; i += 256) {
            int kq = i / DPROJ, d = i - kq * DPROJ;
            Ws[kq][d] = wbase[(size_t)(kk + kq) * DPROJ + d];
        }
        __syncthreads();
        #pragma unroll
        for (int kq = 0; kq < 32; ++kq) {
            float4 av = *(const float4*)&As[kq][ty * 4];
            float b0 = Ws[kq][tx * 3], b1 = Ws[kq][tx * 3 + 1], b2 = Ws[kq][tx * 3 + 2];
            acc[0][0] = fmaf(av.x, b0, acc[0][0]); acc[0][1] = fmaf(av.x, b1, acc[0][1]); acc[0][2] = fmaf(av.x, b2, acc[0][2]);
            acc[1][0] = fmaf(av.y, b0, acc[1][0]); acc[1][1] = fmaf(av.y, b1, acc[1][1]); acc[1][2] = fmaf(av.y, b2, acc[1][2]);
            acc[2][0] = fmaf(av.z, b0, acc[2][0]); acc[2][1] = fmaf(av.z, b1, acc[2][1]); acc[2][2] = fmaf(av.z, b2, acc[2][2]);
            acc[3][0] = fmaf(av.w, b0, acc[3][0]); acc[3][1] = fmaf(av.w, b1, acc[3][1]); acc[3][2] = fmaf(av.w, b2, acc[3][2]);
        }
        __syncthreads();
    }
    #pragma unroll
    for (int i = 0; i < 4; ++i)
        #pragma unroll
        for (int j = 0; j < 3; ++j)
            pj[ty * 4 + i][tx * 3 + j] = acc[i][j];
    __syncthreads();

    // delta = softplus(dpart @ dt_w + 2*dt_b); du = delta * u (u re-gathered)
    for (int o = threadIdx.x; o < 64 * C_DIM; o += 256) {
        int ll = o / C_DIM, c = o - ll * C_DIM;
        float s = 2.f * dtb[k * C_DIM + c];
        #pragma unroll
        for (int r = 0; r < D_RK; ++r) s = fmaf(pj[ll][r], Dw[r * C_DIM + c], s);
        float sp = (s > 20.f) ? s : log1pf(__expf(s));
        size_t oi = ((size_t)kb * L_SZ + l0 + ll) * C_DIM + c;
        delta[oi] = sp;
        float u = xc[((size_t)b * L_SZ + scan_map(k, l0 + ll)) * C_DIM + c];
        du[oi] = sp * u;
    }
    for (int o = threadIdx.x; o < 64 * N_ST; o += 256) {
        int ll = o / N_ST, n = o & 15;
        Bm[((size_t)kb * L_SZ + l0 + ll) * N_ST + n] = pj[ll][D_RK + n];
        Cm[((size_t)kb * L_SZ + l0 + ll) * N_ST + n] = pj[ll][D_RK + N_ST + n];
    }
}

// ---- staging helpers: transpose 64x16 global tile into [16][TPAD] LDS ----
#define STAGE_CTILE(dst, src_base) { \
    const int tr_ = threadIdx.x >> 2; \
    const int tq_ = threadIdx.x & 3; \
    const float4 v_ = *(const float4*)&(src_base)[(size_t)tr_ * C_DIM + tq_ * 4]; \
    dst[tq_ * 4 + 0][tr_] = v_.x; dst[tq_ * 4 + 1][tr_] = v_.y; \
    dst[tq_ * 4 + 2][tr_] = v_.z; dst[tq_ * 4 + 3][tr_] = v_.w; }

#define STAGE_NTILE(dst, src_base) { \
    const int t_ = threadIdx.x >> 2; \
    const int nb_ = (threadIdx.x & 3) * 4; \
    const float4 v_ = *(const float4*)&(src_base)[t_ * N_ST + nb_]; \
    dst[nb_ + 0][t_] = v_.x; dst[nb_ + 1][t_] = v_.y; \
    dst[nb_ + 2][t_] = v_.z; dst[nb_ + 3][t_] = v_.w; }

// S1: chunk summary. Aprod -> dead-xz scratch, Bsum -> hb.
__global__ __launch_bounds__(256) void scan_part1(const float* __restrict__ delta,
        const float* __restrict__ du, const float* __restrict__ Bm,
        const float* __restrict__ A_logs,
        float* __restrict__ Apr, float* __restrict__ hb)
{
    __shared__ float d_s[16][TPAD];
    __shared__ float q_s[16][TPAD];
    __shared__ float B_s[16][TPAD];
    const int c0 = blockIdx.x * 16;
    const int kb = blockIdx.y;
    const int k = kb >> 1;
    const int ch = blockIdx.z;
    const size_t tbase = ((size_t)kb * L_SZ + ch * TCHUNK) * C_DIM + c0;
    STAGE_CTILE(d_s, delta + tbase)
    STAGE_CTILE(q_s, du + tbase)
    STAGE_NTILE(B_s, Bm + ((size_t)kb * L_SZ + ch * TCHUNK) * N_ST)
    __syncthreads();

    const int wave = threadIdx.x >> 6;
    const int lane = threadIdx.x & 63;
    const int ci = lane >> 4;
    const int n = lane & 15;
    const int cl = wave * 4 + ci;
    const float A_neg = -__expf(A_logs[((size_t)k * C_DIM + c0 + cl) * N_ST + n]);
    float h = 0.f, dsum = 0.f;
    #pragma unroll 4
    for (int i4 = 0; i4 < TCHUNK; i4 += 4) {
        const float4 d4 = *(const float4*)&d_s[cl][i4];
        const float4 q4 = *(const float4*)&q_s[cl][i4];
        const float4 B4 = *(const float4*)&B_s[n][i4];
        #define S1STEP(dd, qq, BB) { \
            float a_ = __expf((dd) * A_neg); \
            h = fmaf(a_, h, (qq) * (BB)); \
            dsum += (dd); }
        S1STEP(d4.x, q4.x, B4.x) S1STEP(d4.y, q4.y, B4.y)
        S1STEP(d4.z, q4.z, B4.z) S1STEP(d4.w, q4.w, B4.w)
        #undef S1STEP
    }
    unsigned o = ((unsigned)(ch * K_DIR * B_SZ + kb) * C_DIM + c0 + cl) * N_ST + n;
    Apr[apr_idx(o)] = __expf(dsum * A_neg);
    hb[o] = h;
}

// S2: sequential compose over chunks; hb: reads Bsum, writes hinit (same buffer).
__global__ __launch_bounds__(256) void scan_part2(const float* __restrict__ Apr,
        float* hb)
{
    const int kb = blockIdx.y;
    const int wave = threadIdx.x >> 6;
    const int lane = threadIdx.x & 63;
    const int ci = lane >> 4;
    const int n = lane & 15;
    const int c = blockIdx.x * 16 + wave * 4 + ci;
    float h = 0.f;
    #pragma unroll 8
    for (int ch = 0; ch < NCHUNK; ++ch) {
        unsigned o = ((unsigned)(ch * K_DIR * B_SZ + kb) * C_DIM + c) * N_ST + n;
        float Ap = Apr[apr_idx(o)];
        float Bs = hb[o];
        hb[o] = h;                 // hinit (exclusive prefix)
        h = fmaf(Ap, h, Bs);
    }
}

// S3: re-run chunk from hinit; y = sum_n h*C -> overwrite du tile (ys).
__global__ __launch_bounds__(256) void scan_part3(const float* __restrict__ delta,
        float* duys, const float* __restrict__ Bm, const float* __restrict__ Cm,
        const float* __restrict__ A_logs, const float* __restrict__ hb)
{
    __shared__ float d_s[16][TPAD];
    __shared__ float q_s[16][TPAD];
    __shared__ float B_s[16][TPAD];
    __shared__ float C_s[16][TPAD];
    const int c0 = blockIdx.x * 16;
    const int kb = blockIdx.y;
    const int k = kb >> 1;
    const int ch = blockIdx.z;
    const size_t tbase = ((size_t)kb * L_SZ + ch * TCHUNK) * C_DIM + c0;
    STAGE_CTILE(d_s, delta + tbase)
    STAGE_CTILE(q_s, duys + tbase)   // read du tile (will be overwritten below)
    STAGE_NTILE(B_s, Bm + ((size_t)kb * L_SZ + ch * TCHUNK) * N_ST)
    STAGE_NTILE(C_s, Cm + ((size_t)kb * L_SZ + ch * TCHUNK) * N_ST)
    __syncthreads();

    const int wave = threadIdx.x >> 6;
    const int lane = threadIdx.x & 63;
    const int ci = lane >> 4;
    const int n = lane & 15;
    const int cl = wave * 4 + ci;
    const float A_neg = -__expf(A_logs[((size_t)k * C_DIM + c0 + cl) * N_ST + n]);
    float* yp = duys + tbase + cl;
    float h = hb[((unsigned)(ch * K_DIR * B_SZ + kb) * C_DIM + c0 + cl) * N_ST + n];
    #pragma unroll 4
    for (int i4 = 0; i4 < TCHUNK; i4 += 4) {
        const float4 d4 = *(const float4*)&d_s[cl][i4];
        const float4 q4 = *(const float4*)&q_s[cl][i4];
        const float4 B4 = *(const float4*)&B_s[n][i4];
        const float4 C4 = *(const float4*)&C_s[n][i4];
        #define S3STEP(dd, qq, BB, CC, ii) { \
            float a_ = __expf((dd) * A_neg); \
            h = fmaf(a_, h, (qq) * (BB)); \
            float p_ = h * (CC); \
            p_ = DPP_ADD(p_, 0x128); p_ = DPP_ADD(p_, 0x124); \
            p_ = DPP_ADD(p_, 0x122); p_ = DPP_ADD(p_, 0x121); \
            if (n == 0) yp[(size_t)(i4 + (ii)) * C_DIM] = p_; }
        S3STEP(d4.x, q4.x, B4.x, C4.x, 0) S3STEP(d4.y, q4.y, B4.y, C4.y, 1)
        S3STEP(d4.z, q4.z, B4.z, C4.z, 2) S3STEP(d4.w, q4.w, B4.w, C4.w, 3)
        #undef S3STEP
    }
}

// fused: gather 4 directions + (sum_k Ds)*xc + LayerNorm + *silu(z). wave per row.
__global__ __launch_bounds__(256) void ln_silu_fused(const float* __restrict__ ys,
        const float* __restrict__ xz, const float* __restrict__ xc,
        const float* __restrict__ Dsv, const float* __restrict__ g,
        const float* __restrict__ bb, float* __restrict__ outp)
{
    const int row = blockIdx.x * 4 + (threadIdx.x >> 6);  // b*L + l
    const int lane = threadIdx.x & 63;
    const int b = row >> 12, l = row & (L_SZ - 1);
    const int l2 = ((l & 63) << 6) | (l >> 6);
    const float* r0 = ys + ((size_t)(0 * B_SZ + b) * L_SZ + l) * C_DIM;
    const float* r1 = ys + ((size_t)(1 * B_SZ + b) * L_SZ + (L_SZ - 1 - l)) * C_DIM;
    const float* r2 = ys + ((size_t)(2 * B_SZ + b) * L_SZ + l2) * C_DIM;
    const float* r3 = ys + ((size_t)(3 * B_SZ + b) * L_SZ + (L_SZ - 1 - l2)) * C_DIM;
    float v[3];
    float s = 0.f, s2 = 0.f;
    #pragma unroll
    for (int j = 0; j < 3; ++j) {
        int cc = lane + 64 * j;
        float ds4 = Dsv[cc] + Dsv[C_DIM + cc] + Dsv[2 * C_DIM + cc] + Dsv[3 * C_DIM + cc];
        v[j] = r0[cc] + r1[cc] + r2[cc] + r3[cc]
             + ds4 * xc[(size_t)row * C_DIM + cc];
        s += v[j];
        s2 += v[j] * v[j];
    }
    #pragma unroll
    for (int off = 1; off < 64; off <<= 1) {
        s += __shfl_xor(s, off);
        s2 += __shfl_xor(s2, off);
    }
    float mu = s / C_DIM;
    float var = s2 / C_DIM - mu * mu;
    float rstd = rsqrtf(var + 1e-5f);
    #pragma unroll
    for (int j = 0; j < 3; ++j) {
        int cc = lane + 64 * j;
        float zv = xz[(size_t)row * (2 * C_DIM) + C_DIM + cc];
        float t = (v[j] - mu) * rstd * g[cc] + bb[cc];
        outp[(size_t)row * C_DIM + cc] = t * (zv * sigmoidf_(zv));
    }
}

extern "C" void kernel_launch(void* const* d_in, const int* in_sizes, int n_in,
                              void* d_out, int out_size, void* d_ws, size_t ws_size,
                              hipStream_t stream)
{
    const float* x         = (const float*)d_in[0];
    const float* in_proj_w = (const float*)d_in[1];
    const float* conv_w    = (const float*)d_in[2];
    const float* conv_b    = (const float*)d_in[3];
    const float* x_proj_w  = (const float*)d_in[4];
    const float* dt_w      = (const float*)d_in[5];
    const float* dt_b      = (const float*)d_in[6];
    const float* A_logs    = (const float*)d_in[7];
    const float* Ds        = (const float*)d_in[8];
    const float* ln_g      = (const float*)d_in[9];
    const float* ln_b      = (const float*)d_in[10];
    const float* out_w     = (const float*)d_in[11];
    float* out = (float*)d_out;
    float* ws = (float*)d_ws;

    const size_t M = (size_t)B_SZ * L_SZ;          // 8192
    const size_t KM = (size_t)K_DIR * M;           // 32768

    float* xz    = ws;                       // M*384  (first half dead after conv -> Aprod scratch)
    float* xc    = xz + M * 384;             // M*192
    float* delta = xc + M * C_DIM;           // KM*192
    float* duys  = delta + KM * C_DIM;       // KM*192 : du, then ys in-place
    float* Bm    = duys + KM * C_DIM;        // KM*16
    float* Cm    = Bm + KM * N_ST;           // KM*16
    float* hb    = Cm + KM * N_ST;           // NCHUNK*8*192*16 : Bsum then hinit
    float* tbuf  = delta;                    // reuse after scan

    gemm_f32<<<dim3(M / 64, 384 / 64), 256, 0, stream>>>(x, in_proj_w, xz, (int)M, 2 * C_DIM, C_DIM);
    conv_silu<<<dim3(H_SZ, 2, B_SZ), 192, 0, stream>>>(xz, conv_w, conv_b, xc);
    proj_kernel<<<dim3(L_SZ / 64, B_SZ, K_DIR), 256, 0, stream>>>(xc, x_proj_w, dt_w, dt_b, delta, duys, Bm, Cm);
    scan_part1<<<dim3(C_DIM / 16, K_DIR * B_SZ, NCHUNK), 256, 0, stream>>>(delta, duys, Bm, A_logs, xz, hb);
    scan_part2<<<dim3(C_DIM / 16, K_DIR * B_SZ), 256, 0, stream>>>(xz, hb);
    scan_part3<<<dim3(C_DIM / 16, K_DIR * B_SZ, NCHUNK), 256, 0, stream>>>(delta, duys, Bm, Cm, A_logs, hb);
    ln_silu_fused<<<dim3(M / 4), 256, 0, stream>>>(duys, xz, xc, Ds, ln_g, ln_b, tbuf);
    gemm_f32<<<dim3(M / 64, C_DIM / 64), 256, 0, stream>>>(tbuf, out_w, out, (int)M, C_DIM, C_DIM);
}

// Round 6
// 228.610 us; speedup vs baseline: 8.6182x; 1.0382x over previous
//
#include <hip/hip_runtime.h>
#include <math.h>

#define C_DIM 192
#define N_ST 16
#define K_DIR 4
#define D_RK 12
#define B_SZ 2
#define H_SZ 64
#define W_SZ 64
#define L_SZ 4096
#define DPROJ 44   // D_RK + 2*N_ST
#define NPADJ 48   // DPROJ padded
#define NCHUNK 64
#define TCHUNK 64  // L_SZ / NCHUNK
#define TPAD 68    // TCHUNK + 4 (bank stagger)

__device__ __forceinline__ float sigmoidf_(float x) { return 1.f / (1.f + __expf(-x)); }

// DPP row_ror add: cross-lane sum within 16-lane rows on the VALU pipe (no LDS)
#define DPP_ADD(x, ctrl) ((x) + __builtin_bit_cast(float, \
    __builtin_amdgcn_update_dpp(0, __builtin_bit_cast(int, (x)), (ctrl), 0xf, 0xf, false)))

// scan-order index t -> memory index l in (B,L,C) layout, per direction k
__device__ __forceinline__ int scan_map(int k, int t) {
    int te = (k & 1) ? (L_SZ - 1 - t) : t;
    return (k >= 2) ? (((te & 63) << 6) | (te >> 6)) : te;  // transpose HxW (64x64)
}

// Aprod scratch lives in the dead x_ssm half of xz (cols 0..191 of each 384-row)
__device__ __forceinline__ size_t apr_idx(unsigned o) {
    unsigned r = o / 192u;
    unsigned m = o - r * 192u;
    return (size_t)r * 384u + m;
}

// C = A(MxK) * B(KxN), row-major. Tiles 64x64, K-step 16, thread 4x4.
__global__ __launch_bounds__(256) void gemm_f32(const float* __restrict__ A,
        const float* __restrict__ Bw, float* __restrict__ Cc, int M, int N, int Kd)
{
    __shared__ float As[16][64];
    __shared__ float Bs[16][64];
    const int tx = threadIdx.x & 15, ty = threadIdx.x >> 4;
    const int row0 = blockIdx.x * 64, col0 = blockIdx.y * 64;
    float acc[4][4] = {{0.f}};
    for (int kk = 0; kk < Kd; kk += 16) {
        for (int i = threadIdx.x; i < 1024; i += 256) {
            int m = i >> 4, kq = i & 15;
            As[kq][m] = A[(size_t)(row0 + m) * Kd + kk + kq];
        }
        for (int i = threadIdx.x; i < 1024; i += 256) {
            int kq = i >> 6, nn = i & 63;
            Bs[kq][nn] = Bw[(size_t)(kk + kq) * N + col0 + nn];
        }
        __syncthreads();
        #pragma unroll
        for (int kq = 0; kq < 16; ++kq) {
            float av[4], bv[4];
            #pragma unroll
            for (int i = 0; i < 4; ++i) av[i] = As[kq][ty * 4 + i];
            #pragma unroll
            for (int j = 0; j < 4; ++j) bv[j] = Bs[kq][tx * 4 + j];
            #pragma unroll
            for (int i = 0; i < 4; ++i)
                #pragma unroll
                for (int j = 0; j < 4; ++j)
                    acc[i][j] = fmaf(av[i], bv[j], acc[i][j]);
        }
        __syncthreads();
    }
    #pragma unroll
    for (int i = 0; i < 4; ++i)
        #pragma unroll
        for (int j = 0; j < 4; ++j)
            Cc[(size_t)(row0 + ty * 4 + i) * N + col0 + tx * 4 + j] = acc[i][j];
}

// depthwise 3x3 SAME conv + bias + SiLU -> xc (B,L,C). Sliding-window over w.
__global__ __launch_bounds__(192) void conv_silu(const float* __restrict__ xz,
        const float* __restrict__ cw, const float* __restrict__ cb, float* __restrict__ xc)
{
    const int c = threadIdx.x;
    const int h = blockIdx.x;
    const int w0 = blockIdx.y * 32;
    const int b = blockIdx.z;
    float wg[9];
    #pragma unroll
    for (int i = 0; i < 9; ++i) wg[i] = cw[c * 9 + i];
    const float* base = xz + ((size_t)b * L_SZ + (size_t)h * W_SZ) * (2 * C_DIM) + c;
    const bool hm = (h > 0), hp = (h < H_SZ - 1);
    const int RS = W_SZ * 2 * C_DIM;  // 24576
    float cL[3], cC[3], cR[3];
    #define LDCOL(w, dst) { \
        int off_ = (w) * (2 * C_DIM); \
        dst[0] = hm ? base[off_ - RS] : 0.f; \
        dst[1] = base[off_]; \
        dst[2] = hp ? base[off_ + RS] : 0.f; }
    if (w0 > 0) { LDCOL(w0 - 1, cL) } else { cL[0] = cL[1] = cL[2] = 0.f; }
    LDCOL(w0, cC)
    const float bias = cb[c];
    for (int w = w0; w < w0 + 32; ++w) {
        if (w < W_SZ - 1) { LDCOL(w + 1, cR) } else { cR[0] = cR[1] = cR[2] = 0.f; }
        float acc = bias;
        #pragma unroll
        for (int r = 0; r < 3; ++r)
            acc += cL[r] * wg[r * 3] + cC[r] * wg[r * 3 + 1] + cR[r] * wg[r * 3 + 2];
        float v = acc * sigmoidf_(acc);
        xc[((size_t)b * L_SZ + h * W_SZ + w) * C_DIM + c] = v;
        cL[0] = cC[0]; cL[1] = cC[1]; cL[2] = cC[2];
        cC[0] = cR[0]; cC[1] = cR[1]; cC[2] = cR[2];
    }
    #undef LDCOL
}

// per (k,b,scan-tile of 32): proj GEMM (32x48 tile, K=192 in chunks of 32),
// thread tile 2x3; As ds_read_b64 pairs, Ws ds_read_b128 triples.
// Then delta = softplus(dpart@dt_w + 2*dt_b) (dt_w from global, L2-hot),
// du = delta*u. Grid 1024 blocks -> 4 blocks/CU.
__global__ __launch_bounds__(256) void proj_kernel(const float* __restrict__ xc,
        const float* __restrict__ xpw, const float* __restrict__ dtw,
        const float* __restrict__ dtb,
        float* __restrict__ delta, float* __restrict__ du,
        float* __restrict__ Bm, float* __restrict__ Cm)
{
    __shared__ float As[32][34];       // [kq][row] transposed, 8B-aligned rows
    __shared__ float Ws[32][16][4];    // [kq][col-group][3 + pad]
    __shared__ float pj[32][NPADJ];    // proj outputs
    __shared__ int   rows_s[32];
    const int l0 = blockIdx.x * 32;
    const int b = blockIdx.y;
    const int k = blockIdx.z;
    const int kb = k * B_SZ + b;
    const int tid = threadIdx.x;

    if (tid < 32) rows_s[tid] = scan_map(k, l0 + tid);
    __syncthreads();

    const int ty = tid >> 4;      // 0..15 -> rows ty*2, ty*2+1
    const int tx = tid & 15;      // 0..15 -> cols tx*3..tx*3+2

    const int srow = tid >> 3;          // 0..31
    const int sq   = (tid & 7) * 4;     // 0,4,...,28
    const size_t xrow = ((size_t)b * L_SZ + rows_s[srow]) * C_DIM;
    const float* wbase = xpw + (size_t)k * C_DIM * DPROJ;

    float acc[2][3] = {{0.f}};
    for (int kk = 0; kk < C_DIM; kk += 32) {
        float4 a4 = *(const float4*)&xc[xrow + kk + sq];
        float wreg[6];
        #pragma unroll
        for (int j = 0; j < 6; ++j) {
            int i = tid + j * 256;
            wreg[j] = (i < 32 * DPROJ) ? wbase[(size_t)kk * DPROJ + i] : 0.f;
        }
        __syncthreads();   // previous chunk's reads done
        As[sq + 0][srow] = a4.x; As[sq + 1][srow] = a4.y;
        As[sq + 2][srow] = a4.z; As[sq + 3][srow] = a4.w;
        #pragma unroll
        for (int j = 0; j < 6; ++j) {
            int i = tid + j * 256;
            if (i < 32 * DPROJ) {
                int kq = i / DPROJ;
                int d  = i - kq * DPROJ;
                int g  = (d * 171) >> 9;     // d/3 for d < 512
                Ws[kq][g][d - 3 * g] = wreg[j];
            }
        }
        __syncthreads();
        #pragma unroll
        for (int kq = 0; kq < 32; ++kq) {
            float2 av = *(const float2*)&As[kq][ty * 2];
            float4 wv = *(const float4*)&Ws[kq][tx][0];   // .w is pad
            acc[0][0] = fmaf(av.x, wv.x, acc[0][0]);
            acc[0][1] = fmaf(av.x, wv.y, acc[0][1]);
            acc[0][2] = fmaf(av.x, wv.z, acc[0][2]);
            acc[1][0] = fmaf(av.y, wv.x, acc[1][0]);
            acc[1][1] = fmaf(av.y, wv.y, acc[1][1]);
            acc[1][2] = fmaf(av.y, wv.z, acc[1][2]);
        }
    }
    #pragma unroll
    for (int i = 0; i < 2; ++i)
        #pragma unroll
        for (int j = 0; j < 3; ++j)
            pj[ty * 2 + i][tx * 3 + j] = acc[i][j];
    __syncthreads();

    // delta = softplus(dpart @ dt_w + 2*dt_b); du = delta * u
    const float* dwb = dtw + (size_t)k * D_RK * C_DIM;
    for (int o = tid; o < 32 * C_DIM; o += 256) {
        int ll = o / C_DIM, c = o - ll * C_DIM;
        float s = 2.f * dtb[k * C_DIM + c];
        #pragma unroll
        for (int r = 0; r < D_RK; ++r) s = fmaf(pj[ll][r], dwb[r * C_DIM + c], s);
        float sp = (s > 20.f) ? s : log1pf(__expf(s));
        size_t oi = ((size_t)kb * L_SZ + l0 + ll) * C_DIM + c;
        delta[oi] = sp;
        float u = xc[((size_t)b * L_SZ + rows_s[ll]) * C_DIM + c];
        du[oi] = sp * u;
    }
    {
        int ll = tid >> 4, n = tid & 15;
        #pragma unroll
        for (int j = 0; j < 2; ++j) {
            size_t oo = ((size_t)kb * L_SZ + l0 + ll + j * 16) * N_ST + n;
            Bm[oo] = pj[ll + j * 16][D_RK + n];
            Cm[oo] = pj[ll + j * 16][D_RK + N_ST + n];
        }
    }
}

// ---- staging helpers: transpose 64x16 global tile into [16][TPAD] LDS ----
#define STAGE_CTILE(dst, src_base) { \
    const int tr_ = threadIdx.x >> 2; \
    const int tq_ = threadIdx.x & 3; \
    const float4 v_ = *(const float4*)&(src_base)[(size_t)tr_ * C_DIM + tq_ * 4]; \
    dst[tq_ * 4 + 0][tr_] = v_.x; dst[tq_ * 4 + 1][tr_] = v_.y; \
    dst[tq_ * 4 + 2][tr_] = v_.z; dst[tq_ * 4 + 3][tr_] = v_.w; }

#define STAGE_NTILE(dst, src_base) { \
    const int t_ = threadIdx.x >> 2; \
    const int nb_ = (threadIdx.x & 3) * 4; \
    const float4 v_ = *(const float4*)&(src_base)[t_ * N_ST + nb_]; \
    dst[nb_ + 0][t_] = v_.x; dst[nb_ + 1][t_] = v_.y; \
    dst[nb_ + 2][t_] = v_.z; dst[nb_ + 3][t_] = v_.w; }

// S1: chunk summary. Aprod -> dead-xz scratch, Bsum -> hb.
__global__ __launch_bounds__(256) void scan_part1(const float* __restrict__ delta,
        const float* __restrict__ du, const float* __restrict__ Bm,
        const float* __restrict__ A_logs,
        float* __restrict__ Apr, float* __restrict__ hb)
{
    __shared__ float d_s[16][TPAD];
    __shared__ float q_s[16][TPAD];
    __shared__ float B_s[16][TPAD];
    const int c0 = blockIdx.x * 16;
    const int kb = blockIdx.y;
    const int k = kb >> 1;
    const int ch = blockIdx.z;
    const size_t tbase = ((size_t)kb * L_SZ + ch * TCHUNK) * C_DIM + c0;
    STAGE_CTILE(d_s, delta + tbase)
    STAGE_CTILE(q_s, du + tbase)
    STAGE_NTILE(B_s, Bm + ((size_t)kb * L_SZ + ch * TCHUNK) * N_ST)
    __syncthreads();

    const int wave = threadIdx.x >> 6;
    const int lane = threadIdx.x & 63;
    const int ci = lane >> 4;
    const int n = lane & 15;
    const int cl = wave * 4 + ci;
    const float A_neg = -__expf(A_logs[((size_t)k * C_DIM + c0 + cl) * N_ST + n]);
    float h = 0.f, dsum = 0.f;
    #pragma unroll 4
    for (int i4 = 0; i4 < TCHUNK; i4 += 4) {
        const float4 d4 = *(const float4*)&d_s[cl][i4];
        const float4 q4 = *(const float4*)&q_s[cl][i4];
        const float4 B4 = *(const float4*)&B_s[n][i4];
        #define S1STEP(dd, qq, BB) { \
            float a_ = __expf((dd) * A_neg); \
            h = fmaf(a_, h, (qq) * (BB)); \
            dsum += (dd); }
        S1STEP(d4.x, q4.x, B4.x) S1STEP(d4.y, q4.y, B4.y)
        S1STEP(d4.z, q4.z, B4.z) S1STEP(d4.w, q4.w, B4.w)
        #undef S1STEP
    }
    unsigned o = ((unsigned)(ch * K_DIR * B_SZ + kb) * C_DIM + c0 + cl) * N_ST + n;
    Apr[apr_idx(o)] = __expf(dsum * A_neg);
    hb[o] = h;
}

// S2: sequential compose over chunks; hb: reads Bsum, writes hinit (same buffer).
__global__ __launch_bounds__(256) void scan_part2(const float* __restrict__ Apr,
        float* hb)
{
    const int kb = blockIdx.y;
    const int wave = threadIdx.x >> 6;
    const int lane = threadIdx.x & 63;
    const int ci = lane >> 4;
    const int n = lane & 15;
    const int c = blockIdx.x * 16 + wave * 4 + ci;
    float h = 0.f;
    #pragma unroll 8
    for (int ch = 0; ch < NCHUNK; ++ch) {
        unsigned o = ((unsigned)(ch * K_DIR * B_SZ + kb) * C_DIM + c) * N_ST + n;
        float Ap = Apr[apr_idx(o)];
        float Bs = hb[o];
        hb[o] = h;                 // hinit (exclusive prefix)
        h = fmaf(Ap, h, Bs);
    }
}

// S3: re-run chunk from hinit; y = sum_n h*C -> overwrite du tile (ys).
__global__ __launch_bounds__(256) void scan_part3(const float* __restrict__ delta,
        float* duys, const float* __restrict__ Bm, const float* __restrict__ Cm,
        const float* __restrict__ A_logs, const float* __restrict__ hb)
{
    __shared__ float d_s[16][TPAD];
    __shared__ float q_s[16][TPAD];
    __shared__ float B_s[16][TPAD];
    __shared__ float C_s[16][TPAD];
    const int c0 = blockIdx.x * 16;
    const int kb = blockIdx.y;
    const int k = kb >> 1;
    const int ch = blockIdx.z;
    const size_t tbase = ((size_t)kb * L_SZ + ch * TCHUNK) * C_DIM + c0;
    STAGE_CTILE(d_s, delta + tbase)
    STAGE_CTILE(q_s, duys + tbase)   // read du tile (will be overwritten below)
    STAGE_NTILE(B_s, Bm + ((size_t)kb * L_SZ + ch * TCHUNK) * N_ST)
    STAGE_NTILE(C_s, Cm + ((size_t)kb * L_SZ + ch * TCHUNK) * N_ST)
    __syncthreads();

    const int wave = threadIdx.x >> 6;
    const int lane = threadIdx.x & 63;
    const int ci = lane >> 4;
    const int n = lane & 15;
    const int cl = wave * 4 + ci;
    const float A_neg = -__expf(A_logs[((size_t)k * C_DIM + c0 + cl) * N_ST + n]);
    float* yp = duys + tbase + cl;
    float h = hb[((unsigned)(ch * K_DIR * B_SZ + kb) * C_DIM + c0 + cl) * N_ST + n];
    #pragma unroll 4
    for (int i4 = 0; i4 < TCHUNK; i4 += 4) {
        const float4 d4 = *(const float4*)&d_s[cl][i4];
        const float4 q4 = *(const float4*)&q_s[cl][i4];
        const float4 B4 = *(const float4*)&B_s[n][i4];
        const float4 C4 = *(const float4*)&C_s[n][i4];
        #define S3STEP(dd, qq, BB, CC, ii) { \
            float a_ = __expf((dd) * A_neg); \
            h = fmaf(a_, h, (qq) * (BB)); \
            float p_ = h * (CC); \
            p_ = DPP_ADD(p_, 0x128); p_ = DPP_ADD(p_, 0x124); \
            p_ = DPP_ADD(p_, 0x122); p_ = DPP_ADD(p_, 0x121); \
            if (n == 0) yp[(size_t)(i4 + (ii)) * C_DIM] = p_; }
        S3STEP(d4.x, q4.x, B4.x, C4.x, 0) S3STEP(d4.y, q4.y, B4.y, C4.y, 1)
        S3STEP(d4.z, q4.z, B4.z, C4.z, 2) S3STEP(d4.w, q4.w, B4.w, C4.w, 3)
        #undef S3STEP
    }
}

// fused: gather 4 directions + (sum_k Ds)*xc + LayerNorm + *silu(z). wave per row.
__global__ __launch_bounds__(256) void ln_silu_fused(const float* __restrict__ ys,
        const float* __restrict__ xz, const float* __restrict__ xc,
        const float* __restrict__ Dsv, const float* __restrict__ g,
        const float* __restrict__ bb, float* __restrict__ outp)
{
    const int row = blockIdx.x * 4 + (threadIdx.x >> 6);  // b*L + l
    const int lane = threadIdx.x & 63;
    const int b = row >> 12, l = row & (L_SZ - 1);
    const int l2 = ((l & 63) << 6) | (l >> 6);
    const float* r0 = ys + ((size_t)(0 * B_SZ + b) * L_SZ + l) * C_DIM;
    const float* r1 = ys + ((size_t)(1 * B_SZ + b) * L_SZ + (L_SZ - 1 - l)) * C_DIM;
    const float* r2 = ys + ((size_t)(2 * B_SZ + b) * L_SZ + l2) * C_DIM;
    const float* r3 = ys + ((size_t)(3 * B_SZ + b) * L_SZ + (L_SZ - 1 - l2)) * C_DIM;
    float v[3];
    float s = 0.f, s2 = 0.f;
    #pragma unroll
    for (int j = 0; j < 3; ++j) {
        int cc = lane + 64 * j;
        float ds4 = Dsv[cc] + Dsv[C_DIM + cc] + Dsv[2 * C_DIM + cc] + Dsv[3 * C_DIM + cc];
        v[j] = r0[cc] + r1[cc] + r2[cc] + r3[cc]
             + ds4 * xc[(size_t)row * C_DIM + cc];
        s += v[j];
        s2 += v[j] * v[j];
    }
    #pragma unroll
    for (int off = 1; off < 64; off <<= 1) {
        s += __shfl_xor(s, off);
        s2 += __shfl_xor(s2, off);
    }
    float mu = s / C_DIM;
    float var = s2 / C_DIM - mu * mu;
    float rstd = rsqrtf(var + 1e-5f);
    #pragma unroll
    for (int j = 0; j < 3; ++j) {
        int cc = lane + 64 * j;
        float zv = xz[(size_t)row * (2 * C_DIM) + C_DIM + cc];
        float t = (v[j] - mu) * rstd * g[cc] + bb[cc];
        outp[(size_t)row * C_DIM + cc] = t * (zv * sigmoidf_(zv));
    }
}

extern "C" void kernel_launch(void* const* d_in, const int* in_sizes, int n_in,
                              void* d_out, int out_size, void* d_ws, size_t ws_size,
                              hipStream_t stream)
{
    const float* x         = (const float*)d_in[0];
    const float* in_proj_w = (const float*)d_in[1];
    const float* conv_w    = (const float*)d_in[2];
    const float* conv_b    = (const float*)d_in[3];
    const float* x_proj_w  = (const float*)d_in[4];
    const float* dt_w      = (const float*)d_in[5];
    const float* dt_b      = (const float*)d_in[6];
    const float* A_logs    = (const float*)d_in[7];
    const float* Ds        = (const float*)d_in[8];
    const float* ln_g      = (const float*)d_in[9];
    const float* ln_b      = (const float*)d_in[10];
    const float* out_w     = (const float*)d_in[11];
    float* out = (float*)d_out;
    float* ws = (float*)d_ws;

    const size_t M = (size_t)B_SZ * L_SZ;          // 8192
    const size_t KM = (size_t)K_DIR * M;           // 32768

    float* xz    = ws;                       // M*384  (first half dead after conv -> Aprod scratch)
    float* xc    = xz + M * 384;             // M*192
    float* delta = xc + M * C_DIM;           // KM*192
    float* duys  = delta + KM * C_DIM;       // KM*192 : du, then ys in-place
    float* Bm    = duys + KM * C_DIM;        // KM*16
    float* Cm    = Bm + KM * N_ST;           // KM*16
    float* hb    = Cm + KM * N_ST;           // NCHUNK*8*192*16 : Bsum then hinit
    float* tbuf  = delta;                    // reuse after scan

    gemm_f32<<<dim3(M / 64, 384 / 64), 256, 0, stream>>>(x, in_proj_w, xz, (int)M, 2 * C_DIM, C_DIM);
    conv_silu<<<dim3(H_SZ, 2, B_SZ), 192, 0, stream>>>(xz, conv_w, conv_b, xc);
    proj_kernel<<<dim3(L_SZ / 32, B_SZ, K_DIR), 256, 0, stream>>>(xc, x_proj_w, dt_w, dt_b, delta, duys, Bm, Cm);
    scan_part1<<<dim3(C_DIM / 16, K_DIR * B_SZ, NCHUNK), 256, 0, stream>>>(delta, duys, Bm, A_logs, xz, hb);
    scan_part2<<<dim3(C_DIM / 16, K_DIR * B_SZ), 256, 0, stream>>>(xz, hb);
    scan_part3<<<dim3(C_DIM / 16, K_DIR * B_SZ, NCHUNK), 256, 0, stream>>>(delta, duys, Bm, Cm, A_logs, hb);
    ln_silu_fused<<<dim3(M / 4), 256, 0, stream>>>(duys, xz, xc, Ds, ln_g, ln_b, tbuf);
    gemm_f32<<<dim3(M / 64, C_DIM / 64), 256, 0, stream>>>(tbuf, out_w, out, (int)M, C_DIM, C_DIM);
}

// Round 7
// 223.267 us; speedup vs baseline: 8.8244x; 1.0239x over previous
//
#include <hip/hip_runtime.h>
#include <math.h>

#define C_DIM 192
#define N_ST 16
#define K_DIR 4
#define D_RK 12
#define B_SZ 2
#define H_SZ 64
#define W_SZ 64
#define L_SZ 4096
#define DPROJ 44   // D_RK + 2*N_ST
#define NPADJ 48   // DPROJ padded
#define NCHUNK 64
#define TCHUNK 64  // L_SZ / NCHUNK
#define TPAD 68    // TCHUNK + 4 (bank stagger)

__device__ __forceinline__ float sigmoidf_(float x) { return 1.f / (1.f + __expf(-x)); }

// DPP row_ror add: cross-lane sum within 16-lane rows on the VALU pipe (no LDS)
#define DPP_ADD(x, ctrl) ((x) + __builtin_bit_cast(float, \
    __builtin_amdgcn_update_dpp(0, __builtin_bit_cast(int, (x)), (ctrl), 0xf, 0xf, false)))

// scan-order index t <-> memory index l (involution for every k)
__device__ __forceinline__ int scan_map(int k, int t) {
    int te = (k & 1) ? (L_SZ - 1 - t) : t;
    return (k >= 2) ? (((te & 63) << 6) | (te >> 6)) : te;  // transpose HxW (64x64)
}

// Aprod scratch lives in the dead x_ssm half of xz (cols 0..191 of each 384-row)
__device__ __forceinline__ size_t apr_idx(unsigned o) {
    unsigned r = o / 192u;
    unsigned m = o - r * 192u;
    return (size_t)r * 384u + m;
}

// C = A(MxK) * B(KxN), row-major. Tiles 64x64, K-step 16, thread 4x4.
__global__ __launch_bounds__(256) void gemm_f32(const float* __restrict__ A,
        const float* __restrict__ Bw, float* __restrict__ Cc, int M, int N, int Kd)
{
    __shared__ float As[16][64];
    __shared__ float Bs[16][64];
    const int tx = threadIdx.x & 15, ty = threadIdx.x >> 4;
    const int row0 = blockIdx.x * 64, col0 = blockIdx.y * 64;
    float acc[4][4] = {{0.f}};
    for (int kk = 0; kk < Kd; kk += 16) {
        for (int i = threadIdx.x; i < 1024; i += 256) {
            int m = i >> 4, kq = i & 15;
            As[kq][m] = A[(size_t)(row0 + m) * Kd + kk + kq];
        }
        for (int i = threadIdx.x; i < 1024; i += 256) {
            int kq = i >> 6, nn = i & 63;
            Bs[kq][nn] = Bw[(size_t)(kk + kq) * N + col0 + nn];
        }
        __syncthreads();
        #pragma unroll
        for (int kq = 0; kq < 16; ++kq) {
            float av[4], bv[4];
            #pragma unroll
            for (int i = 0; i < 4; ++i) av[i] = As[kq][ty * 4 + i];
            #pragma unroll
            for (int j = 0; j < 4; ++j) bv[j] = Bs[kq][tx * 4 + j];
            #pragma unroll
            for (int i = 0; i < 4; ++i)
                #pragma unroll
                for (int j = 0; j < 4; ++j)
                    acc[i][j] = fmaf(av[i], bv[j], acc[i][j]);
        }
        __syncthreads();
    }
    #pragma unroll
    for (int i = 0; i < 4; ++i)
        #pragma unroll
        for (int j = 0; j < 4; ++j)
            Cc[(size_t)(row0 + ty * 4 + i) * N + col0 + tx * 4 + j] = acc[i][j];
}

// depthwise 3x3 SAME conv + bias + SiLU -> xc (B,L,C). Sliding-window over w.
__global__ __launch_bounds__(192) void conv_silu(const float* __restrict__ xz,
        const float* __restrict__ cw, const float* __restrict__ cb, float* __restrict__ xc)
{
    const int c = threadIdx.x;
    const int h = blockIdx.x;
    const int w0 = blockIdx.y * 32;
    const int b = blockIdx.z;
    float wg[9];
    #pragma unroll
    for (int i = 0; i < 9; ++i) wg[i] = cw[c * 9 + i];
    const float* base = xz + ((size_t)b * L_SZ + (size_t)h * W_SZ) * (2 * C_DIM) + c;
    const bool hm = (h > 0), hp = (h < H_SZ - 1);
    const int RS = W_SZ * 2 * C_DIM;  // 24576
    float cL[3], cC[3], cR[3];
    #define LDCOL(w, dst) { \
        int off_ = (w) * (2 * C_DIM); \
        dst[0] = hm ? base[off_ - RS] : 0.f; \
        dst[1] = base[off_]; \
        dst[2] = hp ? base[off_ + RS] : 0.f; }
    if (w0 > 0) { LDCOL(w0 - 1, cL) } else { cL[0] = cL[1] = cL[2] = 0.f; }
    LDCOL(w0, cC)
    const float bias = cb[c];
    for (int w = w0; w < w0 + 32; ++w) {
        if (w < W_SZ - 1) { LDCOL(w + 1, cR) } else { cR[0] = cR[1] = cR[2] = 0.f; }
        float acc = bias;
        #pragma unroll
        for (int r = 0; r < 3; ++r)
            acc += cL[r] * wg[r * 3] + cC[r] * wg[r * 3 + 1] + cR[r] * wg[r * 3 + 2];
        float v = acc * sigmoidf_(acc);
        xc[((size_t)b * L_SZ + h * W_SZ + w) * C_DIM + c] = v;
        cL[0] = cC[0]; cL[1] = cC[1]; cL[2] = cC[2];
        cC[0] = cR[0]; cC[1] = cR[1]; cC[2] = cR[2];
    }
    #undef LDCOL
}

// Memory-order proj: block = 32 contiguous rows x one direction k.
// A-tile staged once full-K transposed; u comes from the same LDS tile;
// outputs scattered to scan order via the involution scan_map.
__global__ __launch_bounds__(256) void proj_fused(const float* __restrict__ xc,
        const float* __restrict__ xpw, const float* __restrict__ dtw,
        const float* __restrict__ dtb,
        float* __restrict__ delta, float* __restrict__ du,
        float* __restrict__ Bm, float* __restrict__ Cm)
{
    __shared__ float As[C_DIM][34];    // [kq][row], even pad: aligned b64 reads
    __shared__ float Ws[32][16][4];    // [kq][col-group][3 + pad]
    __shared__ float pj[32][NPADJ];
    const int m0 = blockIdx.x * 32;        // flat (b,l) row base
    const int b  = m0 >> 12;
    const int l0 = m0 & (L_SZ - 1);
    const int k  = blockIdx.y;
    const int kb = k * B_SZ + b;
    const int tid = threadIdx.x;

    // stage A: 32 rows x 192, coalesced float4, transposed into LDS
    #pragma unroll
    for (int j = 0; j < 6; ++j) {
        int idx = tid + j * 256;           // 0..1535 float4s
        int r = idx / 48;                  // row 0..31
        int q = idx - r * 48;              // float4 col 0..47
        float4 v = *(const float4*)&xc[((size_t)m0 + r) * C_DIM + q * 4];
        As[q * 4 + 0][r] = v.x; As[q * 4 + 1][r] = v.y;
        As[q * 4 + 2][r] = v.z; As[q * 4 + 3][r] = v.w;
    }

    const int ty = tid >> 4;      // rows ty*2, ty*2+1
    const int tx = tid & 15;      // cols tx*3..+2
    const float* wbase = xpw + (size_t)k * C_DIM * DPROJ;

    float acc[2][3] = {{0.f}};
    for (int kk = 0; kk < C_DIM; kk += 32) {
        float wreg[6];
        #pragma unroll
        for (int j = 0; j < 6; ++j) {
            int i = tid + j * 256;
            wreg[j] = (i < 32 * DPROJ) ? wbase[(size_t)kk * DPROJ + i] : 0.f;
        }
        __syncthreads();   // previous chunk's Ws reads done (also covers A-stage 1st iter)
        #pragma unroll
        for (int j = 0; j < 6; ++j) {
            int i = tid + j * 256;
            if (i < 32 * DPROJ) {
                int kq = i / DPROJ;
                int d  = i - kq * DPROJ;
                int g  = (d * 171) >> 9;     // d/3
                Ws[kq][g][d - 3 * g] = wreg[j];
            }
        }
        __syncthreads();
        #pragma unroll
        for (int kq = 0; kq < 32; ++kq) {
            float2 av = *(const float2*)&As[kk + kq][ty * 2];
            float4 wv = *(const float4*)&Ws[kq][tx][0];   // .w pad
            acc[0][0] = fmaf(av.x, wv.x, acc[0][0]);
            acc[0][1] = fmaf(av.x, wv.y, acc[0][1]);
            acc[0][2] = fmaf(av.x, wv.z, acc[0][2]);
            acc[1][0] = fmaf(av.y, wv.x, acc[1][0]);
            acc[1][1] = fmaf(av.y, wv.y, acc[1][1]);
            acc[1][2] = fmaf(av.y, wv.z, acc[1][2]);
        }
    }
    #pragma unroll
    for (int i = 0; i < 2; ++i)
        #pragma unroll
        for (int j = 0; j < 3; ++j)
            pj[ty * 2 + i][tx * 3 + j] = acc[i][j];
    __syncthreads();

    // delta = softplus(dpart @ dt_w + 2*dt_b); du = delta * u (u from LDS A-tile)
    const float* dwb = dtw + (size_t)k * D_RK * C_DIM;
    #pragma unroll
    for (int it = 0; it < 24; ++it) {
        int o = tid + it * 256;            // 32*192
        int ll = o / C_DIM, c = o - ll * C_DIM;
        float s = 2.f * dtb[k * C_DIM + c];
        #pragma unroll
        for (int r = 0; r < D_RK; ++r) s = fmaf(pj[ll][r], dwb[r * C_DIM + c], s);
        float sp = (s > 20.f) ? s : log1pf(__expf(s));
        int te = scan_map(k, l0 + ll);
        size_t oi = ((size_t)kb * L_SZ + te) * C_DIM + c;
        delta[oi] = sp;
        du[oi] = sp * As[c][ll];
    }
    #pragma unroll
    for (int j = 0; j < 2; ++j) {
        int o = tid + j * 256;             // 32*16
        int ll = o >> 4, n = o & 15;
        int te = scan_map(k, l0 + ll);
        size_t oo = ((size_t)kb * L_SZ + te) * N_ST + n;
        Bm[oo] = pj[ll][D_RK + n];
        Cm[oo] = pj[ll][D_RK + N_ST + n];
    }
}

// ---- staging helpers: transpose 64x16 global tile into [16][TPAD] LDS ----
#define STAGE_CTILE(dst, src_base) { \
    const int tr_ = threadIdx.x >> 2; \
    const int tq_ = threadIdx.x & 3; \
    const float4 v_ = *(const float4*)&(src_base)[(size_t)tr_ * C_DIM + tq_ * 4]; \
    dst[tq_ * 4 + 0][tr_] = v_.x; dst[tq_ * 4 + 1][tr_] = v_.y; \
    dst[tq_ * 4 + 2][tr_] = v_.z; dst[tq_ * 4 + 3][tr_] = v_.w; }

#define STAGE_NTILE(dst, src_base) { \
    const int t_ = threadIdx.x >> 2; \
    const int nb_ = (threadIdx.x & 3) * 4; \
    const float4 v_ = *(const float4*)&(src_base)[t_ * N_ST + nb_]; \
    dst[nb_ + 0][t_] = v_.x; dst[nb_ + 1][t_] = v_.y; \
    dst[nb_ + 2][t_] = v_.z; dst[nb_ + 3][t_] = v_.w; }

// S1: chunk summary. Aprod -> dead-xz scratch, Bsum -> hb.
__global__ __launch_bounds__(256) void scan_part1(const float* __restrict__ delta,
        const float* __restrict__ du, const float* __restrict__ Bm,
        const float* __restrict__ A_logs,
        float* __restrict__ Apr, float* __restrict__ hb)
{
    __shared__ float d_s[16][TPAD];
    __shared__ float q_s[16][TPAD];
    __shared__ float B_s[16][TPAD];
    const int c0 = blockIdx.x * 16;
    const int kb = blockIdx.y;
    const int k = kb >> 1;
    const int ch = blockIdx.z;
    const size_t tbase = ((size_t)kb * L_SZ + ch * TCHUNK) * C_DIM + c0;
    STAGE_CTILE(d_s, delta + tbase)
    STAGE_CTILE(q_s, du + tbase)
    STAGE_NTILE(B_s, Bm + ((size_t)kb * L_SZ + ch * TCHUNK) * N_ST)
    __syncthreads();

    const int wave = threadIdx.x >> 6;
    const int lane = threadIdx.x & 63;
    const int ci = lane >> 4;
    const int n = lane & 15;
    const int cl = wave * 4 + ci;
    const float A_neg = -__expf(A_logs[((size_t)k * C_DIM + c0 + cl) * N_ST + n]);
    float h = 0.f, dsum = 0.f;
    #pragma unroll 4
    for (int i4 = 0; i4 < TCHUNK; i4 += 4) {
        const float4 d4 = *(const float4*)&d_s[cl][i4];
        const float4 q4 = *(const float4*)&q_s[cl][i4];
        const float4 B4 = *(const float4*)&B_s[n][i4];
        #define S1STEP(dd, qq, BB) { \
            float a_ = __expf((dd) * A_neg); \
            h = fmaf(a_, h, (qq) * (BB)); \
            dsum += (dd); }
        S1STEP(d4.x, q4.x, B4.x) S1STEP(d4.y, q4.y, B4.y)
        S1STEP(d4.z, q4.z, B4.z) S1STEP(d4.w, q4.w, B4.w)
        #undef S1STEP
    }
    unsigned o = ((unsigned)(ch * K_DIR * B_SZ + kb) * C_DIM + c0 + cl) * N_ST + n;
    Apr[apr_idx(o)] = __expf(dsum * A_neg);
    hb[o] = h;
}

// S2: sequential compose over chunks; hb: reads Bsum, writes hinit (same buffer).
__global__ __launch_bounds__(256) void scan_part2(const float* __restrict__ Apr,
        float* hb)
{
    const int kb = blockIdx.y;
    const int wave = threadIdx.x >> 6;
    const int lane = threadIdx.x & 63;
    const int ci = lane >> 4;
    const int n = lane & 15;
    const int c = blockIdx.x * 16 + wave * 4 + ci;
    float h = 0.f;
    #pragma unroll 8
    for (int ch = 0; ch < NCHUNK; ++ch) {
        unsigned o = ((unsigned)(ch * K_DIR * B_SZ + kb) * C_DIM + c) * N_ST + n;
        float Ap = Apr[apr_idx(o)];
        float Bs = hb[o];
        hb[o] = h;                 // hinit (exclusive prefix)
        h = fmaf(Ap, h, Bs);
    }
}

// S3: re-run chunk from hinit; y = sum_n h*C -> overwrite du tile (ys).
__global__ __launch_bounds__(256) void scan_part3(const float* __restrict__ delta,
        float* duys, const float* __restrict__ Bm, const float* __restrict__ Cm,
        const float* __restrict__ A_logs, const float* __restrict__ hb)
{
    __shared__ float d_s[16][TPAD];
    __shared__ float q_s[16][TPAD];
    __shared__ float B_s[16][TPAD];
    __shared__ float C_s[16][TPAD];
    const int c0 = blockIdx.x * 16;
    const int kb = blockIdx.y;
    const int k = kb >> 1;
    const int ch = blockIdx.z;
    const size_t tbase = ((size_t)kb * L_SZ + ch * TCHUNK) * C_DIM + c0;
    STAGE_CTILE(d_s, delta + tbase)
    STAGE_CTILE(q_s, duys + tbase)   // read du tile (will be overwritten below)
    STAGE_NTILE(B_s, Bm + ((size_t)kb * L_SZ + ch * TCHUNK) * N_ST)
    STAGE_NTILE(C_s, Cm + ((size_t)kb * L_SZ + ch * TCHUNK) * N_ST)
    __syncthreads();

    const int wave = threadIdx.x >> 6;
    const int lane = threadIdx.x & 63;
    const int ci = lane >> 4;
    const int n = lane & 15;
    const int cl = wave * 4 + ci;
    const float A_neg = -__expf(A_logs[((size_t)k * C_DIM + c0 + cl) * N_ST + n]);
    float* yp = duys + tbase + cl;
    float h = hb[((unsigned)(ch * K_DIR * B_SZ + kb) * C_DIM + c0 + cl) * N_ST + n];
    #pragma unroll 4
    for (int i4 = 0; i4 < TCHUNK; i4 += 4) {
        const float4 d4 = *(const float4*)&d_s[cl][i4];
        const float4 q4 = *(const float4*)&q_s[cl][i4];
        const float4 B4 = *(const float4*)&B_s[n][i4];
        const float4 C4 = *(const float4*)&C_s[n][i4];
        #define S3STEP(dd, qq, BB, CC, ii) { \
            float a_ = __expf((dd) * A_neg); \
            h = fmaf(a_, h, (qq) * (BB)); \
            float p_ = h * (CC); \
            p_ = DPP_ADD(p_, 0x128); p_ = DPP_ADD(p_, 0x124); \
            p_ = DPP_ADD(p_, 0x122); p_ = DPP_ADD(p_, 0x121); \
            if (n == 0) yp[(size_t)(i4 + (ii)) * C_DIM] = p_; }
        S3STEP(d4.x, q4.x, B4.x, C4.x, 0) S3STEP(d4.y, q4.y, B4.y, C4.y, 1)
        S3STEP(d4.z, q4.z, B4.z, C4.z, 2) S3STEP(d4.w, q4.w, B4.w, C4.w, 3)
        #undef S3STEP
    }
}

// fused: gather 4 directions + (sum_k Ds)*xc + LayerNorm + *silu(z). wave per row.
__global__ __launch_bounds__(256) void ln_silu_fused(const float* __restrict__ ys,
        const float* __restrict__ xz, const float* __restrict__ xc,
        const float* __restrict__ Dsv, const float* __restrict__ g,
        const float* __restrict__ bb, float* __restrict__ outp)
{
    const int row = blockIdx.x * 4 + (threadIdx.x >> 6);  // b*L + l
    const int lane = threadIdx.x & 63;
    const int b = row >> 12, l = row & (L_SZ - 1);
    const int l2 = ((l & 63) << 6) | (l >> 6);
    const float* r0 = ys + ((size_t)(0 * B_SZ + b) * L_SZ + l) * C_DIM;
    const float* r1 = ys + ((size_t)(1 * B_SZ + b) * L_SZ + (L_SZ - 1 - l)) * C_DIM;
    const float* r2 = ys + ((size_t)(2 * B_SZ + b) * L_SZ + l2) * C_DIM;
    const float* r3 = ys + ((size_t)(3 * B_SZ + b) * L_SZ + (L_SZ - 1 - l2)) * C_DIM;
    float v[3];
    float s = 0.f, s2 = 0.f;
    #pragma unroll
    for (int j = 0; j < 3; ++j) {
        int cc = lane + 64 * j;
        float ds4 = Dsv[cc] + Dsv[C_DIM + cc] + Dsv[2 * C_DIM + cc] + Dsv[3 * C_DIM + cc];
        v[j] = r0[cc] + r1[cc] + r2[cc] + r3[cc]
             + ds4 * xc[(size_t)row * C_DIM + cc];
        s += v[j];
        s2 += v[j] * v[j];
    }
    #pragma unroll
    for (int off = 1; off < 64; off <<= 1) {
        s += __shfl_xor(s, off);
        s2 += __shfl_xor(s2, off);
    }
    float mu = s / C_DIM;
    float var = s2 / C_DIM - mu * mu;
    float rstd = rsqrtf(var + 1e-5f);
    #pragma unroll
    for (int j = 0; j < 3; ++j) {
        int cc = lane + 64 * j;
        float zv = xz[(size_t)row * (2 * C_DIM) + C_DIM + cc];
        float t = (v[j] - mu) * rstd * g[cc] + bb[cc];
        outp[(size_t)row * C_DIM + cc] = t * (zv * sigmoidf_(zv));
    }
}

extern "C" void kernel_launch(void* const* d_in, const int* in_sizes, int n_in,
                              void* d_out, int out_size, void* d_ws, size_t ws_size,
                              hipStream_t stream)
{
    const float* x         = (const float*)d_in[0];
    const float* in_proj_w = (const float*)d_in[1];
    const float* conv_w    = (const float*)d_in[2];
    const float* conv_b    = (const float*)d_in[3];
    const float* x_proj_w  = (const float*)d_in[4];
    const float* dt_w      = (const float*)d_in[5];
    const float* dt_b      = (const float*)d_in[6];
    const float* A_logs    = (const float*)d_in[7];
    const float* Ds        = (const float*)d_in[8];
    const float* ln_g      = (const float*)d_in[9];
    const float* ln_b      = (const float*)d_in[10];
    const float* out_w     = (const float*)d_in[11];
    float* out = (float*)d_out;
    float* ws = (float*)d_ws;

    const size_t M = (size_t)B_SZ * L_SZ;          // 8192
    const size_t KM = (size_t)K_DIR * M;           // 32768

    float* xz    = ws;                       // M*384  (first half dead after conv -> Aprod scratch)
    float* xc    = xz + M * 384;             // M*192
    float* delta = xc + M * C_DIM;           // KM*192
    float* duys  = delta + KM * C_DIM;       // KM*192 : du, then ys in-place
    float* Bm    = duys + KM * C_DIM;        // KM*16
    float* Cm    = Bm + KM * N_ST;           // KM*16
    float* hb    = Cm + KM * N_ST;           // NCHUNK*8*192*16 : Bsum then hinit
    float* tbuf  = delta;                    // reuse after scan

    gemm_f32<<<dim3(M / 64, 384 / 64), 256, 0, stream>>>(x, in_proj_w, xz, (int)M, 2 * C_DIM, C_DIM);
    conv_silu<<<dim3(H_SZ, 2, B_SZ), 192, 0, stream>>>(xz, conv_w, conv_b, xc);
    proj_fused<<<dim3(M / 32, K_DIR), 256, 0, stream>>>(xc, x_proj_w, dt_w, dt_b, delta, duys, Bm, Cm);
    scan_part1<<<dim3(C_DIM / 16, K_DIR * B_SZ, NCHUNK), 256, 0, stream>>>(delta, duys, Bm, A_logs, xz, hb);
    scan_part2<<<dim3(C_DIM / 16, K_DIR * B_SZ), 256, 0, stream>>>(xz, hb);
    scan_part3<<<dim3(C_DIM / 16, K_DIR * B_SZ, NCHUNK), 256, 0, stream>>>(delta, duys, Bm, Cm, A_logs, hb);
    ln_silu_fused<<<dim3(M / 4), 256, 0, stream>>>(duys, xz, xc, Ds, ln_g, ln_b, tbuf);
    gemm_f32<<<dim3(M / 64, C_DIM / 64), 256, 0, stream>>>(tbuf, out_w, out, (int)M, C_DIM, C_DIM);
}

// Round 9
// 203.934 us; speedup vs baseline: 9.6610x; 1.0948x over previous
//
#include <hip/hip_runtime.h>
#include <math.h>

#define C_DIM 192
#define N_ST 16
#define K_DIR 4
#define D_RK 12
#define B_SZ 2
#define H_SZ 64
#define W_SZ 64
#define L_SZ 4096
#define DPROJ 44   // D_RK + 2*N_ST
#define NCHUNK 64
#define TCHUNK 64  // L_SZ / NCHUNK
#define TPAD 68    // TCHUNK + 4 (bank stagger)

typedef short bf16x8 __attribute__((ext_vector_type(8)));
typedef float f32x4 __attribute__((ext_vector_type(4)));

__device__ __forceinline__ float sigmoidf_(float x) { return 1.f / (1.f + __expf(-x)); }

// f32 -> bf16 (round-to-nearest-even), as raw ushort
__device__ __forceinline__ unsigned short f2bf(float f) {
    unsigned u = __builtin_bit_cast(unsigned, f);
    return (unsigned short)((u + 0x7FFFu + ((u >> 16) & 1u)) >> 16);
}

// DPP row_ror add: cross-lane sum within 16-lane rows on the VALU pipe (no LDS)
#define DPP_ADD(x, ctrl) ((x) + __builtin_bit_cast(float, \
    __builtin_amdgcn_update_dpp(0, __builtin_bit_cast(int, (x)), (ctrl), 0xf, 0xf, false)))

// scan-order index t <-> memory index l (involution for every k)
__device__ __forceinline__ int scan_map(int k, int t) {
    int te = (k & 1) ? (L_SZ - 1 - t) : t;
    return (k >= 2) ? (((te & 63) << 6) | (te >> 6)) : te;  // transpose HxW (64x64)
}

// Aprod scratch lives in the dead x_ssm half of xz (cols 0..191 of each 384-row)
__device__ __forceinline__ size_t apr_idx(unsigned o) {
    unsigned r = o / 192u;
    unsigned m = o - r * 192u;
    return (size_t)r * 384u + m;
}

// C = A(MxK) * B(KxN), row-major. Tiles 64x64, K-step 16, thread 4x4.
__global__ __launch_bounds__(256) void gemm_f32(const float* __restrict__ A,
        const float* __restrict__ Bw, float* __restrict__ Cc, int M, int N, int Kd)
{
    __shared__ float As[16][64];
    __shared__ float Bs[16][64];
    const int tx = threadIdx.x & 15, ty = threadIdx.x >> 4;
    const int row0 = blockIdx.x * 64, col0 = blockIdx.y * 64;
    float acc[4][4] = {{0.f}};
    for (int kk = 0; kk < Kd; kk += 16) {
        for (int i = threadIdx.x; i < 1024; i += 256) {
            int m = i >> 4, kq = i & 15;
            As[kq][m] = A[(size_t)(row0 + m) * Kd + kk + kq];
        }
        for (int i = threadIdx.x; i < 1024; i += 256) {
            int kq = i >> 6, nn = i & 63;
            Bs[kq][nn] = Bw[(size_t)(kk + kq) * N + col0 + nn];
        }
        __syncthreads();
        #pragma unroll
        for (int kq = 0; kq < 16; ++kq) {
            float av[4], bv[4];
            #pragma unroll
            for (int i = 0; i < 4; ++i) av[i] = As[kq][ty * 4 + i];
            #pragma unroll
            for (int j = 0; j < 4; ++j) bv[j] = Bs[kq][tx * 4 + j];
            #pragma unroll
            for (int i = 0; i < 4; ++i)
                #pragma unroll
                for (int j = 0; j < 4; ++j)
                    acc[i][j] = fmaf(av[i], bv[j], acc[i][j]);
        }
        __syncthreads();
    }
    #pragma unroll
    for (int i = 0; i < 4; ++i)
        #pragma unroll
        for (int j = 0; j < 4; ++j)
            Cc[(size_t)(row0 + ty * 4 + i) * N + col0 + tx * 4 + j] = acc[i][j];
}

// depthwise 3x3 SAME conv + bias + SiLU -> xc (B,L,C). Sliding-window over w.
__global__ __launch_bounds__(192) void conv_silu(const float* __restrict__ xz,
        const float* __restrict__ cw, const float* __restrict__ cb, float* __restrict__ xc)
{
    const int c = threadIdx.x;
    const int h = blockIdx.x;
    const int w0 = blockIdx.y * 32;
    const int b = blockIdx.z;
    float wg[9];
    #pragma unroll
    for (int i = 0; i < 9; ++i) wg[i] = cw[c * 9 + i];
    const float* base = xz + ((size_t)b * L_SZ + (size_t)h * W_SZ) * (2 * C_DIM) + c;
    const bool hm = (h > 0), hp = (h < H_SZ - 1);
    const int RS = W_SZ * 2 * C_DIM;  // 24576
    float cL[3], cC[3], cR[3];
    #define LDCOL(w, dst) { \
        int off_ = (w) * (2 * C_DIM); \
        dst[0] = hm ? base[off_ - RS] : 0.f; \
        dst[1] = base[off_]; \
        dst[2] = hp ? base[off_ + RS] : 0.f; }
    if (w0 > 0) { LDCOL(w0 - 1, cL) } else { cL[0] = cL[1] = cL[2] = 0.f; }
    LDCOL(w0, cC)
    const float bias = cb[c];
    for (int w = w0; w < w0 + 32; ++w) {
        if (w < W_SZ - 1) { LDCOL(w + 1, cR) } else { cR[0] = cR[1] = cR[2] = 0.f; }
        float acc = bias;
        #pragma unroll
        for (int r = 0; r < 3; ++r)
            acc += cL[r] * wg[r * 3] + cC[r] * wg[r * 3 + 1] + cR[r] * wg[r * 3 + 2];
        float v = acc * sigmoidf_(acc);
        xc[((size_t)b * L_SZ + h * W_SZ + w) * C_DIM + c] = v;
        cL[0] = cC[0]; cL[1] = cC[1]; cL[2] = cC[2];
        cC[0] = cR[0]; cC[1] = cR[1]; cC[2] = cR[2];
    }
    #undef LDCOL
}

// one-time weight conversion to MFMA fragment-ready bf16 layouts:
// Wt_g[k][kg<24][col<48][j<8] = x_proj_w[k][kg*8+j][col] (col>=44 -> 0)
// Dw_g[k][kb<4][c<192][j<8]   = dt_w[k][kb*8+j][c]       (kb*8+j>=12 -> 0)
__global__ __launch_bounds__(256) void wconvert(const float* __restrict__ xpw,
        const float* __restrict__ dtw, unsigned short* __restrict__ Wt_g,
        unsigned short* __restrict__ Dw_g)
{
    const int k = blockIdx.x;
    const int tid = threadIdx.x;
    #pragma unroll
    for (int it = 0; it < 36; ++it) {
        int idx = tid + it * 256;                 // 9216
        int kg = idx / 384;
        int rem = idx - kg * 384;
        int col = rem >> 3, j = rem & 7;
        int kr = kg * 8 + j;
        float v = (col < DPROJ) ? xpw[(size_t)k * C_DIM * DPROJ + kr * DPROJ + col] : 0.f;
        Wt_g[(size_t)k * 9216 + idx] = f2bf(v);
    }
    #pragma unroll
    for (int it = 0; it < 24; ++it) {
        int idx = tid + it * 256;                 // 6144
        int kb2 = idx / 1536;
        int rem = idx - kb2 * 1536;
        int c = rem >> 3, j = rem & 7;
        int kr = kb2 * 8 + j;
        float v = (kr < D_RK) ? dtw[(size_t)k * D_RK * C_DIM + kr * C_DIM + c] : 0.f;
        Dw_g[(size_t)k * 6144 + idx] = f2bf(v);
    }
}

// MFMA proj: block = 64 memory-order rows x one direction.
// GEMM1 (16x16x32 bf16): xc(64x192) @ W(192x48) -> pj.
// GEMM2: dpart(64x32 zero-padded) @ dt_w(32x192) -> delta logits in regs.
// softplus + scatter writes via involution scan_map.
__global__ __launch_bounds__(256) void proj_mfma(const float* __restrict__ xc,
        const unsigned short* __restrict__ Wt_g, const unsigned short* __restrict__ Dw_g,
        const float* __restrict__ dtb,
        float* __restrict__ delta, float* __restrict__ du,
        float* __restrict__ Bm, float* __restrict__ Cm)
{
    __shared__ __align__(16) unsigned short Abt[64 * 25 * 8];  // [row][kg(+pad)][8]
    __shared__ __align__(16) unsigned short Wt[24 * 48 * 8];   // [kg][col][8]
    __shared__ __align__(16) unsigned short Dw[4 * 192 * 8];   // [kb][c][8]
    __shared__ __align__(16) unsigned short pjd[64 * 32];      // [row][k 0..31]
    __shared__ float pj[64][50];

    const int tid = threadIdx.x;
    const int m0 = blockIdx.x * 64;
    const int b  = m0 >> 12;
    const int l0 = m0 & (L_SZ - 1);
    const int k  = blockIdx.y;
    const int kbi = k * B_SZ + b;

    // ---- stage ----
    #pragma unroll
    for (int it = 0; it < 6; ++it) {
        int idx = tid + it * 256;            // 1536 = 64 rows * 24 kgroups
        int r = idx / 24, g = idx - r * 24;
        const float* src = &xc[((size_t)(m0 + r)) * C_DIM + g * 8];
        float4 v0 = *(const float4*)src;
        float4 v1 = *(const float4*)(src + 4);
        uint4 w;
        w.x = f2bf(v0.x) | ((unsigned)f2bf(v0.y) << 16);
        w.y = f2bf(v0.z) | ((unsigned)f2bf(v0.w) << 16);
        w.z = f2bf(v1.x) | ((unsigned)f2bf(v1.y) << 16);
        w.w = f2bf(v1.z) | ((unsigned)f2bf(v1.w) << 16);
        *(uint4*)&Abt[(r * 25 + g) * 8] = w;
    }
    {
        const uint4* src = (const uint4*)(Wt_g + (size_t)k * 9216);
        uint4* dst = (uint4*)Wt;
        #pragma unroll
        for (int it = 0; it < 5; ++it) {
            int idx = tid + it * 256;
            if (idx < 1152) dst[idx] = src[idx];
        }
        const uint4* src2 = (const uint4*)(Dw_g + (size_t)k * 6144);
        uint4* dst2 = (uint4*)Dw;
        #pragma unroll
        for (int it = 0; it < 3; ++it) dst2[tid + it * 256] = src2[tid + it * 256];
    }
    // zero ALL of pjd: 64*32 ushorts = 4096 B = 256 uint4 (was 128 -> NaN bug)
    ((uint4*)pjd)[tid] = make_uint4(0, 0, 0, 0);
    __syncthreads();

    const int wv = tid >> 6;     // wave id = M-tile
    const int ln = tid & 63;
    const int rw = ln & 15;      // row (A) / col (B,D) within tile
    const int kq = ln >> 4;      // k-chunk / D-row-group

    // ---- GEMM1 ----
    f32x4 acc0 = {0.f, 0.f, 0.f, 0.f}, acc1 = acc0, acc2 = acc0;
    #pragma unroll
    for (int ks = 0; ks < 6; ++ks) {
        int kg = ks * 4 + kq;
        bf16x8 a  = *(const bf16x8*)&Abt[((wv * 16 + rw) * 25 + kg) * 8];
        bf16x8 b0 = *(const bf16x8*)&Wt[(kg * 48 + rw) * 8];
        bf16x8 b1 = *(const bf16x8*)&Wt[(kg * 48 + 16 + rw) * 8];
        bf16x8 b2 = *(const bf16x8*)&Wt[(kg * 48 + 32 + rw) * 8];
        acc0 = __builtin_amdgcn_mfma_f32_16x16x32_bf16(a, b0, acc0, 0, 0, 0);
        acc1 = __builtin_amdgcn_mfma_f32_16x16x32_bf16(a, b1, acc1, 0, 0, 0);
        acc2 = __builtin_amdgcn_mfma_f32_16x16x32_bf16(a, b2, acc2, 0, 0, 0);
    }
    #pragma unroll
    for (int i = 0; i < 4; ++i) {
        int row = wv * 16 + kq * 4 + i;   // C/D: col=lane&15, row=(lane>>4)*4+reg
        pj[row][rw]      = acc0[i];
        pj[row][16 + rw] = acc1[i];
        pj[row][32 + rw] = acc2[i];
        if (rw < D_RK) pjd[row * 32 + rw] = f2bf(acc0[i]);
    }
    __syncthreads();

    // ---- GEMM2: delta logits ----
    bf16x8 a2 = *(const bf16x8*)&pjd[(wv * 16 + rw) * 32 + kq * 8];
    f32x4 d2[12];
    #pragma unroll
    for (int nt = 0; nt < 12; ++nt) {
        bf16x8 b2 = *(const bf16x8*)&Dw[(kq * 192 + nt * 16 + rw) * 8];
        f32x4 z = {0.f, 0.f, 0.f, 0.f};
        d2[nt] = __builtin_amdgcn_mfma_f32_16x16x32_bf16(a2, b2, z, 0, 0, 0);
    }

    int rowv[4], tep[4];
    #pragma unroll
    for (int i = 0; i < 4; ++i) {
        rowv[i] = wv * 16 + kq * 4 + i;
        tep[i] = scan_map(k, l0 + rowv[i]);
    }
    #pragma unroll
    for (int nt = 0; nt < 12; ++nt) {
        int c = nt * 16 + rw;
        float dtb2 = 2.f * dtb[k * C_DIM + c];
        #pragma unroll
        for (int i = 0; i < 4; ++i) {
            float s = d2[nt][i] + dtb2;
            float sp = (s > 15.f) ? s : __logf(1.f + __expf(s));
            float u = xc[((size_t)(m0 + rowv[i])) * C_DIM + c];
            size_t oi = ((size_t)kbi * L_SZ + tep[i]) * C_DIM + c;
            delta[oi] = sp;
            du[oi] = sp * u;
        }
    }
    // ---- B/C scatter ----
    #pragma unroll
    for (int j = 0; j < 4; ++j) {
        int o = tid + j * 256;               // 1024 = 64*16
        int ll = o >> 4, n = o & 15;
        int te = scan_map(k, l0 + ll);
        size_t oo = ((size_t)kbi * L_SZ + te) * N_ST + n;
        Bm[oo] = pj[ll][D_RK + n];
        Cm[oo] = pj[ll][D_RK + N_ST + n];
    }
}

// ---- staging helpers: transpose 64x16 global tile into [16][TPAD] LDS ----
#define STAGE_CTILE(dst, src_base) { \
    const int tr_ = threadIdx.x >> 2; \
    const int tq_ = threadIdx.x & 3; \
    const float4 v_ = *(const float4*)&(src_base)[(size_t)tr_ * C_DIM + tq_ * 4]; \
    dst[tq_ * 4 + 0][tr_] = v_.x; dst[tq_ * 4 + 1][tr_] = v_.y; \
    dst[tq_ * 4 + 2][tr_] = v_.z; dst[tq_ * 4 + 3][tr_] = v_.w; }

#define STAGE_NTILE(dst, src_base) { \
    const int t_ = threadIdx.x >> 2; \
    const int nb_ = (threadIdx.x & 3) * 4; \
    const float4 v_ = *(const float4*)&(src_base)[t_ * N_ST + nb_]; \
    dst[nb_ + 0][t_] = v_.x; dst[nb_ + 1][t_] = v_.y; \
    dst[nb_ + 2][t_] = v_.z; dst[nb_ + 3][t_] = v_.w; }

// S1: chunk summary. Aprod -> dead-xz scratch, Bsum -> hb.
__global__ __launch_bounds__(256) void scan_part1(const float* __restrict__ delta,
        const float* __restrict__ du, const float* __restrict__ Bm,
        const float* __restrict__ A_logs,
        float* __restrict__ Apr, float* __restrict__ hb)
{
    __shared__ float d_s[16][TPAD];
    __shared__ float q_s[16][TPAD];
    __shared__ float B_s[16][TPAD];
    const int c0 = blockIdx.x * 16;
    const int kb = blockIdx.y;
    const int k = kb >> 1;
    const int ch = blockIdx.z;
    const size_t tbase = ((size_t)kb * L_SZ + ch * TCHUNK) * C_DIM + c0;
    STAGE_CTILE(d_s, delta + tbase)
    STAGE_CTILE(q_s, du + tbase)
    STAGE_NTILE(B_s, Bm + ((size_t)kb * L_SZ + ch * TCHUNK) * N_ST)
    __syncthreads();

    const int wave = threadIdx.x >> 6;
    const int lane = threadIdx.x & 63;
    const int ci = lane >> 4;
    const int n = lane & 15;
    const int cl = wave * 4 + ci;
    const float A_neg = -__expf(A_logs[((size_t)k * C_DIM + c0 + cl) * N_ST + n]);
    float h = 0.f, dsum = 0.f;
    #pragma unroll 4
    for (int i4 = 0; i4 < TCHUNK; i4 += 4) {
        const float4 d4 = *(const float4*)&d_s[cl][i4];
        const float4 q4 = *(const float4*)&q_s[cl][i4];
        const float4 B4 = *(const float4*)&B_s[n][i4];
        #define S1STEP(dd, qq, BB) { \
            float a_ = __expf((dd) * A_neg); \
            h = fmaf(a_, h, (qq) * (BB)); \
            dsum += (dd); }
        S1STEP(d4.x, q4.x, B4.x) S1STEP(d4.y, q4.y, B4.y)
        S1STEP(d4.z, q4.z, B4.z) S1STEP(d4.w, q4.w, B4.w)
        #undef S1STEP
    }
    unsigned o = ((unsigned)(ch * K_DIR * B_SZ + kb) * C_DIM + c0 + cl) * N_ST + n;
    Apr[apr_idx(o)] = __expf(dsum * A_neg);
    hb[o] = h;
}

// S2: sequential compose over chunks; hb: reads Bsum, writes hinit (same buffer).
__global__ __launch_bounds__(256) void scan_part2(const float* __restrict__ Apr,
        float* hb)
{
    const int kb = blockIdx.y;
    const int wave = threadIdx.x >> 6;
    const int lane = threadIdx.x & 63;
    const int ci = lane >> 4;
    const int n = lane & 15;
    const int c = blockIdx.x * 16 + wave * 4 + ci;
    float h = 0.f;
    #pragma unroll 8
    for (int ch = 0; ch < NCHUNK; ++ch) {
        unsigned o = ((unsigned)(ch * K_DIR * B_SZ + kb) * C_DIM + c) * N_ST + n;
        float Ap = Apr[apr_idx(o)];
        float Bs = hb[o];
        hb[o] = h;                 // hinit (exclusive prefix)
        h = fmaf(Ap, h, Bs);
    }
}

// S3: re-run chunk from hinit; y = sum_n h*C -> overwrite du tile (ys).
__global__ __launch_bounds__(256) void scan_part3(const float* __restrict__ delta,
        float* duys, const float* __restrict__ Bm, const float* __restrict__ Cm,
        const float* __restrict__ A_logs, const float* __restrict__ hb)
{
    __shared__ float d_s[16][TPAD];
    __shared__ float q_s[16][TPAD];
    __shared__ float B_s[16][TPAD];
    __shared__ float C_s[16][TPAD];
    const int c0 = blockIdx.x * 16;
    const int kb = blockIdx.y;
    const int k = kb >> 1;
    const int ch = blockIdx.z;
    const size_t tbase = ((size_t)kb * L_SZ + ch * TCHUNK) * C_DIM + c0;
    STAGE_CTILE(d_s, delta + tbase)
    STAGE_CTILE(q_s, duys + tbase)   // read du tile (will be overwritten below)
    STAGE_NTILE(B_s, Bm + ((size_t)kb * L_SZ + ch * TCHUNK) * N_ST)
    STAGE_NTILE(C_s, Cm + ((size_t)kb * L_SZ + ch * TCHUNK) * N_ST)
    __syncthreads();

    const int wave = threadIdx.x >> 6;
    const int lane = threadIdx.x & 63;
    const int ci = lane >> 4;
    const int n = lane & 15;
    const int cl = wave * 4 + ci;
    const float A_neg = -__expf(A_logs[((size_t)k * C_DIM + c0 + cl) * N_ST + n]);
    float* yp = duys + tbase + cl;
    float h = hb[((unsigned)(ch * K_DIR * B_SZ + kb) * C_DIM + c0 + cl) * N_ST + n];
    #pragma unroll 4
    for (int i4 = 0; i4 < TCHUNK; i4 += 4) {
        const float4 d4 = *(const float4*)&d_s[cl][i4];
        const float4 q4 = *(const float4*)&q_s[cl][i4];
        const float4 B4 = *(const float4*)&B_s[n][i4];
        const float4 C4 = *(const float4*)&C_s[n][i4];
        #define S3STEP(dd, qq, BB, CC, ii) { \
            float a_ = __expf((dd) * A_neg); \
            h = fmaf(a_, h, (qq) * (BB)); \
            float p_ = h * (CC); \
            p_ = DPP_ADD(p_, 0x128); p_ = DPP_ADD(p_, 0x124); \
            p_ = DPP_ADD(p_, 0x122); p_ = DPP_ADD(p_, 0x121); \
            if (n == 0) yp[(size_t)(i4 + (ii)) * C_DIM] = p_; }
        S3STEP(d4.x, q4.x, B4.x, C4.x, 0) S3STEP(d4.y, q4.y, B4.y, C4.y, 1)
        S3STEP(d4.z, q4.z, B4.z, C4.z, 2) S3STEP(d4.w, q4.w, B4.w, C4.w, 3)
        #undef S3STEP
    }
}

// fused: gather 4 directions + (sum_k Ds)*xc + LayerNorm + *silu(z). wave per row.
__global__ __launch_bounds__(256) void ln_silu_fused(const float* __restrict__ ys,
        const float* __restrict__ xz, const float* __restrict__ xc,
        const float* __restrict__ Dsv, const float* __restrict__ g,
        const float* __restrict__ bb, float* __restrict__ outp)
{
    const int row = blockIdx.x * 4 + (threadIdx.x >> 6);  // b*L + l
    const int lane = threadIdx.x & 63;
    const int b = row >> 12, l = row & (L_SZ - 1);
    const int l2 = ((l & 63) << 6) | (l >> 6);
    const float* r0 = ys + ((size_t)(0 * B_SZ + b) * L_SZ + l) * C_DIM;
    const float* r1 = ys + ((size_t)(1 * B_SZ + b) * L_SZ + (L_SZ - 1 - l)) * C_DIM;
    const float* r2 = ys + ((size_t)(2 * B_SZ + b) * L_SZ + l2) * C_DIM;
    const float* r3 = ys + ((size_t)(3 * B_SZ + b) * L_SZ + (L_SZ - 1 - l2)) * C_DIM;
    float v[3];
    float s = 0.f, s2 = 0.f;
    #pragma unroll
    for (int j = 0; j < 3; ++j) {
        int cc = lane + 64 * j;
        float ds4 = Dsv[cc] + Dsv[C_DIM + cc] + Dsv[2 * C_DIM + cc] + Dsv[3 * C_DIM + cc];
        v[j] = r0[cc] + r1[cc] + r2[cc] + r3[cc]
             + ds4 * xc[(size_t)row * C_DIM + cc];
        s += v[j];
        s2 += v[j] * v[j];
    }
    #pragma unroll
    for (int off = 1; off < 64; off <<= 1) {
        s += __shfl_xor(s, off);
        s2 += __shfl_xor(s2, off);
    }
    float mu = s / C_DIM;
    float var = s2 / C_DIM - mu * mu;
    float rstd = rsqrtf(var + 1e-5f);
    #pragma unroll
    for (int j = 0; j < 3; ++j) {
        int cc = lane + 64 * j;
        float zv = xz[(size_t)row * (2 * C_DIM) + C_DIM + cc];
        float t = (v[j] - mu) * rstd * g[cc] + bb[cc];
        outp[(size_t)row * C_DIM + cc] = t * (zv * sigmoidf_(zv));
    }
}

extern "C" void kernel_launch(void* const* d_in, const int* in_sizes, int n_in,
                              void* d_out, int out_size, void* d_ws, size_t ws_size,
                              hipStream_t stream)
{
    const float* x         = (const float*)d_in[0];
    const float* in_proj_w = (const float*)d_in[1];
    const float* conv_w    = (const float*)d_in[2];
    const float* conv_b    = (const float*)d_in[3];
    const float* x_proj_w  = (const float*)d_in[4];
    const float* dt_w      = (const float*)d_in[5];
    const float* dt_b      = (const float*)d_in[6];
    const float* A_logs    = (const float*)d_in[7];
    const float* Ds        = (const float*)d_in[8];
    const float* ln_g      = (const float*)d_in[9];
    const float* ln_b      = (const float*)d_in[10];
    const float* out_w     = (const float*)d_in[11];
    float* out = (float*)d_out;
    float* ws = (float*)d_ws;

    const size_t M = (size_t)B_SZ * L_SZ;          // 8192
    const size_t KM = (size_t)K_DIR * M;           // 32768

    float* xz    = ws;                       // M*384  (first half dead after conv -> Aprod scratch)
    float* xc    = xz + M * 384;             // M*192
    float* delta = xc + M * C_DIM;           // KM*192
    float* duys  = delta + KM * C_DIM;       // KM*192 : du, then ys in-place
    float* Bm    = duys + KM * C_DIM;        // KM*16
    float* Cm    = Bm + KM * N_ST;           // KM*16
    float* hb    = Cm + KM * N_ST;           // NCHUNK*8*192*16 : Bsum then hinit
    float* tbuf  = delta;                    // reuse after scan

    // bf16 weight buffers live at hb start (dead until scan_part1 overwrites)
    unsigned short* Wt_g = (unsigned short*)hb;            // 4*9216
    unsigned short* Dw_g = Wt_g + 4 * 9216;                // 4*6144

    gemm_f32<<<dim3(M / 64, 384 / 64), 256, 0, stream>>>(x, in_proj_w, xz, (int)M, 2 * C_DIM, C_DIM);
    conv_silu<<<dim3(H_SZ, 2, B_SZ), 192, 0, stream>>>(xz, conv_w, conv_b, xc);
    wconvert<<<dim3(K_DIR), 256, 0, stream>>>(x_proj_w, dt_w, Wt_g, Dw_g);
    proj_mfma<<<dim3(M / 64, K_DIR), 256, 0, stream>>>(xc, Wt_g, Dw_g, dt_b, delta, duys, Bm, Cm);
    scan_part1<<<dim3(C_DIM / 16, K_DIR * B_SZ, NCHUNK), 256, 0, stream>>>(delta, duys, Bm, A_logs, xz, hb);
    scan_part2<<<dim3(C_DIM / 16, K_DIR * B_SZ), 256, 0, stream>>>(xz, hb);
    scan_part3<<<dim3(C_DIM / 16, K_DIR * B_SZ, NCHUNK), 256, 0, stream>>>(delta, duys, Bm, Cm, A_logs, hb);
    ln_silu_fused<<<dim3(M / 4), 256, 0, stream>>>(duys, xz, xc, Ds, ln_g, ln_b, tbuf);
    gemm_f32<<<dim3(M / 64, C_DIM / 64), 256, 0, stream>>>(tbuf, out_w, out, (int)M, C_DIM, C_DIM);
}

// Round 10
// 181.639 us; speedup vs baseline: 10.8468x; 1.1227x over previous
//
#include <hip/hip_runtime.h>
#include <math.h>

#define C_DIM 192
#define N_ST 16
#define K_DIR 4
#define D_RK 12
#define B_SZ 2
#define H_SZ 64
#define W_SZ 64
#define L_SZ 4096
#define DPROJ 44   // D_RK + 2*N_ST
#define NCHUNK 64
#define TCHUNK 64  // L_SZ / NCHUNK

typedef short bf16x8 __attribute__((ext_vector_type(8)));
typedef float f32x4 __attribute__((ext_vector_type(4)));

__device__ __forceinline__ float sigmoidf_(float x) { return 1.f / (1.f + __expf(-x)); }

// f32 -> bf16 (round-to-nearest-even), as raw ushort
__device__ __forceinline__ unsigned short f2bf(float f) {
    unsigned u = __builtin_bit_cast(unsigned, f);
    return (unsigned short)((u + 0x7FFFu + ((u >> 16) & 1u)) >> 16);
}

// scan-order index t <-> memory index l (involution for every k)
__device__ __forceinline__ int scan_map(int k, int t) {
    int te = (k & 1) ? (L_SZ - 1 - t) : t;
    return (k >= 2) ? (((te & 63) << 6) | (te >> 6)) : te;  // transpose HxW (64x64)
}

// Aprod scratch lives in the dead x_ssm half of xz (cols 0..191 of each 384-row)
__device__ __forceinline__ size_t apr_idx(unsigned o) {
    unsigned r = o / 192u;
    unsigned m = o - r * 192u;
    return (size_t)r * 384u + m;
}

// C = A(MxK) * B(KxN), row-major. Tiles 64x64, K-step 16, thread 4x4.
__global__ __launch_bounds__(256) void gemm_f32(const float* __restrict__ A,
        const float* __restrict__ Bw, float* __restrict__ Cc, int M, int N, int Kd)
{
    __shared__ float As[16][64];
    __shared__ float Bs[16][64];
    const int tx = threadIdx.x & 15, ty = threadIdx.x >> 4;
    const int row0 = blockIdx.x * 64, col0 = blockIdx.y * 64;
    float acc[4][4] = {{0.f}};
    for (int kk = 0; kk < Kd; kk += 16) {
        for (int i = threadIdx.x; i < 1024; i += 256) {
            int m = i >> 4, kq = i & 15;
            As[kq][m] = A[(size_t)(row0 + m) * Kd + kk + kq];
        }
        for (int i = threadIdx.x; i < 1024; i += 256) {
            int kq = i >> 6, nn = i & 63;
            Bs[kq][nn] = Bw[(size_t)(kk + kq) * N + col0 + nn];
        }
        __syncthreads();
        #pragma unroll
        for (int kq = 0; kq < 16; ++kq) {
            float av[4], bv[4];
            #pragma unroll
            for (int i = 0; i < 4; ++i) av[i] = As[kq][ty * 4 + i];
            #pragma unroll
            for (int j = 0; j < 4; ++j) bv[j] = Bs[kq][tx * 4 + j];
            #pragma unroll
            for (int i = 0; i < 4; ++i)
                #pragma unroll
                for (int j = 0; j < 4; ++j)
                    acc[i][j] = fmaf(av[i], bv[j], acc[i][j]);
        }
        __syncthreads();
    }
    #pragma unroll
    for (int i = 0; i < 4; ++i)
        #pragma unroll
        for (int j = 0; j < 4; ++j)
            Cc[(size_t)(row0 + ty * 4 + i) * N + col0 + tx * 4 + j] = acc[i][j];
}

// depthwise 3x3 SAME conv + bias + SiLU -> xc (B,L,C). Sliding-window over w.
__global__ __launch_bounds__(192) void conv_silu(const float* __restrict__ xz,
        const float* __restrict__ cw, const float* __restrict__ cb, float* __restrict__ xc)
{
    const int c = threadIdx.x;
    const int h = blockIdx.x;
    const int w0 = blockIdx.y * 32;
    const int b = blockIdx.z;
    float wg[9];
    #pragma unroll
    for (int i = 0; i < 9; ++i) wg[i] = cw[c * 9 + i];
    const float* base = xz + ((size_t)b * L_SZ + (size_t)h * W_SZ) * (2 * C_DIM) + c;
    const bool hm = (h > 0), hp = (h < H_SZ - 1);
    const int RS = W_SZ * 2 * C_DIM;  // 24576
    float cL[3], cC[3], cR[3];
    #define LDCOL(w, dst) { \
        int off_ = (w) * (2 * C_DIM); \
        dst[0] = hm ? base[off_ - RS] : 0.f; \
        dst[1] = base[off_]; \
        dst[2] = hp ? base[off_ + RS] : 0.f; }
    if (w0 > 0) { LDCOL(w0 - 1, cL) } else { cL[0] = cL[1] = cL[2] = 0.f; }
    LDCOL(w0, cC)
    const float bias = cb[c];
    for (int w = w0; w < w0 + 32; ++w) {
        if (w < W_SZ - 1) { LDCOL(w + 1, cR) } else { cR[0] = cR[1] = cR[2] = 0.f; }
        float acc = bias;
        #pragma unroll
        for (int r = 0; r < 3; ++r)
            acc += cL[r] * wg[r * 3] + cC[r] * wg[r * 3 + 1] + cR[r] * wg[r * 3 + 2];
        float v = acc * sigmoidf_(acc);
        xc[((size_t)b * L_SZ + h * W_SZ + w) * C_DIM + c] = v;
        cL[0] = cC[0]; cL[1] = cC[1]; cL[2] = cC[2];
        cC[0] = cR[0]; cC[1] = cR[1]; cC[2] = cR[2];
    }
    #undef LDCOL
}

// one-time weight conversion to MFMA fragment-ready bf16 layouts
__global__ __launch_bounds__(256) void wconvert(const float* __restrict__ xpw,
        const float* __restrict__ dtw, unsigned short* __restrict__ Wt_g,
        unsigned short* __restrict__ Dw_g)
{
    const int k = blockIdx.x;
    const int tid = threadIdx.x;
    #pragma unroll
    for (int it = 0; it < 36; ++it) {
        int idx = tid + it * 256;                 // 9216
        int kg = idx / 384;
        int rem = idx - kg * 384;
        int col = rem >> 3, j = rem & 7;
        int kr = kg * 8 + j;
        float v = (col < DPROJ) ? xpw[(size_t)k * C_DIM * DPROJ + kr * DPROJ + col] : 0.f;
        Wt_g[(size_t)k * 9216 + idx] = f2bf(v);
    }
    #pragma unroll
    for (int it = 0; it < 24; ++it) {
        int idx = tid + it * 256;                 // 6144
        int kb2 = idx / 1536;
        int rem = idx - kb2 * 1536;
        int c = rem >> 3, j = rem & 7;
        int kr = kb2 * 8 + j;
        float v = (kr < D_RK) ? dtw[(size_t)k * D_RK * C_DIM + kr * C_DIM + c] : 0.f;
        Dw_g[(size_t)k * 6144 + idx] = f2bf(v);
    }
}

// MFMA proj: block = 64 memory-order rows x one direction.
__global__ __launch_bounds__(256) void proj_mfma(const float* __restrict__ xc,
        const unsigned short* __restrict__ Wt_g, const unsigned short* __restrict__ Dw_g,
        const float* __restrict__ dtb,
        float* __restrict__ delta, float* __restrict__ du,
        float* __restrict__ Bm, float* __restrict__ Cm)
{
    __shared__ __align__(16) unsigned short Abt[64 * 25 * 8];  // [row][kg(+pad)][8]
    __shared__ __align__(16) unsigned short Wt[24 * 48 * 8];   // [kg][col][8]
    __shared__ __align__(16) unsigned short Dw[4 * 192 * 8];   // [kb][c][8]
    __shared__ __align__(16) unsigned short pjd[64 * 32];      // [row][k 0..31]
    __shared__ float pj[64][50];

    const int tid = threadIdx.x;
    const int m0 = blockIdx.x * 64;
    const int b  = m0 >> 12;
    const int l0 = m0 & (L_SZ - 1);
    const int k  = blockIdx.y;
    const int kbi = k * B_SZ + b;

    #pragma unroll
    for (int it = 0; it < 6; ++it) {
        int idx = tid + it * 256;            // 1536 = 64 rows * 24 kgroups
        int r = idx / 24, g = idx - r * 24;
        const float* src = &xc[((size_t)(m0 + r)) * C_DIM + g * 8];
        float4 v0 = *(const float4*)src;
        float4 v1 = *(const float4*)(src + 4);
        uint4 w;
        w.x = f2bf(v0.x) | ((unsigned)f2bf(v0.y) << 16);
        w.y = f2bf(v0.z) | ((unsigned)f2bf(v0.w) << 16);
        w.z = f2bf(v1.x) | ((unsigned)f2bf(v1.y) << 16);
        w.w = f2bf(v1.z) | ((unsigned)f2bf(v1.w) << 16);
        *(uint4*)&Abt[(r * 25 + g) * 8] = w;
    }
    {
        const uint4* src = (const uint4*)(Wt_g + (size_t)k * 9216);
        uint4* dst = (uint4*)Wt;
        #pragma unroll
        for (int it = 0; it < 5; ++it) {
            int idx = tid + it * 256;
            if (idx < 1152) dst[idx] = src[idx];
        }
        const uint4* src2 = (const uint4*)(Dw_g + (size_t)k * 6144);
        uint4* dst2 = (uint4*)Dw;
        #pragma unroll
        for (int it = 0; it < 3; ++it) dst2[tid + it * 256] = src2[tid + it * 256];
    }
    // zero ALL of pjd: 4096 B = 256 uint4
    ((uint4*)pjd)[tid] = make_uint4(0, 0, 0, 0);
    __syncthreads();

    const int wv = tid >> 6;
    const int ln = tid & 63;
    const int rw = ln & 15;
    const int kq = ln >> 4;

    // ---- GEMM1 ----
    f32x4 acc0 = {0.f, 0.f, 0.f, 0.f}, acc1 = acc0, acc2 = acc0;
    #pragma unroll
    for (int ks = 0; ks < 6; ++ks) {
        int kg = ks * 4 + kq;
        bf16x8 a  = *(const bf16x8*)&Abt[((wv * 16 + rw) * 25 + kg) * 8];
        bf16x8 b0 = *(const bf16x8*)&Wt[(kg * 48 + rw) * 8];
        bf16x8 b1 = *(const bf16x8*)&Wt[(kg * 48 + 16 + rw) * 8];
        bf16x8 b2 = *(const bf16x8*)&Wt[(kg * 48 + 32 + rw) * 8];
        acc0 = __builtin_amdgcn_mfma_f32_16x16x32_bf16(a, b0, acc0, 0, 0, 0);
        acc1 = __builtin_amdgcn_mfma_f32_16x16x32_bf16(a, b1, acc1, 0, 0, 0);
        acc2 = __builtin_amdgcn_mfma_f32_16x16x32_bf16(a, b2, acc2, 0, 0, 0);
    }
    #pragma unroll
    for (int i = 0; i < 4; ++i) {
        int row = wv * 16 + kq * 4 + i;
        pj[row][rw]      = acc0[i];
        pj[row][16 + rw] = acc1[i];
        pj[row][32 + rw] = acc2[i];
        if (rw < D_RK) pjd[row * 32 + rw] = f2bf(acc0[i]);
    }
    __syncthreads();

    // ---- GEMM2: delta logits ----
    bf16x8 a2 = *(const bf16x8*)&pjd[(wv * 16 + rw) * 32 + kq * 8];
    f32x4 d2[12];
    #pragma unroll
    for (int nt = 0; nt < 12; ++nt) {
        bf16x8 b2 = *(const bf16x8*)&Dw[(kq * 192 + nt * 16 + rw) * 8];
        f32x4 z = {0.f, 0.f, 0.f, 0.f};
        d2[nt] = __builtin_amdgcn_mfma_f32_16x16x32_bf16(a2, b2, z, 0, 0, 0);
    }

    int rowv[4], tep[4];
    #pragma unroll
    for (int i = 0; i < 4; ++i) {
        rowv[i] = wv * 16 + kq * 4 + i;
        tep[i] = scan_map(k, l0 + rowv[i]);
    }
    #pragma unroll
    for (int nt = 0; nt < 12; ++nt) {
        int c = nt * 16 + rw;
        float dtb2 = 2.f * dtb[k * C_DIM + c];
        #pragma unroll
        for (int i = 0; i < 4; ++i) {
            float s = d2[nt][i] + dtb2;
            float sp = (s > 15.f) ? s : __logf(1.f + __expf(s));
            float u = xc[((size_t)(m0 + rowv[i])) * C_DIM + c];
            size_t oi = ((size_t)kbi * L_SZ + tep[i]) * C_DIM + c;
            delta[oi] = sp;
            du[oi] = sp * u;
        }
    }
    #pragma unroll
    for (int j = 0; j < 4; ++j) {
        int o = tid + j * 256;               // 1024 = 64*16
        int ll = o >> 4, n = o & 15;
        int te = scan_map(k, l0 + ll);
        size_t oo = ((size_t)kbi * L_SZ + te) * N_ST + n;
        Bm[oo] = pj[ll][D_RK + n];
        Cm[oo] = pj[ll][D_RK + N_ST + n];
    }
}

// ---- chunked scan, lane = (channel, 4 states) ----
// block = (c-group of 64, kb, chunk); wave = 16 channels x 16 states.
// delta/du read direct from global (L2-hot, 64B broadcast-coalesced);
// B (and C) tiles in LDS with uniform b128 broadcast reads.

// S1: chunk summary. Aprod(float4) -> dead-xz scratch, Bsum(float4) -> hb.
__global__ __launch_bounds__(256) void scan_part1(const float* __restrict__ delta,
        const float* __restrict__ du, const float* __restrict__ Bm,
        const float* __restrict__ A_logs,
        float* __restrict__ Apr, float* __restrict__ hb)
{
    __shared__ float B_s[TCHUNK][16];
    const int c0 = blockIdx.x * 64;
    const int kb = blockIdx.y;
    const int k = kb >> 1;
    const int ch = blockIdx.z;
    const int tid = threadIdx.x;
    ((float4*)B_s)[tid] = ((const float4*)(Bm + ((size_t)kb * L_SZ + ch * TCHUNK) * N_ST))[tid];
    __syncthreads();

    const int w = tid >> 6, ln = tid & 63;
    const int cl = ln & 15, g = ln >> 4;
    const int c = c0 + w * 16 + cl;
    const float4 Alg = *(const float4*)&A_logs[((size_t)k * C_DIM + c) * N_ST + g * 4];
    const float An0 = -__expf(Alg.x) * 1.44269504089f;
    const float An1 = -__expf(Alg.y) * 1.44269504089f;
    const float An2 = -__expf(Alg.z) * 1.44269504089f;
    const float An3 = -__expf(Alg.w) * 1.44269504089f;
    const float* dp = delta + ((size_t)kb * L_SZ + ch * TCHUNK) * C_DIM + c;
    const float* qp = du    + ((size_t)kb * L_SZ + ch * TCHUNK) * C_DIM + c;
    float h0 = 0.f, h1 = 0.f, h2 = 0.f, h3 = 0.f, dsum = 0.f;
    #pragma unroll 4
    for (int t = 0; t < TCHUNK; ++t) {
        float dlt = dp[(size_t)t * C_DIM];
        float qv  = qp[(size_t)t * C_DIM];
        float4 B4 = *(const float4*)&B_s[t][g * 4];
        dsum += dlt;
        h0 = fmaf(__builtin_amdgcn_exp2f(dlt * An0), h0, qv * B4.x);
        h1 = fmaf(__builtin_amdgcn_exp2f(dlt * An1), h1, qv * B4.y);
        h2 = fmaf(__builtin_amdgcn_exp2f(dlt * An2), h2, qv * B4.z);
        h3 = fmaf(__builtin_amdgcn_exp2f(dlt * An3), h3, qv * B4.w);
    }
    unsigned o = ((unsigned)(ch * K_DIR * B_SZ + kb) * C_DIM + c) * N_ST + g * 4;
    float4 Ap4;
    Ap4.x = __builtin_amdgcn_exp2f(dsum * An0);
    Ap4.y = __builtin_amdgcn_exp2f(dsum * An1);
    Ap4.z = __builtin_amdgcn_exp2f(dsum * An2);
    Ap4.w = __builtin_amdgcn_exp2f(dsum * An3);
    *(float4*)&Apr[apr_idx(o)] = Ap4;       // stays within one 192-col row (verified)
    float4 hv = make_float4(h0, h1, h2, h3);
    *(float4*)&hb[o] = hv;
}

// S2: sequential compose over chunks; hb: reads Bsum, writes hinit (same buffer).
__global__ __launch_bounds__(256) void scan_part2(const float* __restrict__ Apr,
        float* hb)
{
    const int kb = blockIdx.y;
    const int wave = threadIdx.x >> 6;
    const int lane = threadIdx.x & 63;
    const int ci = lane >> 4;
    const int n = lane & 15;
    const int c = blockIdx.x * 16 + wave * 4 + ci;
    float h = 0.f;
    #pragma unroll 8
    for (int ch = 0; ch < NCHUNK; ++ch) {
        unsigned o = ((unsigned)(ch * K_DIR * B_SZ + kb) * C_DIM + c) * N_ST + n;
        float Ap = Apr[apr_idx(o)];
        float Bs = hb[o];
        hb[o] = h;                 // hinit (exclusive prefix)
        h = fmaf(Ap, h, Bs);
    }
}

// S3: re-run chunk from hinit; y = sum_n h*C -> overwrite du tile (ys).
__global__ __launch_bounds__(256) void scan_part3(const float* __restrict__ delta,
        float* duys, const float* __restrict__ Bm, const float* __restrict__ Cm,
        const float* __restrict__ A_logs, const float* __restrict__ hb)
{
    __shared__ float B_s[TCHUNK][16];
    __shared__ float C_s[TCHUNK][16];
    const int c0 = blockIdx.x * 64;
    const int kb = blockIdx.y;
    const int k = kb >> 1;
    const int ch = blockIdx.z;
    const int tid = threadIdx.x;
    ((float4*)B_s)[tid] = ((const float4*)(Bm + ((size_t)kb * L_SZ + ch * TCHUNK) * N_ST))[tid];
    ((float4*)C_s)[tid] = ((const float4*)(Cm + ((size_t)kb * L_SZ + ch * TCHUNK) * N_ST))[tid];
    __syncthreads();

    const int w = tid >> 6, ln = tid & 63;
    const int cl = ln & 15, g = ln >> 4;
    const int c = c0 + w * 16 + cl;
    const float4 Alg = *(const float4*)&A_logs[((size_t)k * C_DIM + c) * N_ST + g * 4];
    const float An0 = -__expf(Alg.x) * 1.44269504089f;
    const float An1 = -__expf(Alg.y) * 1.44269504089f;
    const float An2 = -__expf(Alg.z) * 1.44269504089f;
    const float An3 = -__expf(Alg.w) * 1.44269504089f;
    const size_t tbase = ((size_t)kb * L_SZ + ch * TCHUNK) * C_DIM + c;
    const float* dp = delta + tbase;
    float* qy = duys + tbase;          // read du[t], later write y[t] (same addr, safe order)
    unsigned o = ((unsigned)(ch * K_DIR * B_SZ + kb) * C_DIM + c) * N_ST + g * 4;
    float4 hv = *(const float4*)&hb[o];
    float h0 = hv.x, h1 = hv.y, h2 = hv.z, h3 = hv.w;
    #pragma unroll 4
    for (int t = 0; t < TCHUNK; ++t) {
        float dlt = dp[(size_t)t * C_DIM];
        float qv  = qy[(size_t)t * C_DIM];
        float4 B4 = *(const float4*)&B_s[t][g * 4];
        float4 C4 = *(const float4*)&C_s[t][g * 4];
        h0 = fmaf(__builtin_amdgcn_exp2f(dlt * An0), h0, qv * B4.x);
        h1 = fmaf(__builtin_amdgcn_exp2f(dlt * An1), h1, qv * B4.y);
        h2 = fmaf(__builtin_amdgcn_exp2f(dlt * An2), h2, qv * B4.z);
        h3 = fmaf(__builtin_amdgcn_exp2f(dlt * An3), h3, qv * B4.w);
        float p = h0 * C4.x;
        p = fmaf(h1, C4.y, p);
        p = fmaf(h2, C4.z, p);
        p = fmaf(h3, C4.w, p);
        p += __shfl_xor(p, 16);
        p += __shfl_xor(p, 32);
        if (g == 0) qy[(size_t)t * C_DIM] = p;
    }
}

// fused: gather 4 directions + (sum_k Ds)*xc + LayerNorm + *silu(z). wave per row.
__global__ __launch_bounds__(256) void ln_silu_fused(const float* __restrict__ ys,
        const float* __restrict__ xz, const float* __restrict__ xc,
        const float* __restrict__ Dsv, const float* __restrict__ g,
        const float* __restrict__ bb, float* __restrict__ outp)
{
    const int row = blockIdx.x * 4 + (threadIdx.x >> 6);  // b*L + l
    const int lane = threadIdx.x & 63;
    const int b = row >> 12, l = row & (L_SZ - 1);
    const int l2 = ((l & 63) << 6) | (l >> 6);
    const float* r0 = ys + ((size_t)(0 * B_SZ + b) * L_SZ + l) * C_DIM;
    const float* r1 = ys + ((size_t)(1 * B_SZ + b) * L_SZ + (L_SZ - 1 - l)) * C_DIM;
    const float* r2 = ys + ((size_t)(2 * B_SZ + b) * L_SZ + l2) * C_DIM;
    const float* r3 = ys + ((size_t)(3 * B_SZ + b) * L_SZ + (L_SZ - 1 - l2)) * C_DIM;
    float v[3];
    float s = 0.f, s2 = 0.f;
    #pragma unroll
    for (int j = 0; j < 3; ++j) {
        int cc = lane + 64 * j;
        float ds4 = Dsv[cc] + Dsv[C_DIM + cc] + Dsv[2 * C_DIM + cc] + Dsv[3 * C_DIM + cc];
        v[j] = r0[cc] + r1[cc] + r2[cc] + r3[cc]
             + ds4 * xc[(size_t)row * C_DIM + cc];
        s += v[j];
        s2 += v[j] * v[j];
    }
    #pragma unroll
    for (int off = 1; off < 64; off <<= 1) {
        s += __shfl_xor(s, off);
        s2 += __shfl_xor(s2, off);
    }
    float mu = s / C_DIM;
    float var = s2 / C_DIM - mu * mu;
    float rstd = rsqrtf(var + 1e-5f);
    #pragma unroll
    for (int j = 0; j < 3; ++j) {
        int cc = lane + 64 * j;
        float zv = xz[(size_t)row * (2 * C_DIM) + C_DIM + cc];
        float t = (v[j] - mu) * rstd * g[cc] + bb[cc];
        outp[(size_t)row * C_DIM + cc] = t * (zv * sigmoidf_(zv));
    }
}

extern "C" void kernel_launch(void* const* d_in, const int* in_sizes, int n_in,
                              void* d_out, int out_size, void* d_ws, size_t ws_size,
                              hipStream_t stream)
{
    const float* x         = (const float*)d_in[0];
    const float* in_proj_w = (const float*)d_in[1];
    const float* conv_w    = (const float*)d_in[2];
    const float* conv_b    = (const float*)d_in[3];
    const float* x_proj_w  = (const float*)d_in[4];
    const float* dt_w      = (const float*)d_in[5];
    const float* dt_b      = (const float*)d_in[6];
    const float* A_logs    = (const float*)d_in[7];
    const float* Ds        = (const float*)d_in[8];
    const float* ln_g      = (const float*)d_in[9];
    const float* ln_b      = (const float*)d_in[10];
    const float* out_w     = (const float*)d_in[11];
    float* out = (float*)d_out;
    float* ws = (float*)d_ws;

    const size_t M = (size_t)B_SZ * L_SZ;          // 8192
    const size_t KM = (size_t)K_DIR * M;           // 32768

    float* xz    = ws;                       // M*384  (first half dead after conv -> Aprod scratch)
    float* xc    = xz + M * 384;             // M*192
    float* delta = xc + M * C_DIM;           // KM*192
    float* duys  = delta + KM * C_DIM;       // KM*192 : du, then ys in-place
    float* Bm    = duys + KM * C_DIM;        // KM*16
    float* Cm    = Bm + KM * N_ST;           // KM*16
    float* hb    = Cm + KM * N_ST;           // NCHUNK*8*192*16 : Bsum then hinit
    float* tbuf  = delta;                    // reuse after scan

    // bf16 weight buffers live at hb start (dead until scan_part1 overwrites)
    unsigned short* Wt_g = (unsigned short*)hb;            // 4*9216
    unsigned short* Dw_g = Wt_g + 4 * 9216;                // 4*6144

    gemm_f32<<<dim3(M / 64, 384 / 64), 256, 0, stream>>>(x, in_proj_w, xz, (int)M, 2 * C_DIM, C_DIM);
    conv_silu<<<dim3(H_SZ, 2, B_SZ), 192, 0, stream>>>(xz, conv_w, conv_b, xc);
    wconvert<<<dim3(K_DIR), 256, 0, stream>>>(x_proj_w, dt_w, Wt_g, Dw_g);
    proj_mfma<<<dim3(M / 64, K_DIR), 256, 0, stream>>>(xc, Wt_g, Dw_g, dt_b, delta, duys, Bm, Cm);
    scan_part1<<<dim3(C_DIM / 64, K_DIR * B_SZ, NCHUNK), 256, 0, stream>>>(delta, duys, Bm, A_logs, xz, hb);
    scan_part2<<<dim3(C_DIM / 16, K_DIR * B_SZ), 256, 0, stream>>>(xz, hb);
    scan_part3<<<dim3(C_DIM / 64, K_DIR * B_SZ, NCHUNK), 256, 0, stream>>>(delta, duys, Bm, Cm, A_logs, hb);
    ln_silu_fused<<<dim3(M / 4), 256, 0, stream>>>(duys, xz, xc, Ds, ln_g, ln_b, tbuf);
    gemm_f32<<<dim3(M / 64, C_DIM / 64), 256, 0, stream>>>(tbuf, out_w, out, (int)M, C_DIM, C_DIM);
}

// Round 11
// 138.419 us; speedup vs baseline: 14.2336x; 1.3122x over previous
//
#include <hip/hip_runtime.h>
#include <math.h>

#define C_DIM 192
#define N_ST 16
#define K_DIR 4
#define D_RK 12
#define B_SZ 2
#define H_SZ 64
#define W_SZ 64
#define L_SZ 4096
#define DPROJ 44   // D_RK + 2*N_ST
#define NCHUNK 64
#define TCHUNK 64  // L_SZ / NCHUNK

typedef short bf16x8 __attribute__((ext_vector_type(8)));
typedef float f32x4 __attribute__((ext_vector_type(4)));

__device__ __forceinline__ float sigmoidf_(float x) { return 1.f / (1.f + __expf(-x)); }

// f32 -> bf16 (round-to-nearest-even), as raw ushort
__device__ __forceinline__ unsigned short f2bf(float f) {
    unsigned u = __builtin_bit_cast(unsigned, f);
    return (unsigned short)((u + 0x7FFFu + ((u >> 16) & 1u)) >> 16);
}

// scan-order index t <-> memory index l (involution for every k)
__device__ __forceinline__ int scan_map(int k, int t) {
    int te = (k & 1) ? (L_SZ - 1 - t) : t;
    return (k >= 2) ? (((te & 63) << 6) | (te >> 6)) : te;  // transpose HxW (64x64)
}

// Aprod scratch lives in the dead x_ssm half of xz (cols 0..191 of each 384-row)
__device__ __forceinline__ size_t apr_idx(unsigned o) {
    unsigned r = o / 192u;
    unsigned m = o - r * 192u;
    return (size_t)r * 384u + m;
}

// ---- early weight conversion: in_proj_w / x_proj_w / dt_w -> bf16 fragments ----
// Wip [kg<24][col<384][8]; Wt_g [k][kg<24][col<48][8]; Dw_g [k][kb<4][c<192][8]
__global__ __launch_bounds__(256) void wconv_all(const float* __restrict__ ipw,
        const float* __restrict__ xpw, const float* __restrict__ dtw,
        unsigned short* __restrict__ Wip, unsigned short* __restrict__ Wt_g,
        unsigned short* __restrict__ Dw_g)
{
    int idx = blockIdx.x * 256 + threadIdx.x;   // 0 .. 135167
    if (idx < 73728) {                          // in_proj_w
        int kg = idx / 3072;                    // 384*8
        int rem = idx - kg * 3072;
        int col = rem >> 3, j = rem & 7;
        Wip[idx] = f2bf(ipw[(size_t)(kg * 8 + j) * 384 + col]);
    } else if (idx < 110592) {                  // x_proj_w
        int i2 = idx - 73728;
        int k = i2 / 9216;
        int rem = i2 - k * 9216;
        int kg = rem / 384;
        int r2 = rem - kg * 384;
        int col = r2 >> 3, j = r2 & 7;
        int kr = kg * 8 + j;
        float v = (col < DPROJ) ? xpw[(size_t)k * C_DIM * DPROJ + kr * DPROJ + col] : 0.f;
        Wt_g[i2] = f2bf(v);
    } else {                                    // dt_w
        int i3 = idx - 110592;
        int k = i3 / 6144;
        int rem = i3 - k * 6144;
        int kb2 = rem / 1536;
        int r2 = rem - kb2 * 1536;
        int c = r2 >> 3, j = r2 & 7;
        int kr = kb2 * 8 + j;
        float v = (kr < D_RK) ? dtw[(size_t)k * D_RK * C_DIM + kr * C_DIM + c] : 0.f;
        Dw_g[i3] = f2bf(v);
    }
}

// late: out_w (192x192) -> Wout [kg<24][col<192][8] (into dead Cm region)
__global__ __launch_bounds__(256) void wconv_out(const float* __restrict__ ow,
        unsigned short* __restrict__ Wout)
{
    int idx = blockIdx.x * 256 + threadIdx.x;   // 0 .. 36863
    int kg = idx / 1536;                        // 192*8
    int rem = idx - kg * 1536;
    int col = rem >> 3, j = rem & 7;
    Wout[idx] = f2bf(ow[(size_t)(kg * 8 + j) * C_DIM + col]);
}

// MFMA GEMM: C(MxN) = A(Mx192 f32) @ W(192xN, bf16 fragments [kg][col][8]).
// Block = 32 rows x 192 cols; 4 waves = 2 m-tiles x 2 n-halves (96 cols each).
__global__ __launch_bounds__(256) void gemm_bf16(const float* __restrict__ A,
        const unsigned short* __restrict__ Wt, float* __restrict__ Cc, int N)
{
    __shared__ __align__(16) unsigned short Abt[32 * 25 * 8];  // 12.8 KB
    const int tid = threadIdx.x;
    const int m0 = blockIdx.x * 32;
    const int col0 = blockIdx.y * 192;

    #pragma unroll
    for (int it = 0; it < 3; ++it) {
        int idx = tid + it * 256;            // 768 = 32 rows * 24 kg
        int r = idx / 24, g = idx - r * 24;
        const float* src = &A[((size_t)(m0 + r)) * C_DIM + g * 8];
        float4 v0 = *(const float4*)src;
        float4 v1 = *(const float4*)(src + 4);
        uint4 w;
        w.x = f2bf(v0.x) | ((unsigned)f2bf(v0.y) << 16);
        w.y = f2bf(v0.z) | ((unsigned)f2bf(v0.w) << 16);
        w.z = f2bf(v1.x) | ((unsigned)f2bf(v1.y) << 16);
        w.w = f2bf(v1.z) | ((unsigned)f2bf(v1.w) << 16);
        *(uint4*)&Abt[(r * 25 + g) * 8] = w;
    }
    __syncthreads();

    const int wv = tid >> 6;
    const int ln = tid & 63;
    const int rw = ln & 15;
    const int kq = ln >> 4;
    const int mt = wv >> 1;        // 0,1
    const int nh = wv & 1;         // 0,1 -> col offset nh*96

    f32x4 acc[6];
    #pragma unroll
    for (int nt = 0; nt < 6; ++nt) acc[nt] = (f32x4){0.f, 0.f, 0.f, 0.f};

    #pragma unroll
    for (int ks = 0; ks < 6; ++ks) {
        int kg = ks * 4 + kq;
        bf16x8 a = *(const bf16x8*)&Abt[((mt * 16 + rw) * 25 + kg) * 8];
        #pragma unroll
        for (int nt = 0; nt < 6; ++nt) {
            int col = col0 + nh * 96 + nt * 16 + rw;
            bf16x8 b = *(const bf16x8*)&Wt[((size_t)kg * N + col) * 8];
            acc[nt] = __builtin_amdgcn_mfma_f32_16x16x32_bf16(a, b, acc[nt], 0, 0, 0);
        }
    }
    #pragma unroll
    for (int nt = 0; nt < 6; ++nt)
        #pragma unroll
        for (int i = 0; i < 4; ++i) {
            int row = m0 + mt * 16 + kq * 4 + i;
            int col = col0 + nh * 96 + nt * 16 + rw;
            Cc[(size_t)row * N + col] = acc[nt][i];
        }
}

// depthwise 3x3 SAME conv + bias + SiLU -> xc (B,L,C). Sliding-window over w.
__global__ __launch_bounds__(192) void conv_silu(const float* __restrict__ xz,
        const float* __restrict__ cw, const float* __restrict__ cb, float* __restrict__ xc)
{
    const int c = threadIdx.x;
    const int h = blockIdx.x;
    const int w0 = blockIdx.y * 32;
    const int b = blockIdx.z;
    float wg[9];
    #pragma unroll
    for (int i = 0; i < 9; ++i) wg[i] = cw[c * 9 + i];
    const float* base = xz + ((size_t)b * L_SZ + (size_t)h * W_SZ) * (2 * C_DIM) + c;
    const bool hm = (h > 0), hp = (h < H_SZ - 1);
    const int RS = W_SZ * 2 * C_DIM;  // 24576
    float cL[3], cC[3], cR[3];
    #define LDCOL(w, dst) { \
        int off_ = (w) * (2 * C_DIM); \
        dst[0] = hm ? base[off_ - RS] : 0.f; \
        dst[1] = base[off_]; \
        dst[2] = hp ? base[off_ + RS] : 0.f; }
    if (w0 > 0) { LDCOL(w0 - 1, cL) } else { cL[0] = cL[1] = cL[2] = 0.f; }
    LDCOL(w0, cC)
    const float bias = cb[c];
    for (int w = w0; w < w0 + 32; ++w) {
        if (w < W_SZ - 1) { LDCOL(w + 1, cR) } else { cR[0] = cR[1] = cR[2] = 0.f; }
        float acc = bias;
        #pragma unroll
        for (int r = 0; r < 3; ++r)
            acc += cL[r] * wg[r * 3] + cC[r] * wg[r * 3 + 1] + cR[r] * wg[r * 3 + 2];
        float v = acc * sigmoidf_(acc);
        xc[((size_t)b * L_SZ + h * W_SZ + w) * C_DIM + c] = v;
        cL[0] = cC[0]; cL[1] = cC[1]; cL[2] = cC[2];
        cC[0] = cR[0]; cC[1] = cR[1]; cC[2] = cR[2];
    }
    #undef LDCOL
}

// MFMA proj: block = 64 memory-order rows x one direction.
__global__ __launch_bounds__(256) void proj_mfma(const float* __restrict__ xc,
        const unsigned short* __restrict__ Wt_g, const unsigned short* __restrict__ Dw_g,
        const float* __restrict__ dtb,
        float* __restrict__ delta, float* __restrict__ du,
        float* __restrict__ Bm, float* __restrict__ Cm)
{
    __shared__ __align__(16) unsigned short Abt[64 * 25 * 8];  // [row][kg(+pad)][8]
    __shared__ __align__(16) unsigned short Wt[24 * 48 * 8];   // [kg][col][8]
    __shared__ __align__(16) unsigned short Dw[4 * 192 * 8];   // [kb][c][8]
    __shared__ __align__(16) unsigned short pjd[64 * 32];      // [row][k 0..31]
    __shared__ float pj[64][50];

    const int tid = threadIdx.x;
    const int m0 = blockIdx.x * 64;
    const int b  = m0 >> 12;
    const int l0 = m0 & (L_SZ - 1);
    const int k  = blockIdx.y;
    const int kbi = k * B_SZ + b;

    #pragma unroll
    for (int it = 0; it < 6; ++it) {
        int idx = tid + it * 256;            // 1536 = 64 rows * 24 kgroups
        int r = idx / 24, g = idx - r * 24;
        const float* src = &xc[((size_t)(m0 + r)) * C_DIM + g * 8];
        float4 v0 = *(const float4*)src;
        float4 v1 = *(const float4*)(src + 4);
        uint4 w;
        w.x = f2bf(v0.x) | ((unsigned)f2bf(v0.y) << 16);
        w.y = f2bf(v0.z) | ((unsigned)f2bf(v0.w) << 16);
        w.z = f2bf(v1.x) | ((unsigned)f2bf(v1.y) << 16);
        w.w = f2bf(v1.z) | ((unsigned)f2bf(v1.w) << 16);
        *(uint4*)&Abt[(r * 25 + g) * 8] = w;
    }
    {
        const uint4* src = (const uint4*)Wt_g + (size_t)k * 1152;
        uint4* dst = (uint4*)Wt;
        #pragma unroll
        for (int it = 0; it < 5; ++it) {
            int idx = tid + it * 256;
            if (idx < 1152) dst[idx] = src[idx];
        }
        const uint4* src2 = (const uint4*)Dw_g + (size_t)k * 768;
        uint4* dst2 = (uint4*)Dw;
        #pragma unroll
        for (int it = 0; it < 3; ++it) dst2[tid + it * 256] = src2[tid + it * 256];
    }
    // zero ALL of pjd: 4096 B = 256 uint4
    ((uint4*)pjd)[tid] = make_uint4(0, 0, 0, 0);
    __syncthreads();

    const int wv = tid >> 6;
    const int ln = tid & 63;
    const int rw = ln & 15;
    const int kq = ln >> 4;

    // ---- GEMM1 ----
    f32x4 acc0 = {0.f, 0.f, 0.f, 0.f}, acc1 = acc0, acc2 = acc0;
    #pragma unroll
    for (int ks = 0; ks < 6; ++ks) {
        int kg = ks * 4 + kq;
        bf16x8 a  = *(const bf16x8*)&Abt[((wv * 16 + rw) * 25 + kg) * 8];
        bf16x8 b0 = *(const bf16x8*)&Wt[(kg * 48 + rw) * 8];
        bf16x8 b1 = *(const bf16x8*)&Wt[(kg * 48 + 16 + rw) * 8];
        bf16x8 b2 = *(const bf16x8*)&Wt[(kg * 48 + 32 + rw) * 8];
        acc0 = __builtin_amdgcn_mfma_f32_16x16x32_bf16(a, b0, acc0, 0, 0, 0);
        acc1 = __builtin_amdgcn_mfma_f32_16x16x32_bf16(a, b1, acc1, 0, 0, 0);
        acc2 = __builtin_amdgcn_mfma_f32_16x16x32_bf16(a, b2, acc2, 0, 0, 0);
    }
    #pragma unroll
    for (int i = 0; i < 4; ++i) {
        int row = wv * 16 + kq * 4 + i;
        pj[row][rw]      = acc0[i];
        pj[row][16 + rw] = acc1[i];
        pj[row][32 + rw] = acc2[i];
        if (rw < D_RK) pjd[row * 32 + rw] = f2bf(acc0[i]);
    }
    __syncthreads();

    // ---- GEMM2: delta logits ----
    bf16x8 a2 = *(const bf16x8*)&pjd[(wv * 16 + rw) * 32 + kq * 8];
    f32x4 d2[12];
    #pragma unroll
    for (int nt = 0; nt < 12; ++nt) {
        bf16x8 b2 = *(const bf16x8*)&Dw[(kq * 192 + nt * 16 + rw) * 8];
        f32x4 z = {0.f, 0.f, 0.f, 0.f};
        d2[nt] = __builtin_amdgcn_mfma_f32_16x16x32_bf16(a2, b2, z, 0, 0, 0);
    }

    int rowv[4], tep[4];
    #pragma unroll
    for (int i = 0; i < 4; ++i) {
        rowv[i] = wv * 16 + kq * 4 + i;
        tep[i] = scan_map(k, l0 + rowv[i]);
    }
    #pragma unroll
    for (int nt = 0; nt < 12; ++nt) {
        int c = nt * 16 + rw;
        float dtb2 = 2.f * dtb[k * C_DIM + c];
        #pragma unroll
        for (int i = 0; i < 4; ++i) {
            float s = d2[nt][i] + dtb2;
            float sp = (s > 15.f) ? s : __logf(1.f + __expf(s));
            float u = xc[((size_t)(m0 + rowv[i])) * C_DIM + c];
            size_t oi = ((size_t)kbi * L_SZ + tep[i]) * C_DIM + c;
            delta[oi] = sp;
            du[oi] = sp * u;
        }
    }
    #pragma unroll
    for (int j = 0; j < 4; ++j) {
        int o = tid + j * 256;               // 1024 = 64*16
        int ll = o >> 4, n = o & 15;
        int te = scan_map(k, l0 + ll);
        size_t oo = ((size_t)kbi * L_SZ + te) * N_ST + n;
        Bm[oo] = pj[ll][D_RK + n];
        Cm[oo] = pj[ll][D_RK + N_ST + n];
    }
}

// ---- chunked scan, lane = (channel, 4 states) ----
// S1: chunk summary. Aprod(float4) -> dead-xz scratch, Bsum(float4) -> hb.
__global__ __launch_bounds__(256) void scan_part1(const float* __restrict__ delta,
        const float* __restrict__ du, const float* __restrict__ Bm,
        const float* __restrict__ A_logs,
        float* __restrict__ Apr, float* __restrict__ hb)
{
    __shared__ float B_s[TCHUNK][16];
    const int c0 = blockIdx.x * 64;
    const int kb = blockIdx.y;
    const int k = kb >> 1;
    const int ch = blockIdx.z;
    const int tid = threadIdx.x;
    ((float4*)B_s)[tid] = ((const float4*)(Bm + ((size_t)kb * L_SZ + ch * TCHUNK) * N_ST))[tid];
    __syncthreads();

    const int w = tid >> 6, ln = tid & 63;
    const int cl = ln & 15, g = ln >> 4;
    const int c = c0 + w * 16 + cl;
    const float4 Alg = *(const float4*)&A_logs[((size_t)k * C_DIM + c) * N_ST + g * 4];
    const float An0 = -__expf(Alg.x) * 1.44269504089f;
    const float An1 = -__expf(Alg.y) * 1.44269504089f;
    const float An2 = -__expf(Alg.z) * 1.44269504089f;
    const float An3 = -__expf(Alg.w) * 1.44269504089f;
    const float* dp = delta + ((size_t)kb * L_SZ + ch * TCHUNK) * C_DIM + c;
    const float* qp = du    + ((size_t)kb * L_SZ + ch * TCHUNK) * C_DIM + c;
    float h0 = 0.f, h1 = 0.f, h2 = 0.f, h3 = 0.f, dsum = 0.f;
    #pragma unroll 4
    for (int t = 0; t < TCHUNK; ++t) {
        float dlt = dp[(size_t)t * C_DIM];
        float qv  = qp[(size_t)t * C_DIM];
        float4 B4 = *(const float4*)&B_s[t][g * 4];
        dsum += dlt;
        h0 = fmaf(__builtin_amdgcn_exp2f(dlt * An0), h0, qv * B4.x);
        h1 = fmaf(__builtin_amdgcn_exp2f(dlt * An1), h1, qv * B4.y);
        h2 = fmaf(__builtin_amdgcn_exp2f(dlt * An2), h2, qv * B4.z);
        h3 = fmaf(__builtin_amdgcn_exp2f(dlt * An3), h3, qv * B4.w);
    }
    unsigned o = ((unsigned)(ch * K_DIR * B_SZ + kb) * C_DIM + c) * N_ST + g * 4;
    float4 Ap4;
    Ap4.x = __builtin_amdgcn_exp2f(dsum * An0);
    Ap4.y = __builtin_amdgcn_exp2f(dsum * An1);
    Ap4.z = __builtin_amdgcn_exp2f(dsum * An2);
    Ap4.w = __builtin_amdgcn_exp2f(dsum * An3);
    *(float4*)&Apr[apr_idx(o)] = Ap4;
    float4 hv = make_float4(h0, h1, h2, h3);
    *(float4*)&hb[o] = hv;
}

// S2: sequential compose over chunks; hb: reads Bsum, writes hinit (same buffer).
__global__ __launch_bounds__(256) void scan_part2(const float* __restrict__ Apr,
        float* hb)
{
    const int kb = blockIdx.y;
    const int wave = threadIdx.x >> 6;
    const int lane = threadIdx.x & 63;
    const int ci = lane >> 4;
    const int n = lane & 15;
    const int c = blockIdx.x * 16 + wave * 4 + ci;
    float h = 0.f;
    #pragma unroll 8
    for (int ch = 0; ch < NCHUNK; ++ch) {
        unsigned o = ((unsigned)(ch * K_DIR * B_SZ + kb) * C_DIM + c) * N_ST + n;
        float Ap = Apr[apr_idx(o)];
        float Bs = hb[o];
        hb[o] = h;                 // hinit (exclusive prefix)
        h = fmaf(Ap, h, Bs);
    }
}

// S3: re-run chunk from hinit; y = sum_n h*C -> overwrite du tile (ys).
__global__ __launch_bounds__(256) void scan_part3(const float* __restrict__ delta,
        float* duys, const float* __restrict__ Bm, const float* __restrict__ Cm,
        const float* __restrict__ A_logs, const float* __restrict__ hb)
{
    __shared__ float B_s[TCHUNK][16];
    __shared__ float C_s[TCHUNK][16];
    const int c0 = blockIdx.x * 64;
    const int kb = blockIdx.y;
    const int k = kb >> 1;
    const int ch = blockIdx.z;
    const int tid = threadIdx.x;
    ((float4*)B_s)[tid] = ((const float4*)(Bm + ((size_t)kb * L_SZ + ch * TCHUNK) * N_ST))[tid];
    ((float4*)C_s)[tid] = ((const float4*)(Cm + ((size_t)kb * L_SZ + ch * TCHUNK) * N_ST))[tid];
    __syncthreads();

    const int w = tid >> 6, ln = tid & 63;
    const int cl = ln & 15, g = ln >> 4;
    const int c = c0 + w * 16 + cl;
    const float4 Alg = *(const float4*)&A_logs[((size_t)k * C_DIM + c) * N_ST + g * 4];
    const float An0 = -__expf(Alg.x) * 1.44269504089f;
    const float An1 = -__expf(Alg.y) * 1.44269504089f;
    const float An2 = -__expf(Alg.z) * 1.44269504089f;
    const float An3 = -__expf(Alg.w) * 1.44269504089f;
    const size_t tbase = ((size_t)kb * L_SZ + ch * TCHUNK) * C_DIM + c;
    const float* dp = delta + tbase;
    float* qy = duys + tbase;          // read du[t], later write y[t] (same addr, safe order)
    unsigned o = ((unsigned)(ch * K_DIR * B_SZ + kb) * C_DIM + c) * N_ST + g * 4;
    float4 hv = *(const float4*)&hb[o];
    float h0 = hv.x, h1 = hv.y, h2 = hv.z, h3 = hv.w;
    #pragma unroll 4
    for (int t = 0; t < TCHUNK; ++t) {
        float dlt = dp[(size_t)t * C_DIM];
        float qv  = qy[(size_t)t * C_DIM];
        float4 B4 = *(const float4*)&B_s[t][g * 4];
        float4 C4 = *(const float4*)&C_s[t][g * 4];
        h0 = fmaf(__builtin_amdgcn_exp2f(dlt * An0), h0, qv * B4.x);
        h1 = fmaf(__builtin_amdgcn_exp2f(dlt * An1), h1, qv * B4.y);
        h2 = fmaf(__builtin_amdgcn_exp2f(dlt * An2), h2, qv * B4.z);
        h3 = fmaf(__builtin_amdgcn_exp2f(dlt * An3), h3, qv * B4.w);
        float p = h0 * C4.x;
        p = fmaf(h1, C4.y, p);
        p = fmaf(h2, C4.z, p);
        p = fmaf(h3, C4.w, p);
        p += __shfl_xor(p, 16);
        p += __shfl_xor(p, 32);
        if (g == 0) qy[(size_t)t * C_DIM] = p;
    }
}

// fused: gather 4 directions + (sum_k Ds)*xc + LayerNorm + *silu(z). wave per row.
__global__ __launch_bounds__(256) void ln_silu_fused(const float* __restrict__ ys,
        const float* __restrict__ xz, const float* __restrict__ xc,
        const float* __restrict__ Dsv, const float* __restrict__ g,
        const float* __restrict__ bb, float* __restrict__ outp)
{
    const int row = blockIdx.x * 4 + (threadIdx.x >> 6);  // b*L + l
    const int lane = threadIdx.x & 63;
    const int b = row >> 12, l = row & (L_SZ - 1);
    const int l2 = ((l & 63) << 6) | (l >> 6);
    const float* r0 = ys + ((size_t)(0 * B_SZ + b) * L_SZ + l) * C_DIM;
    const float* r1 = ys + ((size_t)(1 * B_SZ + b) * L_SZ + (L_SZ - 1 - l)) * C_DIM;
    const float* r2 = ys + ((size_t)(2 * B_SZ + b) * L_SZ + l2) * C_DIM;
    const float* r3 = ys + ((size_t)(3 * B_SZ + b) * L_SZ + (L_SZ - 1 - l2)) * C_DIM;
    float v[3];
    float s = 0.f, s2 = 0.f;
    #pragma unroll
    for (int j = 0; j < 3; ++j) {
        int cc = lane + 64 * j;
        float ds4 = Dsv[cc] + Dsv[C_DIM + cc] + Dsv[2 * C_DIM + cc] + Dsv[3 * C_DIM + cc];
        v[j] = r0[cc] + r1[cc] + r2[cc] + r3[cc]
             + ds4 * xc[(size_t)row * C_DIM + cc];
        s += v[j];
        s2 += v[j] * v[j];
    }
    #pragma unroll
    for (int off = 1; off < 64; off <<= 1) {
        s += __shfl_xor(s, off);
        s2 += __shfl_xor(s2, off);
    }
    float mu = s / C_DIM;
    float var = s2 / C_DIM - mu * mu;
    float rstd = rsqrtf(var + 1e-5f);
    #pragma unroll
    for (int j = 0; j < 3; ++j) {
        int cc = lane + 64 * j;
        float zv = xz[(size_t)row * (2 * C_DIM) + C_DIM + cc];
        float t = (v[j] - mu) * rstd * g[cc] + bb[cc];
        outp[(size_t)row * C_DIM + cc] = t * (zv * sigmoidf_(zv));
    }
}

extern "C" void kernel_launch(void* const* d_in, const int* in_sizes, int n_in,
                              void* d_out, int out_size, void* d_ws, size_t ws_size,
                              hipStream_t stream)
{
    const float* x         = (const float*)d_in[0];
    const float* in_proj_w = (const float*)d_in[1];
    const float* conv_w    = (const float*)d_in[2];
    const float* conv_b    = (const float*)d_in[3];
    const float* x_proj_w  = (const float*)d_in[4];
    const float* dt_w      = (const float*)d_in[5];
    const float* dt_b      = (const float*)d_in[6];
    const float* A_logs    = (const float*)d_in[7];
    const float* Ds        = (const float*)d_in[8];
    const float* ln_g      = (const float*)d_in[9];
    const float* ln_b      = (const float*)d_in[10];
    const float* out_w     = (const float*)d_in[11];
    float* out = (float*)d_out;
    float* ws = (float*)d_ws;

    const size_t M = (size_t)B_SZ * L_SZ;          // 8192
    const size_t KM = (size_t)K_DIR * M;           // 32768

    float* xz    = ws;                       // M*384  (first half dead after conv -> Aprod scratch)
    float* xc    = xz + M * 384;             // M*192
    float* delta = xc + M * C_DIM;           // KM*192
    float* duys  = delta + KM * C_DIM;       // KM*192 : du, then ys in-place
    float* Bm    = duys + KM * C_DIM;        // KM*16
    float* Cm    = Bm + KM * N_ST;           // KM*16
    float* hb    = Cm + KM * N_ST;           // NCHUNK*8*192*16 : Bsum then hinit
    float* tbuf  = delta;                    // reuse after scan

    // bf16 weight buffers in hb (dead until scan_part1 overwrites)
    unsigned short* Wt_g = (unsigned short*)hb;            // 4*9216
    unsigned short* Dw_g = Wt_g + 4 * 9216;                // 4*6144
    unsigned short* Wip  = Dw_g + 4 * 6144;                // 73728
    // out_w fragments in Cm (dead after scan_part3)
    unsigned short* Wout = (unsigned short*)Cm;            // 36864

    wconv_all<<<dim3(528), 256, 0, stream>>>(in_proj_w, x_proj_w, dt_w, Wip, Wt_g, Dw_g);
    gemm_bf16<<<dim3(M / 32, 2), 256, 0, stream>>>(x, Wip, xz, 2 * C_DIM);
    conv_silu<<<dim3(H_SZ, 2, B_SZ), 192, 0, stream>>>(xz, conv_w, conv_b, xc);
    proj_mfma<<<dim3(M / 64, K_DIR), 256, 0, stream>>>(xc, Wt_g, Dw_g, dt_b, delta, duys, Bm, Cm);
    scan_part1<<<dim3(C_DIM / 64, K_DIR * B_SZ, NCHUNK), 256, 0, stream>>>(delta, duys, Bm, A_logs, xz, hb);
    scan_part2<<<dim3(C_DIM / 16, K_DIR * B_SZ), 256, 0, stream>>>(xz, hb);
    scan_part3<<<dim3(C_DIM / 64, K_DIR * B_SZ, NCHUNK), 256, 0, stream>>>(delta, duys, Bm, Cm, A_logs, hb);
    wconv_out<<<dim3(144), 256, 0, stream>>>(out_w, Wout);
    ln_silu_fused<<<dim3(M / 4), 256, 0, stream>>>(duys, xz, xc, Ds, ln_g, ln_b, tbuf);
    gemm_bf16<<<dim3(M / 32, 1), 256, 0, stream>>>(tbuf, Wout, out, C_DIM);
}

// Round 12
// 130.029 us; speedup vs baseline: 15.1521x; 1.0645x over previous
//
#include <hip/hip_runtime.h>
#include <math.h>

#define C_DIM 192
#define N_ST 16
#define K_DIR 4
#define D_RK 12
#define B_SZ 2
#define H_SZ 64
#define W_SZ 64
#define L_SZ 4096
#define DPROJ 44   // D_RK + 2*N_ST
#define NCHUNK 64
#define TCHUNK 64  // L_SZ / NCHUNK

typedef short bf16x8 __attribute__((ext_vector_type(8)));
typedef float f32x4 __attribute__((ext_vector_type(4)));

__device__ __forceinline__ float sigmoidf_(float x) { return 1.f / (1.f + __expf(-x)); }

// f32 -> bf16 (round-to-nearest-even), as raw ushort
__device__ __forceinline__ unsigned short f2bf(float f) {
    unsigned u = __builtin_bit_cast(unsigned, f);
    return (unsigned short)((u + 0x7FFFu + ((u >> 16) & 1u)) >> 16);
}
__device__ __forceinline__ float bfhi(unsigned p) {           // hi bf16 -> f32
    return __builtin_bit_cast(float, p & 0xFFFF0000u);
}
__device__ __forceinline__ float bflo(unsigned p) {           // lo bf16 -> f32
    return __builtin_bit_cast(float, p << 16);
}

// scan-order index t <-> memory index l (involution for every k)
__device__ __forceinline__ int scan_map(int k, int t) {
    int te = (k & 1) ? (L_SZ - 1 - t) : t;
    return (k >= 2) ? (((te & 63) << 6) | (te >> 6)) : te;  // transpose HxW (64x64)
}

// Aprod scratch lives in the dead x_ssm half of xz (cols 0..191 of each 384-row)
__device__ __forceinline__ size_t apr_idx(unsigned o) {
    unsigned r = o / 192u;
    unsigned m = o - r * 192u;
    return (size_t)r * 384u + m;
}

// ---- one-time weight conversion -> bf16 MFMA fragments ----
// Wip [kg<24][col<384][8]; Wt_g [k][kg<24][col<48][8]; Dw_g [k][kb<4][c<192][8];
// Wout [kg<24][col<192][8]
__global__ __launch_bounds__(256) void wconv_all(const float* __restrict__ ipw,
        const float* __restrict__ xpw, const float* __restrict__ dtw,
        const float* __restrict__ ow,
        unsigned short* __restrict__ Wip, unsigned short* __restrict__ Wt_g,
        unsigned short* __restrict__ Dw_g, unsigned short* __restrict__ Wout)
{
    int idx = blockIdx.x * 256 + threadIdx.x;   // 0 .. 172031
    if (idx < 73728) {                          // in_proj_w
        int kg = idx / 3072;                    // 384*8
        int rem = idx - kg * 3072;
        int col = rem >> 3, j = rem & 7;
        Wip[idx] = f2bf(ipw[(size_t)(kg * 8 + j) * 384 + col]);
    } else if (idx < 110592) {                  // x_proj_w
        int i2 = idx - 73728;
        int k = i2 / 9216;
        int rem = i2 - k * 9216;
        int kg = rem / 384;
        int r2 = rem - kg * 384;
        int col = r2 >> 3, j = r2 & 7;
        int kr = kg * 8 + j;
        float v = (col < DPROJ) ? xpw[(size_t)k * C_DIM * DPROJ + kr * DPROJ + col] : 0.f;
        Wt_g[i2] = f2bf(v);
    } else if (idx < 135168) {                  // dt_w
        int i3 = idx - 110592;
        int k = i3 / 6144;
        int rem = i3 - k * 6144;
        int kb2 = rem / 1536;
        int r2 = rem - kb2 * 1536;
        int c = r2 >> 3, j = r2 & 7;
        int kr = kb2 * 8 + j;
        float v = (kr < D_RK) ? dtw[(size_t)k * D_RK * C_DIM + kr * C_DIM + c] : 0.f;
        Dw_g[i3] = f2bf(v);
    } else {                                    // out_w
        int i4 = idx - 135168;
        int kg = i4 / 1536;                     // 192*8
        int rem = i4 - kg * 1536;
        int col = rem >> 3, j = rem & 7;
        Wout[i4] = f2bf(ow[(size_t)(kg * 8 + j) * C_DIM + col]);
    }
}

// MFMA GEMM: C(MxN) = A(Mx192 f32) @ W(192xN bf16 fragments [kg][col][8]).
// Block = 32 rows x 192 cols; 4 waves = 2 m-tiles x 2 n-halves (96 cols each).
__global__ __launch_bounds__(256) void gemm_bf16(const float* __restrict__ A,
        const unsigned short* __restrict__ Wt, float* __restrict__ Cc, int N)
{
    __shared__ __align__(16) unsigned short Abt[32 * 25 * 8];  // 12.8 KB
    const int tid = threadIdx.x;
    const int m0 = blockIdx.x * 32;
    const int col0 = blockIdx.y * 192;

    #pragma unroll
    for (int it = 0; it < 3; ++it) {
        int idx = tid + it * 256;            // 768 = 32 rows * 24 kg
        int r = idx / 24, g = idx - r * 24;
        const float* src = &A[((size_t)(m0 + r)) * C_DIM + g * 8];
        float4 v0 = *(const float4*)src;
        float4 v1 = *(const float4*)(src + 4);
        uint4 w;
        w.x = f2bf(v0.x) | ((unsigned)f2bf(v0.y) << 16);
        w.y = f2bf(v0.z) | ((unsigned)f2bf(v0.w) << 16);
        w.z = f2bf(v1.x) | ((unsigned)f2bf(v1.y) << 16);
        w.w = f2bf(v1.z) | ((unsigned)f2bf(v1.w) << 16);
        *(uint4*)&Abt[(r * 25 + g) * 8] = w;
    }
    __syncthreads();

    const int wv = tid >> 6;
    const int ln = tid & 63;
    const int rw = ln & 15;
    const int kq = ln >> 4;
    const int mt = wv >> 1;
    const int nh = wv & 1;

    f32x4 acc[6];
    #pragma unroll
    for (int nt = 0; nt < 6; ++nt) acc[nt] = (f32x4){0.f, 0.f, 0.f, 0.f};

    #pragma unroll
    for (int ks = 0; ks < 6; ++ks) {
        int kg = ks * 4 + kq;
        bf16x8 a = *(const bf16x8*)&Abt[((mt * 16 + rw) * 25 + kg) * 8];
        #pragma unroll
        for (int nt = 0; nt < 6; ++nt) {
            int col = col0 + nh * 96 + nt * 16 + rw;
            bf16x8 b = *(const bf16x8*)&Wt[((size_t)kg * N + col) * 8];
            acc[nt] = __builtin_amdgcn_mfma_f32_16x16x32_bf16(a, b, acc[nt], 0, 0, 0);
        }
    }
    #pragma unroll
    for (int nt = 0; nt < 6; ++nt)
        #pragma unroll
        for (int i = 0; i < 4; ++i) {
            int row = m0 + mt * 16 + kq * 4 + i;
            int col = col0 + nh * 96 + nt * 16 + rw;
            Cc[(size_t)row * N + col] = acc[nt][i];
        }
}

// depthwise 3x3 SAME conv + bias + SiLU -> xc (B,L,C). Sliding-window over w.
__global__ __launch_bounds__(192) void conv_silu(const float* __restrict__ xz,
        const float* __restrict__ cw, const float* __restrict__ cb, float* __restrict__ xc)
{
    const int c = threadIdx.x;
    const int h = blockIdx.x;
    const int w0 = blockIdx.y * 32;
    const int b = blockIdx.z;
    float wg[9];
    #pragma unroll
    for (int i = 0; i < 9; ++i) wg[i] = cw[c * 9 + i];
    const float* base = xz + ((size_t)b * L_SZ + (size_t)h * W_SZ) * (2 * C_DIM) + c;
    const bool hm = (h > 0), hp = (h < H_SZ - 1);
    const int RS = W_SZ * 2 * C_DIM;  // 24576
    float cL[3], cC[3], cR[3];
    #define LDCOL(w, dst) { \
        int off_ = (w) * (2 * C_DIM); \
        dst[0] = hm ? base[off_ - RS] : 0.f; \
        dst[1] = base[off_]; \
        dst[2] = hp ? base[off_ + RS] : 0.f; }
    if (w0 > 0) { LDCOL(w0 - 1, cL) } else { cL[0] = cL[1] = cL[2] = 0.f; }
    LDCOL(w0, cC)
    const float bias = cb[c];
    for (int w = w0; w < w0 + 32; ++w) {
        if (w < W_SZ - 1) { LDCOL(w + 1, cR) } else { cR[0] = cR[1] = cR[2] = 0.f; }
        float acc = bias;
        #pragma unroll
        for (int r = 0; r < 3; ++r)
            acc += cL[r] * wg[r * 3] + cC[r] * wg[r * 3 + 1] + cR[r] * wg[r * 3 + 2];
        float v = acc * sigmoidf_(acc);
        xc[((size_t)b * L_SZ + h * W_SZ + w) * C_DIM + c] = v;
        cL[0] = cC[0]; cL[1] = cC[1]; cL[2] = cC[2];
        cC[0] = cR[0]; cC[1] = cR[1]; cC[2] = cR[2];
    }
    #undef LDCOL
}

// MFMA proj: block = 64 memory-order rows x one direction.
// Writes dq = packed(bf16 delta, bf16 du) - ONE scatter store per element.
__global__ __launch_bounds__(256) void proj_mfma(const float* __restrict__ xc,
        const unsigned short* __restrict__ Wt_g, const unsigned short* __restrict__ Dw_g,
        const float* __restrict__ dtb,
        unsigned* __restrict__ dq,
        float* __restrict__ Bm, float* __restrict__ Cm)
{
    __shared__ __align__(16) unsigned short Abt[64 * 25 * 8];
    __shared__ __align__(16) unsigned short Wt[24 * 48 * 8];
    __shared__ __align__(16) unsigned short Dw[4 * 192 * 8];
    __shared__ __align__(16) unsigned short pjd[64 * 32];
    __shared__ float pj[64][50];

    const int tid = threadIdx.x;
    const int m0 = blockIdx.x * 64;
    const int b  = m0 >> 12;
    const int l0 = m0 & (L_SZ - 1);
    const int k  = blockIdx.y;
    const int kbi = k * B_SZ + b;

    #pragma unroll
    for (int it = 0; it < 6; ++it) {
        int idx = tid + it * 256;            // 1536 = 64 rows * 24 kgroups
        int r = idx / 24, g = idx - r * 24;
        const float* src = &xc[((size_t)(m0 + r)) * C_DIM + g * 8];
        float4 v0 = *(const float4*)src;
        float4 v1 = *(const float4*)(src + 4);
        uint4 w;
        w.x = f2bf(v0.x) | ((unsigned)f2bf(v0.y) << 16);
        w.y = f2bf(v0.z) | ((unsigned)f2bf(v0.w) << 16);
        w.z = f2bf(v1.x) | ((unsigned)f2bf(v1.y) << 16);
        w.w = f2bf(v1.z) | ((unsigned)f2bf(v1.w) << 16);
        *(uint4*)&Abt[(r * 25 + g) * 8] = w;
    }
    {
        const uint4* src = (const uint4*)Wt_g + (size_t)k * 1152;
        uint4* dst = (uint4*)Wt;
        #pragma unroll
        for (int it = 0; it < 5; ++it) {
            int idx = tid + it * 256;
            if (idx < 1152) dst[idx] = src[idx];
        }
        const uint4* src2 = (const uint4*)Dw_g + (size_t)k * 768;
        uint4* dst2 = (uint4*)Dw;
        #pragma unroll
        for (int it = 0; it < 3; ++it) dst2[tid + it * 256] = src2[tid + it * 256];
    }
    ((uint4*)pjd)[tid] = make_uint4(0, 0, 0, 0);   // all 256 uint4s
    __syncthreads();

    const int wv = tid >> 6;
    const int ln = tid & 63;
    const int rw = ln & 15;
    const int kq = ln >> 4;

    // ---- GEMM1 ----
    f32x4 acc0 = {0.f, 0.f, 0.f, 0.f}, acc1 = acc0, acc2 = acc0;
    #pragma unroll
    for (int ks = 0; ks < 6; ++ks) {
        int kg = ks * 4 + kq;
        bf16x8 a  = *(const bf16x8*)&Abt[((wv * 16 + rw) * 25 + kg) * 8];
        bf16x8 b0 = *(const bf16x8*)&Wt[(kg * 48 + rw) * 8];
        bf16x8 b1 = *(const bf16x8*)&Wt[(kg * 48 + 16 + rw) * 8];
        bf16x8 b2 = *(const bf16x8*)&Wt[(kg * 48 + 32 + rw) * 8];
        acc0 = __builtin_amdgcn_mfma_f32_16x16x32_bf16(a, b0, acc0, 0, 0, 0);
        acc1 = __builtin_amdgcn_mfma_f32_16x16x32_bf16(a, b1, acc1, 0, 0, 0);
        acc2 = __builtin_amdgcn_mfma_f32_16x16x32_bf16(a, b2, acc2, 0, 0, 0);
    }
    #pragma unroll
    for (int i = 0; i < 4; ++i) {
        int row = wv * 16 + kq * 4 + i;
        pj[row][rw]      = acc0[i];
        pj[row][16 + rw] = acc1[i];
        pj[row][32 + rw] = acc2[i];
        if (rw < D_RK) pjd[row * 32 + rw] = f2bf(acc0[i]);
    }
    __syncthreads();

    // ---- GEMM2: delta logits ----
    bf16x8 a2 = *(const bf16x8*)&pjd[(wv * 16 + rw) * 32 + kq * 8];
    f32x4 d2[12];
    #pragma unroll
    for (int nt = 0; nt < 12; ++nt) {
        bf16x8 b2 = *(const bf16x8*)&Dw[(kq * 192 + nt * 16 + rw) * 8];
        f32x4 z = {0.f, 0.f, 0.f, 0.f};
        d2[nt] = __builtin_amdgcn_mfma_f32_16x16x32_bf16(a2, b2, z, 0, 0, 0);
    }

    int rowv[4], tep[4];
    #pragma unroll
    for (int i = 0; i < 4; ++i) {
        rowv[i] = wv * 16 + kq * 4 + i;
        tep[i] = scan_map(k, l0 + rowv[i]);
    }
    #pragma unroll
    for (int nt = 0; nt < 12; ++nt) {
        int c = nt * 16 + rw;
        float dtb2 = 2.f * dtb[k * C_DIM + c];
        #pragma unroll
        for (int i = 0; i < 4; ++i) {
            float s = d2[nt][i] + dtb2;
            float sp = (s > 15.f) ? s : __logf(1.f + __expf(s));
            float u = xc[((size_t)(m0 + rowv[i])) * C_DIM + c];
            size_t oi = ((size_t)kbi * L_SZ + tep[i]) * C_DIM + c;
            dq[oi] = ((unsigned)f2bf(sp) << 16) | (unsigned)f2bf(sp * u);
        }
    }
    #pragma unroll
    for (int j = 0; j < 4; ++j) {
        int o = tid + j * 256;               // 1024 = 64*16
        int ll = o >> 4, n = o & 15;
        int te = scan_map(k, l0 + ll);
        size_t oo = ((size_t)kbi * L_SZ + te) * N_ST + n;
        Bm[oo] = pj[ll][D_RK + n];
        Cm[oo] = pj[ll][D_RK + N_ST + n];
    }
}

// ---- chunked scan, lane = (channel, 4 states), packed bf16 delta/du loads ----
// S1: chunk summary. Aprod(float4) -> dead-xz scratch, Bsum(float4) -> hb.
__global__ __launch_bounds__(256) void scan_part1(const unsigned* __restrict__ dq,
        const float* __restrict__ Bm, const float* __restrict__ A_logs,
        float* __restrict__ Apr, float* __restrict__ hb)
{
    __shared__ float B_s[TCHUNK][16];
    const int c0 = blockIdx.x * 64;
    const int kb = blockIdx.y;
    const int k = kb >> 1;
    const int ch = blockIdx.z;
    const int tid = threadIdx.x;
    ((float4*)B_s)[tid] = ((const float4*)(Bm + ((size_t)kb * L_SZ + ch * TCHUNK) * N_ST))[tid];
    __syncthreads();

    const int w = tid >> 6, ln = tid & 63;
    const int cl = ln & 15, g = ln >> 4;
    const int c = c0 + w * 16 + cl;
    const float4 Alg = *(const float4*)&A_logs[((size_t)k * C_DIM + c) * N_ST + g * 4];
    const float An0 = -__expf(Alg.x) * 1.44269504089f;
    const float An1 = -__expf(Alg.y) * 1.44269504089f;
    const float An2 = -__expf(Alg.z) * 1.44269504089f;
    const float An3 = -__expf(Alg.w) * 1.44269504089f;
    const unsigned* pq = dq + ((size_t)kb * L_SZ + ch * TCHUNK) * C_DIM + c;
    float h0 = 0.f, h1 = 0.f, h2 = 0.f, h3 = 0.f, dsum = 0.f;
    #pragma unroll 4
    for (int t = 0; t < TCHUNK; ++t) {
        unsigned pk = pq[(size_t)t * C_DIM];
        float dlt = bfhi(pk);
        float qv  = bflo(pk);
        float4 B4 = *(const float4*)&B_s[t][g * 4];
        dsum += dlt;
        h0 = fmaf(__builtin_amdgcn_exp2f(dlt * An0), h0, qv * B4.x);
        h1 = fmaf(__builtin_amdgcn_exp2f(dlt * An1), h1, qv * B4.y);
        h2 = fmaf(__builtin_amdgcn_exp2f(dlt * An2), h2, qv * B4.z);
        h3 = fmaf(__builtin_amdgcn_exp2f(dlt * An3), h3, qv * B4.w);
    }
    unsigned o = ((unsigned)(ch * K_DIR * B_SZ + kb) * C_DIM + c) * N_ST + g * 4;
    float4 Ap4;
    Ap4.x = __builtin_amdgcn_exp2f(dsum * An0);
    Ap4.y = __builtin_amdgcn_exp2f(dsum * An1);
    Ap4.z = __builtin_amdgcn_exp2f(dsum * An2);
    Ap4.w = __builtin_amdgcn_exp2f(dsum * An3);
    *(float4*)&Apr[apr_idx(o)] = Ap4;
    float4 hv = make_float4(h0, h1, h2, h3);
    *(float4*)&hb[o] = hv;
}

// S2: sequential compose over chunks; hb: reads Bsum, writes hinit (same buffer).
__global__ __launch_bounds__(256) void scan_part2(const float* __restrict__ Apr,
        float* hb)
{
    const int kb = blockIdx.y;
    const int wave = threadIdx.x >> 6;
    const int lane = threadIdx.x & 63;
    const int ci = lane >> 4;
    const int n = lane & 15;
    const int c = blockIdx.x * 16 + wave * 4 + ci;
    float h = 0.f;
    #pragma unroll 8
    for (int ch = 0; ch < NCHUNK; ++ch) {
        unsigned o = ((unsigned)(ch * K_DIR * B_SZ + kb) * C_DIM + c) * N_ST + n;
        float Ap = Apr[apr_idx(o)];
        float Bs = hb[o];
        hb[o] = h;                 // hinit (exclusive prefix)
        h = fmaf(Ap, h, Bs);
    }
}

// S3: re-run chunk from hinit; y = sum_n h*C -> ys (f32).
__global__ __launch_bounds__(256) void scan_part3(const unsigned* __restrict__ dq,
        const float* __restrict__ Bm, const float* __restrict__ Cm,
        const float* __restrict__ A_logs, const float* __restrict__ hb,
        float* __restrict__ ys)
{
    __shared__ float B_s[TCHUNK][16];
    __shared__ float C_s[TCHUNK][16];
    const int c0 = blockIdx.x * 64;
    const int kb = blockIdx.y;
    const int k = kb >> 1;
    const int ch = blockIdx.z;
    const int tid = threadIdx.x;
    ((float4*)B_s)[tid] = ((const float4*)(Bm + ((size_t)kb * L_SZ + ch * TCHUNK) * N_ST))[tid];
    ((float4*)C_s)[tid] = ((const float4*)(Cm + ((size_t)kb * L_SZ + ch * TCHUNK) * N_ST))[tid];
    __syncthreads();

    const int w = tid >> 6, ln = tid & 63;
    const int cl = ln & 15, g = ln >> 4;
    const int c = c0 + w * 16 + cl;
    const float4 Alg = *(const float4*)&A_logs[((size_t)k * C_DIM + c) * N_ST + g * 4];
    const float An0 = -__expf(Alg.x) * 1.44269504089f;
    const float An1 = -__expf(Alg.y) * 1.44269504089f;
    const float An2 = -__expf(Alg.z) * 1.44269504089f;
    const float An3 = -__expf(Alg.w) * 1.44269504089f;
    const size_t tbase = ((size_t)kb * L_SZ + ch * TCHUNK) * C_DIM + c;
    const unsigned* pq = dq + tbase;
    float* yp = ys + tbase;
    unsigned o = ((unsigned)(ch * K_DIR * B_SZ + kb) * C_DIM + c) * N_ST + g * 4;
    float4 hv = *(const float4*)&hb[o];
    float h0 = hv.x, h1 = hv.y, h2 = hv.z, h3 = hv.w;
    #pragma unroll 4
    for (int t = 0; t < TCHUNK; ++t) {
        unsigned pk = pq[(size_t)t * C_DIM];
        float dlt = bfhi(pk);
        float qv  = bflo(pk);
        float4 B4 = *(const float4*)&B_s[t][g * 4];
        float4 C4 = *(const float4*)&C_s[t][g * 4];
        h0 = fmaf(__builtin_amdgcn_exp2f(dlt * An0), h0, qv * B4.x);
        h1 = fmaf(__builtin_amdgcn_exp2f(dlt * An1), h1, qv * B4.y);
        h2 = fmaf(__builtin_amdgcn_exp2f(dlt * An2), h2, qv * B4.z);
        h3 = fmaf(__builtin_amdgcn_exp2f(dlt * An3), h3, qv * B4.w);
        float p = h0 * C4.x;
        p = fmaf(h1, C4.y, p);
        p = fmaf(h2, C4.z, p);
        p = fmaf(h3, C4.w, p);
        p += __shfl_xor(p, 16);
        p += __shfl_xor(p, 32);
        if (g == 0) yp[(size_t)t * C_DIM] = p;
    }
}

// fused: gather 4 dirs + Ds*xc + LayerNorm + *silu(z) + out GEMM (MFMA).
// Block = 32 rows; phase 1: 8 threads/row LN; phase 2: gemm_bf16 pattern.
__global__ __launch_bounds__(256) void ln_gemm_fused(const float* __restrict__ ys,
        const float* __restrict__ xz, const float* __restrict__ xc,
        const float* __restrict__ Dsv, const float* __restrict__ g,
        const float* __restrict__ bb, const unsigned short* __restrict__ Wout,
        float* __restrict__ outp)
{
    __shared__ __align__(16) unsigned short Abt[32 * 25 * 8];
    __shared__ float ds4s[C_DIM];
    const int tid = threadIdx.x;
    const int m0 = blockIdx.x * 32;

    if (tid < C_DIM)
        ds4s[tid] = Dsv[tid] + Dsv[C_DIM + tid] + Dsv[2 * C_DIM + tid] + Dsv[3 * C_DIM + tid];
    __syncthreads();

    // ---- phase 1: LN + silu -> bf16 fragments ----
    {
        const int r = tid >> 3;            // row 0..31
        const int t8 = tid & 7;            // 8 threads per row, 24 cols each
        const int row = m0 + r;
        const int b = row >> 12, l = row & (L_SZ - 1);
        const int l2 = ((l & 63) << 6) | (l >> 6);
        const float* r0 = ys + ((size_t)(0 * B_SZ + b) * L_SZ + l) * C_DIM;
        const float* r1 = ys + ((size_t)(1 * B_SZ + b) * L_SZ + (L_SZ - 1 - l)) * C_DIM;
        const float* r2 = ys + ((size_t)(2 * B_SZ + b) * L_SZ + l2) * C_DIM;
        const float* r3 = ys + ((size_t)(3 * B_SZ + b) * L_SZ + (L_SZ - 1 - l2)) * C_DIM;
        const float* xcr = xc + (size_t)row * C_DIM;
        float4 v[6];
        float s = 0.f, s2 = 0.f;
        #pragma unroll
        for (int q = 0; q < 6; ++q) {
            int cc = t8 * 24 + q * 4;
            float4 a0 = *(const float4*)&r0[cc];
            float4 a1 = *(const float4*)&r1[cc];
            float4 a2 = *(const float4*)&r2[cc];
            float4 a3 = *(const float4*)&r3[cc];
            float4 xv = *(const float4*)&xcr[cc];
            float4 dd = *(const float4*)&ds4s[cc];
            float4 vv;
            vv.x = a0.x + a1.x + a2.x + a3.x + dd.x * xv.x;
            vv.y = a0.y + a1.y + a2.y + a3.y + dd.y * xv.y;
            vv.z = a0.z + a1.z + a2.z + a3.z + dd.z * xv.z;
            vv.w = a0.w + a1.w + a2.w + a3.w + dd.w * xv.w;
            v[q] = vv;
            s += vv.x + vv.y + vv.z + vv.w;
            s2 += vv.x * vv.x + vv.y * vv.y + vv.z * vv.z + vv.w * vv.w;
        }
        s += __shfl_xor(s, 1); s2 += __shfl_xor(s2, 1);
        s += __shfl_xor(s, 2); s2 += __shfl_xor(s2, 2);
        s += __shfl_xor(s, 4); s2 += __shfl_xor(s2, 4);
        float mu = s / C_DIM;
        float var = s2 / C_DIM - mu * mu;
        float rstd = rsqrtf(var + 1e-5f);
        const float* zr = xz + (size_t)row * (2 * C_DIM) + C_DIM;
        unsigned short ob[24];
        #pragma unroll
        for (int q = 0; q < 6; ++q) {
            int cc = t8 * 24 + q * 4;
            float4 gv = *(const float4*)&g[cc];
            float4 bv = *(const float4*)&bb[cc];
            float4 zv = *(const float4*)&zr[cc];
            float t0 = (v[q].x - mu) * rstd * gv.x + bv.x;
            float t1 = (v[q].y - mu) * rstd * gv.y + bv.y;
            float t2 = (v[q].z - mu) * rstd * gv.z + bv.z;
            float t3 = (v[q].w - mu) * rstd * gv.w + bv.w;
            ob[q * 4 + 0] = f2bf(t0 * (zv.x * sigmoidf_(zv.x)));
            ob[q * 4 + 1] = f2bf(t1 * (zv.y * sigmoidf_(zv.y)));
            ob[q * 4 + 2] = f2bf(t2 * (zv.z * sigmoidf_(zv.z)));
            ob[q * 4 + 3] = f2bf(t3 * (zv.w * sigmoidf_(zv.w)));
        }
        #pragma unroll
        for (int gi = 0; gi < 3; ++gi) {
            uint4 w;
            w.x = ob[gi * 8 + 0] | ((unsigned)ob[gi * 8 + 1] << 16);
            w.y = ob[gi * 8 + 2] | ((unsigned)ob[gi * 8 + 3] << 16);
            w.z = ob[gi * 8 + 4] | ((unsigned)ob[gi * 8 + 5] << 16);
            w.w = ob[gi * 8 + 6] | ((unsigned)ob[gi * 8 + 7] << 16);
            *(uint4*)&Abt[(r * 25 + t8 * 3 + gi) * 8] = w;
        }
    }
    __syncthreads();

    // ---- phase 2: out GEMM ----
    const int wv = tid >> 6;
    const int ln = tid & 63;
    const int rw = ln & 15;
    const int kq = ln >> 4;
    const int mt = wv >> 1;
    const int nh = wv & 1;

    f32x4 acc[6];
    #pragma unroll
    for (int nt = 0; nt < 6; ++nt) acc[nt] = (f32x4){0.f, 0.f, 0.f, 0.f};
    #pragma unroll
    for (int ks = 0; ks < 6; ++ks) {
        int kg = ks * 4 + kq;
        bf16x8 a = *(const bf16x8*)&Abt[((mt * 16 + rw) * 25 + kg) * 8];
        #pragma unroll
        for (int nt = 0; nt < 6; ++nt) {
            int col = nh * 96 + nt * 16 + rw;
            bf16x8 b = *(const bf16x8*)&Wout[((size_t)kg * C_DIM + col) * 8];
            acc[nt] = __builtin_amdgcn_mfma_f32_16x16x32_bf16(a, b, acc[nt], 0, 0, 0);
        }
    }
    #pragma unroll
    for (int nt = 0; nt < 6; ++nt)
        #pragma unroll
        for (int i = 0; i < 4; ++i) {
            int row = m0 + mt * 16 + kq * 4 + i;
            int col = nh * 96 + nt * 16 + rw;
            outp[(size_t)row * C_DIM + col] = acc[nt][i];
        }
}

extern "C" void kernel_launch(void* const* d_in, const int* in_sizes, int n_in,
                              void* d_out, int out_size, void* d_ws, size_t ws_size,
                              hipStream_t stream)
{
    const float* x         = (const float*)d_in[0];
    const float* in_proj_w = (const float*)d_in[1];
    const float* conv_w    = (const float*)d_in[2];
    const float* conv_b    = (const float*)d_in[3];
    const float* x_proj_w  = (const float*)d_in[4];
    const float* dt_w      = (const float*)d_in[5];
    const float* dt_b      = (const float*)d_in[6];
    const float* A_logs    = (const float*)d_in[7];
    const float* Ds        = (const float*)d_in[8];
    const float* ln_g      = (const float*)d_in[9];
    const float* ln_b      = (const float*)d_in[10];
    const float* out_w     = (const float*)d_in[11];
    float* out = (float*)d_out;
    float* ws = (float*)d_ws;

    const size_t M = (size_t)B_SZ * L_SZ;          // 8192
    const size_t KM = (size_t)K_DIR * M;           // 32768

    float* xz      = ws;                           // M*384 (first half -> Apr scratch)
    float* xc      = xz + M * 384;                 // M*192
    unsigned* dq   = (unsigned*)(xc + M * C_DIM);  // KM*192 packed bf16 (delta,du)
    float* ys      = (float*)(dq + KM * C_DIM);    // KM*192
    float* Bm      = ys + KM * C_DIM;              // KM*16
    float* Cm      = Bm + KM * N_ST;               // KM*16
    float* hb      = Cm + KM * N_ST;               // NCHUNK*8*192*16 : Bsum then hinit
    // bf16 weights: Wip/Wt_g/Dw_g in hb (dead until scan_part1); Wout after hb
    unsigned short* Wt_g = (unsigned short*)hb;            // 4*9216
    unsigned short* Dw_g = Wt_g + 4 * 9216;                // 4*6144
    unsigned short* Wip  = Dw_g + 4 * 6144;                // 73728
    unsigned short* Wout = (unsigned short*)(hb + (size_t)NCHUNK * K_DIR * B_SZ * C_DIM * N_ST);

    wconv_all<<<dim3(672), 256, 0, stream>>>(in_proj_w, x_proj_w, dt_w, out_w, Wip, Wt_g, Dw_g, Wout);
    gemm_bf16<<<dim3(M / 32, 2), 256, 0, stream>>>(x, Wip, xz, 2 * C_DIM);
    conv_silu<<<dim3(H_SZ, 2, B_SZ), 192, 0, stream>>>(xz, conv_w, conv_b, xc);
    proj_mfma<<<dim3(M / 64, K_DIR), 256, 0, stream>>>(xc, Wt_g, Dw_g, dt_b, dq, Bm, Cm);
    scan_part1<<<dim3(C_DIM / 64, K_DIR * B_SZ, NCHUNK), 256, 0, stream>>>(dq, Bm, A_logs, xz, hb);
    scan_part2<<<dim3(C_DIM / 16, K_DIR * B_SZ), 256, 0, stream>>>(xz, hb);
    scan_part3<<<dim3(C_DIM / 64, K_DIR * B_SZ, NCHUNK), 256, 0, stream>>>(dq, Bm, Cm, A_logs, hb, ys);
    ln_gemm_fused<<<dim3(M / 32), 256, 0, stream>>>(ys, xz, xc, Ds, ln_g, ln_b, Wout, out);
}